// Round 1
// baseline (1355.555 us; speedup 1.0000x reference)
//
#include <hip/hip_runtime.h>
#include <hip/hip_bf16.h>
#include <math.h>

#define B_ 256
#define T_ 256
#define CIN 64
#define HID 512
#define NH 8
#define HD 64
#define FFD 2048
#define OUTD 10
#define KS 32

__device__ __forceinline__ float bf2f(unsigned u){
  union { unsigned i; float f; } c; c.i = u << 16; return c.f;
}

// LN stats over 512 values held as (v0 at tid, v1 at tid+256), 256 threads.
__device__ __forceinline__ void ln_stats(float v0, float v1, float* red, float* ms, int tid){
  float s = v0 + v1, s2 = v0*v0 + v1*v1;
  #pragma unroll
  for (int o = 32; o; o >>= 1){ s += __shfl_xor(s, o); s2 += __shfl_xor(s2, o); }
  int lane = tid & 63, wid = tid >> 6;
  if (lane == 0){ red[wid] = s; red[4+wid] = s2; }
  __syncthreads();
  if (tid == 0){
    float S = red[0]+red[1]+red[2]+red[3];
    float S2 = red[4]+red[5]+red[6]+red[7];
    float m = S * (1.f/512.f);
    float var = S2 * (1.f/512.f) - m*m;
    ms[0] = m; ms[1] = rsqrtf(var + 1e-5f);
  }
  __syncthreads();
}

__device__ __forceinline__ float dot_ld4(const float* __restrict__ w, const float* x, int n4){
  float acc = 0.f;
  const float4* w4 = (const float4*)w;
  const float4* x4 = (const float4*)x;
  for (int k = 0; k < n4; k++){
    float4 a = w4[k], b = x4[k];
    acc += a.x*b.x + a.y*b.y + a.z*b.z + a.w*b.w;
  }
  return acc;
}

// ---------------- kernel 1: q (B,512) and y_init = (k0.q) v0 ----------------
__global__ __launch_bounds__(256) void k_init(
    const float* __restrict__ initial, const float* __restrict__ logsig,
    const float* __restrict__ Wi, const float* __restrict__ bi,
    const float* __restrict__ Wip, const float* __restrict__ bip,
    const float* __restrict__ g_in, const float* __restrict__ b_in,
    const float* __restrict__ Wk, const float* __restrict__ bk,
    const float* __restrict__ Wv, const float* __restrict__ bv,
    const float* __restrict__ Wq, const float* __restrict__ bq,
    float* __restrict__ qout, float* __restrict__ yinit)
{
  int b = blockIdx.x, tid = threadIdx.x;
  __shared__ __align__(16) float xls[128];
  __shared__ __align__(16) float hln[512];
  __shared__ __align__(16) float tmp[512];
  __shared__ __align__(16) float v0s[512];
  __shared__ __align__(16) float qs[512];
  __shared__ __align__(16) float ip[64];
  __shared__ float red[8]; __shared__ float ms[2];
  __shared__ float hm[8], hs[8], sal[8];

  // ---- hq from last logsig row -> q ----
  if (tid < 64) xls[tid] = logsig[((size_t)b*T_ + (T_-1))*CIN + tid];
  __syncthreads();
  float h0 = bip[tid]     + dot_ld4(Wip + (size_t)tid*CIN,       xls, CIN/4);
  float h1 = bip[tid+256] + dot_ld4(Wip + (size_t)(tid+256)*CIN, xls, CIN/4);
  ln_stats(h0, h1, red, ms, tid);
  hln[tid]     = (h0-ms[0])*ms[1]*g_in[tid]     + b_in[tid];
  hln[tid+256] = (h1-ms[0])*ms[1]*g_in[tid+256] + b_in[tid+256];
  __syncthreads();
  tmp[tid]     = bq[tid]     + dot_ld4(Wq + (size_t)tid*HID,       hln, HID/4);
  tmp[tid+256] = bq[tid+256] + dot_ld4(Wq + (size_t)(tid+256)*HID, hln, HID/4);
  __syncthreads();
  if (tid < 8){
    float m = -1e30f; for (int e=0;e<64;e++) m = fmaxf(m, tmp[tid*64+e]);
    float s = 0.f;    for (int e=0;e<64;e++) s += expf(tmp[tid*64+e]-m);
    hm[tid] = m; hs[tid] = s;
  }
  __syncthreads();
  {
    float q0 = expf(tmp[tid]-hm[tid>>6]) / hs[tid>>6];
    float q1 = expf(tmp[tid+256]-hm[(tid+256)>>6]) / hs[(tid+256)>>6];
    qs[tid] = q0; qs[tid+256] = q1;
    qout[(size_t)b*HID+tid] = q0; qout[(size_t)b*HID+tid+256] = q1;
  }
  __syncthreads();

  // ---- init branch: init_proj -> h0 -> k0,v0 -> y_init ----
  if (tid < 128) xls[tid] = initial[(size_t)b*128 + tid];
  __syncthreads();
  if (tid < 64) ip[tid] = bi[tid] + dot_ld4(Wi + (size_t)tid*128, xls, 128/4);
  __syncthreads();
  h0 = bip[tid]     + dot_ld4(Wip + (size_t)tid*CIN,       ip, CIN/4);
  h1 = bip[tid+256] + dot_ld4(Wip + (size_t)(tid+256)*CIN, ip, CIN/4);
  ln_stats(h0, h1, red, ms, tid);
  hln[tid]     = (h0-ms[0])*ms[1]*g_in[tid]     + b_in[tid];
  hln[tid+256] = (h1-ms[0])*ms[1]*g_in[tid+256] + b_in[tid+256];
  __syncthreads();
  tmp[tid]     = bk[tid]     + dot_ld4(Wk + (size_t)tid*HID,       hln, HID/4);
  tmp[tid+256] = bk[tid+256] + dot_ld4(Wk + (size_t)(tid+256)*HID, hln, HID/4);
  v0s[tid]     = bv[tid]     + dot_ld4(Wv + (size_t)tid*HID,       hln, HID/4);
  v0s[tid+256] = bv[tid+256] + dot_ld4(Wv + (size_t)(tid+256)*HID, hln, HID/4);
  __syncthreads();
  if (tid < 8){
    float m = -1e30f; for (int e=0;e<64;e++) m = fmaxf(m, tmp[tid*64+e]);
    float s = 0.f;    for (int e=0;e<64;e++) s += expf(tmp[tid*64+e]-m);
    float a = 0.f;
    for (int e=0;e<64;e++) a += (expf(tmp[tid*64+e]-m)/s) * qs[tid*64+e];
    sal[tid] = a;
  }
  __syncthreads();
  yinit[(size_t)b*HID+tid]     = sal[tid>>6]       * v0s[tid];
  yinit[(size_t)b*HID+tid+256] = sal[(tid+256)>>6] * v0s[tid+256];
}

// ---------------- kernel A: Hln = LN(logsig @ Wip.T + bip) -> bf16 ----------------
__global__ __launch_bounds__(512) void k_hln(
    const float* __restrict__ logsig,
    const float* __restrict__ Wip, const float* __restrict__ bip,
    const float* __restrict__ g_in, const float* __restrict__ b_in,
    __hip_bfloat16* __restrict__ Hln)
{
  int b = blockIdx.x, tc = blockIdx.y, tid = threadIdx.x;
  __shared__ __align__(16) float xs[64][64];
  __shared__ float red[16]; __shared__ float ms[2];
  float w[64];
  {
    const float4* wr = (const float4*)(Wip + (size_t)tid*CIN);
    #pragma unroll
    for (int k=0;k<16;k++){ float4 t = wr[k]; w[4*k]=t.x; w[4*k+1]=t.y; w[4*k+2]=t.z; w[4*k+3]=t.w; }
  }
  float bj = bip[tid], gj = g_in[tid], bbj = b_in[tid];
  const float4* src = (const float4*)(logsig + ((size_t)b*T_ + tc*64)*CIN);
  for (int i = tid; i < 1024; i += 512){
    float4 t = src[i];
    int r = i>>4, c = (i&15)*4;
    xs[r][c]=t.x; xs[r][c+1]=t.y; xs[r][c+2]=t.z; xs[r][c+3]=t.w;
  }
  __syncthreads();
  int lane = tid & 63, wid = tid >> 6;
  for (int r = 0; r < 64; r++){
    float acc = bj;
    #pragma unroll
    for (int k4 = 0; k4 < 16; k4++){
      float4 xv = *(const float4*)&xs[r][k4*4];
      acc += w[4*k4]*xv.x + w[4*k4+1]*xv.y + w[4*k4+2]*xv.z + w[4*k4+3]*xv.w;
    }
    float s = acc, s2 = acc*acc;
    #pragma unroll
    for (int o = 32; o; o >>= 1){ s += __shfl_xor(s,o); s2 += __shfl_xor(s2,o); }
    if (lane == 0){ red[wid] = s; red[8+wid] = s2; }
    __syncthreads();
    if (tid == 0){
      float S=0.f, S2=0.f;
      #pragma unroll
      for (int i=0;i<8;i++){ S += red[i]; S2 += red[8+i]; }
      float m = S*(1.f/512.f), var = S2*(1.f/512.f) - m*m;
      ms[0] = m; ms[1] = rsqrtf(var + 1e-5f);
    }
    __syncthreads();
    float o = (acc - ms[0]) * ms[1] * gj + bbj;
    Hln[((size_t)b*T_ + tc*64 + r)*HID + tid] = __float2bfloat16(o);
    __syncthreads();
  }
}

// ---------------- kernel B: fused kv GEMM + softmax + (k.q) + T-reduction ----------------
__global__ __launch_bounds__(256) void k_field(
    const __hip_bfloat16* __restrict__ Hln,
    const float* __restrict__ Wk, const float* __restrict__ bk,
    const float* __restrict__ Wv, const float* __restrict__ bv,
    const float* __restrict__ qws, float* __restrict__ ypart)
{
  int b = blockIdx.x, tc = blockIdx.y, h = blockIdx.z, tid = threadIdx.x;
  __shared__ union {
    struct { __align__(16) float As[KS][68]; __align__(16) float Bs[KS][132]; } st;
    struct { float S[64][129]; float Al[64]; } ep;
  } u;
  float acc[4][8];
  #pragma unroll
  for (int i=0;i<4;i++)
    #pragma unroll
    for (int j=0;j<8;j++) acc[i][j] = 0.f;
  int tg = tid >> 4, cg = tid & 15;
  const __hip_bfloat16* Ab = Hln + ((size_t)b*T_ + tc*64)*HID;
  int arow = tid >> 2, ak0 = (tid & 3)*8;
  int bcol = tid >> 1, bk0 = (tid & 1)*16;
  const float* bsrc = (bcol < 64) ? (Wk + (size_t)(h*64+bcol)*HID)
                                  : (Wv + (size_t)(h*64+bcol-64)*HID);
  for (int kk = 0; kk < HID; kk += KS){
    uint4 raw = *(const uint4*)(Ab + (size_t)arow*HID + kk + ak0);
    u.st.As[ak0+0][arow]=bf2f(raw.x&0xffffu); u.st.As[ak0+1][arow]=bf2f(raw.x>>16);
    u.st.As[ak0+2][arow]=bf2f(raw.y&0xffffu); u.st.As[ak0+3][arow]=bf2f(raw.y>>16);
    u.st.As[ak0+4][arow]=bf2f(raw.z&0xffffu); u.st.As[ak0+5][arow]=bf2f(raw.z>>16);
    u.st.As[ak0+6][arow]=bf2f(raw.w&0xffffu); u.st.As[ak0+7][arow]=bf2f(raw.w>>16);
    const float4* bs4 = (const float4*)(bsrc + kk + bk0);
    #pragma unroll
    for (int i=0;i<4;i++){
      float4 t = bs4[i];
      u.st.Bs[bk0+4*i+0][bcol]=t.x; u.st.Bs[bk0+4*i+1][bcol]=t.y;
      u.st.Bs[bk0+4*i+2][bcol]=t.z; u.st.Bs[bk0+4*i+3][bcol]=t.w;
    }
    __syncthreads();
    #pragma unroll
    for (int k=0;k<KS;k++){
      float4 av  = *(const float4*)&u.st.As[k][tg*4];
      float4 bv0 = *(const float4*)&u.st.Bs[k][cg*8];
      float4 bv1 = *(const float4*)&u.st.Bs[k][cg*8+4];
      float a[4]  = {av.x,av.y,av.z,av.w};
      float bb[8] = {bv0.x,bv0.y,bv0.z,bv0.w,bv1.x,bv1.y,bv1.z,bv1.w};
      #pragma unroll
      for (int i=0;i<4;i++)
        #pragma unroll
        for (int j=0;j<8;j++) acc[i][j] += a[i]*bb[j];
    }
    __syncthreads();
  }
  // biases, write score/value tile
  #pragma unroll
  for (int j=0;j<8;j++){
    int c = cg*8 + j;
    float bias = (c < 64) ? bk[h*64+c] : bv[h*64+c-64];
    #pragma unroll
    for (int i=0;i<4;i++) u.ep.S[tg*4+i][c] = acc[i][j] + bias;
  }
  __syncthreads();
  // per-row: softmax over k-cols, alpha = w_t * (softmax . q)
  int row = tid >> 2, sub = tid & 3;
  const float* qv = qws + (size_t)b*HID + h*64;
  float m = -1e30f;
  for (int c = sub*16; c < sub*16+16; c++) m = fmaxf(m, u.ep.S[row][c]);
  m = fmaxf(m, __shfl_xor(m,1));
  m = fmaxf(m, __shfl_xor(m,2));
  float se = 0.f, sq = 0.f;
  for (int c = sub*16; c < sub*16+16; c++){
    float e = __expf(u.ep.S[row][c] - m);
    se += e; sq += e * qv[c];
  }
  se += __shfl_xor(se,1); se += __shfl_xor(se,2);
  sq += __shfl_xor(sq,1); sq += __shfl_xor(sq,2);
  int t = tc*64 + row;
  float wt = (t == 0) ? (5.f/6.f) : ((t == T_-1) ? (1.f/6.f) : 1.f);
  float alpha = wt * sq / se;
  if (sub == 0) u.ep.Al[row] = alpha;
  __syncthreads();
  // y_part[d] = sum_rows alpha_row * V[row][d]
  if (tid < 64){
    float y = 0.f;
    #pragma unroll 8
    for (int r = 0; r < 64; r++) y += u.ep.Al[r] * u.ep.S[r][64+tid];
    ypart[(((size_t)b*NH + h)*4 + tc)*64 + tid] = y;
  }
}

// ---------------- kernel C: y-sum, Wo, LN, FF, residual, final ----------------
__global__ __launch_bounds__(256) void k_head(
    const float* __restrict__ yinit, const float* __restrict__ ypart,
    const float* __restrict__ Wo, const float* __restrict__ bo,
    const float* __restrict__ g_ff, const float* __restrict__ b_ff,
    const float* __restrict__ W1, const float* __restrict__ b1,
    const float* __restrict__ W2, const float* __restrict__ b2,
    const float* __restrict__ Wf, const float* __restrict__ bf,
    float* __restrict__ out)
{
  int b = blockIdx.x, tid = threadIdx.x;
  __shared__ __align__(16) float y[512];
  __shared__ __align__(16) float yo[512];
  __shared__ __align__(16) float a1[FFD];
  __shared__ float red[8]; __shared__ float ms[2];
  #pragma unroll
  for (int u2=0; u2<2; u2++){
    int jj = tid + u2*256;
    float s = yinit[(size_t)b*HID + jj];
    int hh = jj >> 6, d = jj & 63;
    #pragma unroll
    for (int c=0;c<4;c++) s += ypart[(((size_t)b*NH + hh)*4 + c)*64 + d];
    y[jj] = s;
  }
  __syncthreads();
  float o0 = bo[tid]     + dot_ld4(Wo + (size_t)tid*HID,       y, HID/4);
  float o1 = bo[tid+256] + dot_ld4(Wo + (size_t)(tid+256)*HID, y, HID/4);
  ln_stats(o0, o1, red, ms, tid);
  yo[tid] = o0; yo[tid+256] = o1;
  y[tid]     = (o0-ms[0])*ms[1]*g_ff[tid]     + b_ff[tid];
  y[tid+256] = (o1-ms[0])*ms[1]*g_ff[tid+256] + b_ff[tid+256];
  __syncthreads();
  for (int f = tid; f < FFD; f += 256){
    float a = b1[f] + dot_ld4(W1 + (size_t)f*HID, y, HID/4);
    a1[f] = fmaxf(a, 0.f);
  }
  __syncthreads();
  float f0 = yo[tid]     + b2[tid]     + dot_ld4(W2 + (size_t)tid*FFD,       a1, FFD/4);
  float f1 = yo[tid+256] + b2[tid+256] + dot_ld4(W2 + (size_t)(tid+256)*FFD, a1, FFD/4);
  __syncthreads();
  y[tid] = f0; y[tid+256] = f1;
  __syncthreads();
  if (tid < OUTD){
    out[(size_t)b*OUTD + tid] = bf[tid] + dot_ld4(Wf + (size_t)tid*HID, y, HID/4);
  }
}

extern "C" void kernel_launch(void* const* d_in, const int* in_sizes, int n_in,
                              void* d_out, int out_size, void* d_ws, size_t ws_size,
                              hipStream_t stream)
{
  const float* initial = (const float*)d_in[0];
  const float* logsig  = (const float*)d_in[1];
  const float* Wi  = (const float*)d_in[2];  const float* bi  = (const float*)d_in[3];
  const float* Wip = (const float*)d_in[4];  const float* bip = (const float*)d_in[5];
  const float* g_in= (const float*)d_in[6];  const float* b_in= (const float*)d_in[7];
  const float* Wk  = (const float*)d_in[8];  const float* bk  = (const float*)d_in[9];
  const float* Wv  = (const float*)d_in[10]; const float* bv  = (const float*)d_in[11];
  const float* Wq  = (const float*)d_in[12]; const float* bq  = (const float*)d_in[13];
  const float* Wo  = (const float*)d_in[14]; const float* bo  = (const float*)d_in[15];
  const float* g_ff= (const float*)d_in[16]; const float* b_ff= (const float*)d_in[17];
  const float* W1  = (const float*)d_in[18]; const float* b1  = (const float*)d_in[19];
  const float* W2  = (const float*)d_in[20]; const float* b2  = (const float*)d_in[21];
  const float* Wf  = (const float*)d_in[22]; const float* bf  = (const float*)d_in[23];
  float* out = (float*)d_out;

  char* ws = (char*)d_ws;
  float* qws   = (float*)(ws);                         // 512 KB
  float* yinit = (float*)(ws + (512<<10));             // 512 KB
  float* ypart = (float*)(ws + (1<<20));               // 2 MB
  __hip_bfloat16* Hln = (__hip_bfloat16*)(ws + (3<<20)); // 64 MB

  k_init<<<B_, 256, 0, stream>>>(initial, logsig, Wi, bi, Wip, bip, g_in, b_in,
                                 Wk, bk, Wv, bv, Wq, bq, qws, yinit);
  k_hln<<<dim3(B_, 4), 512, 0, stream>>>(logsig, Wip, bip, g_in, b_in, Hln);
  k_field<<<dim3(B_, 4, NH), 256, 0, stream>>>(Hln, Wk, bk, Wv, bv, qws, ypart);
  k_head<<<B_, 256, 0, stream>>>(yinit, ypart, Wo, bo, g_ff, b_ff,
                                 W1, b1, W2, b2, Wf, bf, out);
}

// Round 2
// 731.537 us; speedup vs baseline: 1.8530x; 1.8530x over previous
//
#include <hip/hip_runtime.h>
#include <hip/hip_bf16.h>
#include <math.h>

#define B_ 256
#define T_ 256
#define CIN 64
#define HID 512
#define NH 8
#define HD 64
#define FFD 2048
#define OUTD 10

typedef __bf16 bf16x8 __attribute__((ext_vector_type(8)));
typedef float f32x4 __attribute__((ext_vector_type(4)));

__device__ __forceinline__ float bf2f(unsigned u){
  union { unsigned i; float f; } c; c.i = u << 16; return c.f;
}

// LN stats over 512 values held as (v0 at tid, v1 at tid+256), 256 threads.
__device__ __forceinline__ void ln_stats(float v0, float v1, float* red, float* ms, int tid){
  float s = v0 + v1, s2 = v0*v0 + v1*v1;
  #pragma unroll
  for (int o = 32; o; o >>= 1){ s += __shfl_xor(s, o); s2 += __shfl_xor(s2, o); }
  int lane = tid & 63, wid = tid >> 6;
  if (lane == 0){ red[wid] = s; red[4+wid] = s2; }
  __syncthreads();
  if (tid == 0){
    float S = red[0]+red[1]+red[2]+red[3];
    float S2 = red[4]+red[5]+red[6]+red[7];
    float m = S * (1.f/512.f);
    float var = S2 * (1.f/512.f) - m*m;
    ms[0] = m; ms[1] = rsqrtf(var + 1e-5f);
  }
  __syncthreads();
}

__device__ __forceinline__ float dot_ld4(const float* __restrict__ w, const float* x, int n4){
  float acc = 0.f;
  const float4* w4 = (const float4*)w;
  const float4* x4 = (const float4*)x;
  for (int k = 0; k < n4; k++){
    float4 a = w4[k], b = x4[k];
    acc += a.x*b.x + a.y*b.y + a.z*b.z + a.w*b.w;
  }
  return acc;
}

// ---------------- prep: Wk -> bf16 ----------------
__global__ __launch_bounds__(256) void k_prep(const float* __restrict__ Wk,
                                              __hip_bfloat16* __restrict__ Wkb){
  int i = blockIdx.x*256 + threadIdx.x;
  Wkb[i] = __float2bfloat16(Wk[i]);
}

// ---------------- kernel 1: q (B,512) and y_init = (k0.q) v0 ----------------
__global__ __launch_bounds__(256) void k_init(
    const float* __restrict__ initial, const float* __restrict__ logsig,
    const float* __restrict__ Wi, const float* __restrict__ bi,
    const float* __restrict__ Wip, const float* __restrict__ bip,
    const float* __restrict__ g_in, const float* __restrict__ b_in,
    const float* __restrict__ Wk, const float* __restrict__ bk,
    const float* __restrict__ Wv, const float* __restrict__ bv,
    const float* __restrict__ Wq, const float* __restrict__ bq,
    float* __restrict__ qout, float* __restrict__ yinit)
{
  int b = blockIdx.x, tid = threadIdx.x;
  __shared__ __align__(16) float xls[128];
  __shared__ __align__(16) float hln[512];
  __shared__ __align__(16) float tmp[512];
  __shared__ __align__(16) float v0s[512];
  __shared__ __align__(16) float qs[512];
  __shared__ __align__(16) float ip[64];
  __shared__ float red[8]; __shared__ float ms[2];
  __shared__ float hm[8], hs[8], sal[8];

  // ---- hq from last logsig row -> q ----
  if (tid < 64) xls[tid] = logsig[((size_t)b*T_ + (T_-1))*CIN + tid];
  __syncthreads();
  float h0 = bip[tid]     + dot_ld4(Wip + (size_t)tid*CIN,       xls, CIN/4);
  float h1 = bip[tid+256] + dot_ld4(Wip + (size_t)(tid+256)*CIN, xls, CIN/4);
  ln_stats(h0, h1, red, ms, tid);
  hln[tid]     = (h0-ms[0])*ms[1]*g_in[tid]     + b_in[tid];
  hln[tid+256] = (h1-ms[0])*ms[1]*g_in[tid+256] + b_in[tid+256];
  __syncthreads();
  tmp[tid]     = bq[tid]     + dot_ld4(Wq + (size_t)tid*HID,       hln, HID/4);
  tmp[tid+256] = bq[tid+256] + dot_ld4(Wq + (size_t)(tid+256)*HID, hln, HID/4);
  __syncthreads();
  if (tid < 8){
    float m = -1e30f; for (int e=0;e<64;e++) m = fmaxf(m, tmp[tid*64+e]);
    float s = 0.f;    for (int e=0;e<64;e++) s += expf(tmp[tid*64+e]-m);
    hm[tid] = m; hs[tid] = s;
  }
  __syncthreads();
  {
    float q0 = expf(tmp[tid]-hm[tid>>6]) / hs[tid>>6];
    float q1 = expf(tmp[tid+256]-hm[(tid+256)>>6]) / hs[(tid+256)>>6];
    qs[tid] = q0; qs[tid+256] = q1;
    qout[(size_t)b*HID+tid] = q0; qout[(size_t)b*HID+tid+256] = q1;
  }
  __syncthreads();

  // ---- init branch: init_proj -> h0 -> k0,v0 -> y_init ----
  if (tid < 128) xls[tid] = initial[(size_t)b*128 + tid];
  __syncthreads();
  if (tid < 64) ip[tid] = bi[tid] + dot_ld4(Wi + (size_t)tid*128, xls, 128/4);
  __syncthreads();
  h0 = bip[tid]     + dot_ld4(Wip + (size_t)tid*CIN,       ip, CIN/4);
  h1 = bip[tid+256] + dot_ld4(Wip + (size_t)(tid+256)*CIN, ip, CIN/4);
  ln_stats(h0, h1, red, ms, tid);
  hln[tid]     = (h0-ms[0])*ms[1]*g_in[tid]     + b_in[tid];
  hln[tid+256] = (h1-ms[0])*ms[1]*g_in[tid+256] + b_in[tid+256];
  __syncthreads();
  tmp[tid]     = bk[tid]     + dot_ld4(Wk + (size_t)tid*HID,       hln, HID/4);
  tmp[tid+256] = bk[tid+256] + dot_ld4(Wk + (size_t)(tid+256)*HID, hln, HID/4);
  v0s[tid]     = bv[tid]     + dot_ld4(Wv + (size_t)tid*HID,       hln, HID/4);
  v0s[tid+256] = bv[tid+256] + dot_ld4(Wv + (size_t)(tid+256)*HID, hln, HID/4);
  __syncthreads();
  if (tid < 8){
    float m = -1e30f; for (int e=0;e<64;e++) m = fmaxf(m, tmp[tid*64+e]);
    float s = 0.f;    for (int e=0;e<64;e++) s += expf(tmp[tid*64+e]-m);
    float a = 0.f;
    for (int e=0;e<64;e++) a += (expf(tmp[tid*64+e]-m)/s) * qs[tid*64+e];
    sal[tid] = a;
  }
  __syncthreads();
  yinit[(size_t)b*HID+tid]     = sal[tid>>6]       * v0s[tid];
  yinit[(size_t)b*HID+tid+256] = sal[(tid+256)>>6] * v0s[tid+256];
}

// ---------------- kernel A: Hln = LN(logsig @ Wip.T + bip) -> bf16 ----------------
__global__ __launch_bounds__(512) void k_hln(
    const float* __restrict__ logsig,
    const float* __restrict__ Wip, const float* __restrict__ bip,
    const float* __restrict__ g_in, const float* __restrict__ b_in,
    __hip_bfloat16* __restrict__ Hln)
{
  int b = blockIdx.x, tc = blockIdx.y, tid = threadIdx.x;
  __shared__ __align__(16) float xs[64][64];
  __shared__ float red[16]; __shared__ float ms[2];
  float w[64];
  {
    const float4* wr = (const float4*)(Wip + (size_t)tid*CIN);
    #pragma unroll
    for (int k=0;k<16;k++){ float4 t = wr[k]; w[4*k]=t.x; w[4*k+1]=t.y; w[4*k+2]=t.z; w[4*k+3]=t.w; }
  }
  float bj = bip[tid], gj = g_in[tid], bbj = b_in[tid];
  const float4* src = (const float4*)(logsig + ((size_t)b*T_ + tc*64)*CIN);
  for (int i = tid; i < 1024; i += 512){
    float4 t = src[i];
    int r = i>>4, c = (i&15)*4;
    xs[r][c]=t.x; xs[r][c+1]=t.y; xs[r][c+2]=t.z; xs[r][c+3]=t.w;
  }
  __syncthreads();
  int lane = tid & 63, wid = tid >> 6;
  for (int r = 0; r < 64; r++){
    float acc = bj;
    #pragma unroll
    for (int k4 = 0; k4 < 16; k4++){
      float4 xv = *(const float4*)&xs[r][k4*4];
      acc += w[4*k4]*xv.x + w[4*k4+1]*xv.y + w[4*k4+2]*xv.z + w[4*k4+3]*xv.w;
    }
    float s = acc, s2 = acc*acc;
    #pragma unroll
    for (int o = 32; o; o >>= 1){ s += __shfl_xor(s,o); s2 += __shfl_xor(s2,o); }
    if (lane == 0){ red[wid] = s; red[8+wid] = s2; }
    __syncthreads();
    if (tid == 0){
      float S=0.f, S2=0.f;
      #pragma unroll
      for (int i=0;i<8;i++){ S += red[i]; S2 += red[8+i]; }
      float m = S*(1.f/512.f), var = S2*(1.f/512.f) - m*m;
      ms[0] = m; ms[1] = rsqrtf(var + 1e-5f);
    }
    __syncthreads();
    float o = (acc - ms[0]) * ms[1] * gj + bbj;
    Hln[((size_t)b*T_ + tc*64 + r)*HID + tid] = __float2bfloat16(o);
    __syncthreads();
  }
}

// ---------------- kernel B: MFMA score GEMM + fused softmax + (k.q) -> alpha ----------------
// Block: (b, tc). 512 threads = 8 waves; wave w = head w. M=64 t-rows, N=64 cols, K=512.
__global__ __launch_bounds__(512) void k_score(
    const __hip_bfloat16* __restrict__ Hln,   // (B*T, 512) bf16
    const __hip_bfloat16* __restrict__ Wkb,   // (512, 512) bf16
    const float* __restrict__ bk,
    const float* __restrict__ qws,            // (B, 512)
    float* __restrict__ alpha)                // (B*T, 8)
{
  int b = blockIdx.x, tc = blockIdx.y;
  int tid = threadIdx.x;
  int w  = tid >> 6;        // wave = head
  int l  = tid & 63;
  int lr = l & 15;          // row (A) / col (B,D) within fragment
  int lg = l >> 4;          // k-block (A,B) / row-group (D)

  const __hip_bfloat16* Abase = Hln + ((size_t)b*T_ + tc*64)*HID;
  const __hip_bfloat16* Bbase = Wkb + (size_t)(w*64)*HID;

  f32x4 acc[4][4];
  #pragma unroll
  for (int i=0;i<4;i++)
    #pragma unroll
    for (int j=0;j<4;j++) acc[i][j] = (f32x4){0.f,0.f,0.f,0.f};

  for (int kk = 0; kk < HID; kk += 32){
    bf16x8 af[4], bfr[4];
    #pragma unroll
    for (int i=0;i<4;i++)
      af[i] = *(const bf16x8*)(Abase + (size_t)(i*16 + lr)*HID + kk + lg*8);
    #pragma unroll
    for (int j=0;j<4;j++)
      bfr[j] = *(const bf16x8*)(Bbase + (size_t)(j*16 + lr)*HID + kk + lg*8);
    #pragma unroll
    for (int i=0;i<4;i++)
      #pragma unroll
      for (int j=0;j<4;j++)
        acc[i][j] = __builtin_amdgcn_mfma_f32_16x16x32_bf16(af[i], bfr[j], acc[i][j], 0,0,0);
  }

  // epilogue: per row t, softmax over the 64 head-cols, dot with q, weight w_t
  float bkv[4], qv[4];
  #pragma unroll
  for (int j=0;j<4;j++){
    bkv[j] = bk[w*64 + j*16 + lr];
    qv[j]  = qws[(size_t)b*HID + w*64 + j*16 + lr];
  }
  #pragma unroll
  for (int i=0;i<4;i++){
    #pragma unroll
    for (int r=0;r<4;r++){
      float v0 = acc[i][0][r]+bkv[0], v1 = acc[i][1][r]+bkv[1];
      float v2 = acc[i][2][r]+bkv[2], v3 = acc[i][3][r]+bkv[3];
      float mx = fmaxf(fmaxf(v0,v1),fmaxf(v2,v3));
      #pragma unroll
      for (int o=1;o<16;o<<=1) mx = fmaxf(mx, __shfl_xor(mx,o));
      float e0=__expf(v0-mx), e1=__expf(v1-mx), e2=__expf(v2-mx), e3=__expf(v3-mx);
      float se = e0+e1+e2+e3;
      float sq = e0*qv[0]+e1*qv[1]+e2*qv[2]+e3*qv[3];
      #pragma unroll
      for (int o=1;o<16;o<<=1){ se += __shfl_xor(se,o); sq += __shfl_xor(sq,o); }
      if (lr == 0){
        int t = tc*64 + i*16 + lg*4 + r;
        float wt = (t == 0) ? (5.f/6.f) : ((t == T_-1) ? (1.f/6.f) : 1.f);
        alpha[((size_t)b*T_ + t)*NH + w] = wt * sq / se;
      }
    }
  }
}

// ---------------- kernel B2: u[b,h,:] = sum_t alpha * Hln; Asum = sum_t alpha ----------------
__global__ __launch_bounds__(256) void k_u(
    const __hip_bfloat16* __restrict__ Hln,
    const float* __restrict__ alpha,
    float* __restrict__ u, float* __restrict__ Asum)
{
  int b = blockIdx.x, tid = threadIdx.x;
  __shared__ float als[T_*NH];
  for (int i = tid; i < T_*NH; i += 256) als[i] = alpha[(size_t)b*T_*NH + i];
  __syncthreads();
  float uacc[8][2];
  #pragma unroll
  for (int h=0;h<8;h++){ uacc[h][0]=0.f; uacc[h][1]=0.f; }
  const unsigned* hb = (const unsigned*)(Hln + (size_t)b*T_*HID);
  for (int t = 0; t < T_; t++){
    unsigned xv = hb[(size_t)t*256 + tid];
    float x0 = bf2f(xv & 0xffffu), x1 = bf2f(xv >> 16);
    #pragma unroll
    for (int h=0;h<8;h++){
      float a = als[t*8+h];
      uacc[h][0] += a*x0; uacc[h][1] += a*x1;
    }
  }
  #pragma unroll
  for (int h=0;h<8;h++){
    u[((size_t)b*NH+h)*HID + 2*tid]   = uacc[h][0];
    u[((size_t)b*NH+h)*HID + 2*tid+1] = uacc[h][1];
  }
  if (tid < 8){
    float s = 0.f;
    for (int t=0;t<T_;t++) s += als[t*8+tid];
    Asum[(size_t)b*NH + tid] = s;
  }
}

// ---------------- kernel C: y from u, Wo, LN, FF, residual, final ----------------
__global__ __launch_bounds__(256) void k_head(
    const float* __restrict__ yinit, const float* __restrict__ u,
    const float* __restrict__ Asum,
    const float* __restrict__ Wv, const float* __restrict__ bv,
    const float* __restrict__ Wo, const float* __restrict__ bo,
    const float* __restrict__ g_ff, const float* __restrict__ b_ff,
    const float* __restrict__ W1, const float* __restrict__ b1,
    const float* __restrict__ W2, const float* __restrict__ b2,
    const float* __restrict__ Wf, const float* __restrict__ bf,
    float* __restrict__ out)
{
  int b = blockIdx.x, tid = threadIdx.x;
  __shared__ __align__(16) float us[NH*HID];   // 16 KB
  __shared__ __align__(16) float y[512];
  __shared__ __align__(16) float yo[512];
  __shared__ __align__(16) float a1[FFD];
  __shared__ float red[8]; __shared__ float ms[2];
  __shared__ float Ab[8];
  for (int i = tid; i < NH*HID; i += 256) us[i] = u[(size_t)b*NH*HID + i];
  if (tid < 8) Ab[tid] = Asum[(size_t)b*NH + tid];
  __syncthreads();
  #pragma unroll
  for (int u2=0; u2<2; u2++){
    int jj = tid + u2*256;
    y[jj] = yinit[(size_t)b*HID + jj] + bv[jj]*Ab[jj>>6]
          + dot_ld4(Wv + (size_t)jj*HID, us + (jj>>6)*HID, HID/4);
  }
  __syncthreads();
  float o0 = bo[tid]     + dot_ld4(Wo + (size_t)tid*HID,       y, HID/4);
  float o1 = bo[tid+256] + dot_ld4(Wo + (size_t)(tid+256)*HID, y, HID/4);
  ln_stats(o0, o1, red, ms, tid);
  yo[tid] = o0; yo[tid+256] = o1;
  y[tid]     = (o0-ms[0])*ms[1]*g_ff[tid]     + b_ff[tid];
  y[tid+256] = (o1-ms[0])*ms[1]*g_ff[tid+256] + b_ff[tid+256];
  __syncthreads();
  for (int f = tid; f < FFD; f += 256){
    float a = b1[f] + dot_ld4(W1 + (size_t)f*HID, y, HID/4);
    a1[f] = fmaxf(a, 0.f);
  }
  __syncthreads();
  float f0 = yo[tid]     + b2[tid]     + dot_ld4(W2 + (size_t)tid*FFD,       a1, FFD/4);
  float f1 = yo[tid+256] + b2[tid+256] + dot_ld4(W2 + (size_t)(tid+256)*FFD, a1, FFD/4);
  __syncthreads();
  y[tid] = f0; y[tid+256] = f1;
  __syncthreads();
  if (tid < OUTD){
    out[(size_t)b*OUTD + tid] = bf[tid] + dot_ld4(Wf + (size_t)tid*HID, y, HID/4);
  }
}

extern "C" void kernel_launch(void* const* d_in, const int* in_sizes, int n_in,
                              void* d_out, int out_size, void* d_ws, size_t ws_size,
                              hipStream_t stream)
{
  const float* initial = (const float*)d_in[0];
  const float* logsig  = (const float*)d_in[1];
  const float* Wi  = (const float*)d_in[2];  const float* bi  = (const float*)d_in[3];
  const float* Wip = (const float*)d_in[4];  const float* bip = (const float*)d_in[5];
  const float* g_in= (const float*)d_in[6];  const float* b_in= (const float*)d_in[7];
  const float* Wk  = (const float*)d_in[8];  const float* bk  = (const float*)d_in[9];
  const float* Wv  = (const float*)d_in[10]; const float* bv  = (const float*)d_in[11];
  const float* Wq  = (const float*)d_in[12]; const float* bq  = (const float*)d_in[13];
  const float* Wo  = (const float*)d_in[14]; const float* bo  = (const float*)d_in[15];
  const float* g_ff= (const float*)d_in[16]; const float* b_ff= (const float*)d_in[17];
  const float* W1  = (const float*)d_in[18]; const float* b1  = (const float*)d_in[19];
  const float* W2  = (const float*)d_in[20]; const float* b2  = (const float*)d_in[21];
  const float* Wf  = (const float*)d_in[22]; const float* bf  = (const float*)d_in[23];
  float* out = (float*)d_out;

  char* ws = (char*)d_ws;
  float* qws   = (float*)(ws);                           // 512 KB
  float* yinit = (float*)(ws + (512<<10));               // 512 KB
  float* alpha = (float*)(ws + (1<<20));                 // 2 MB
  float* u     = (float*)(ws + (3<<20));                 // 4 MB
  float* Asum  = (float*)(ws + (7<<20));                 // 8 KB
  __hip_bfloat16* Wkb = (__hip_bfloat16*)(ws + (8<<20)); // 512 KB
  __hip_bfloat16* Hln = (__hip_bfloat16*)(ws + (9<<20)); // 64 MB

  k_prep<<<dim3((HID*HID)/256), 256, 0, stream>>>(Wk, Wkb);
  k_init<<<B_, 256, 0, stream>>>(initial, logsig, Wi, bi, Wip, bip, g_in, b_in,
                                 Wk, bk, Wv, bv, Wq, bq, qws, yinit);
  k_hln<<<dim3(B_, 4), 512, 0, stream>>>(logsig, Wip, bip, g_in, b_in, Hln);
  k_score<<<dim3(B_, 4), 512, 0, stream>>>(Hln, Wkb, bk, qws, alpha);
  k_u<<<B_, 256, 0, stream>>>(Hln, alpha, u, Asum);
  k_head<<<B_, 256, 0, stream>>>(yinit, u, Asum, Wv, bv, Wo, bo, g_ff, b_ff,
                                 W1, b1, W2, b2, Wf, bf, out);
}

// Round 4
// 587.372 us; speedup vs baseline: 2.3078x; 1.2454x over previous
//
#include <hip/hip_runtime.h>
#include <hip/hip_bf16.h>
#include <math.h>

#define B_ 256
#define T_ 256
#define CIN 64
#define HID 512
#define NH 8
#define HD 64
#define FFD 2048
#define OUTD 10

typedef __bf16 bf16x8 __attribute__((ext_vector_type(8)));
typedef float f32x4 __attribute__((ext_vector_type(4)));

__device__ __forceinline__ float bf2f(unsigned u){
  union { unsigned i; float f; } c; c.i = u << 16; return c.f;
}

// LN stats over 512 values held as (v0 at tid, v1 at tid+256), 256 threads.
__device__ __forceinline__ void ln_stats(float v0, float v1, float* red, float* ms, int tid){
  float s = v0 + v1, s2 = v0*v0 + v1*v1;
  #pragma unroll
  for (int o = 32; o; o >>= 1){ s += __shfl_xor(s, o); s2 += __shfl_xor(s2, o); }
  int lane = tid & 63, wid = tid >> 6;
  if (lane == 0){ red[wid] = s; red[4+wid] = s2; }
  __syncthreads();
  if (tid == 0){
    float S = red[0]+red[1]+red[2]+red[3];
    float S2 = red[4]+red[5]+red[6]+red[7];
    float m = S * (1.f/512.f);
    float var = S2 * (1.f/512.f) - m*m;
    ms[0] = m; ms[1] = rsqrtf(var + 1e-5f);
  }
  __syncthreads();
}

__device__ __forceinline__ float dot_ld4(const float* __restrict__ w, const float* x, int n4){
  float acc = 0.f;
  const float4* w4 = (const float4*)w;
  const float4* x4 = (const float4*)x;
  for (int k = 0; k < n4; k++){
    float4 a = w4[k], b = x4[k];
    acc += a.x*b.x + a.y*b.y + a.z*b.z + a.w*b.w;
  }
  return acc;
}

// ---------------- prep: f32 -> bf16 ----------------
__global__ __launch_bounds__(256) void k_cvt(const float* __restrict__ src,
                                             __hip_bfloat16* __restrict__ dst){
  int i = blockIdx.x*256 + threadIdx.x;
  dst[i] = __float2bfloat16(src[i]);
}

// ---------------- kernel 1: q (B,512) and y_init = (k0.q) v0 ----------------
__global__ __launch_bounds__(256) void k_init(
    const float* __restrict__ initial, const float* __restrict__ logsig,
    const float* __restrict__ Wi, const float* __restrict__ bi,
    const float* __restrict__ Wip, const float* __restrict__ bip,
    const float* __restrict__ g_in, const float* __restrict__ b_in,
    const float* __restrict__ Wk, const float* __restrict__ bk,
    const float* __restrict__ Wv, const float* __restrict__ bv,
    const float* __restrict__ Wq, const float* __restrict__ bq,
    float* __restrict__ qout, float* __restrict__ yinit)
{
  int b = blockIdx.x, tid = threadIdx.x;
  __shared__ __align__(16) float xls[128];
  __shared__ __align__(16) float hln[512];
  __shared__ __align__(16) float tmp[512];
  __shared__ __align__(16) float v0s[512];
  __shared__ __align__(16) float qs[512];
  __shared__ __align__(16) float ip[64];
  __shared__ float red[8]; __shared__ float ms[2];
  __shared__ float hm[8], hs[8], sal[8];

  // ---- hq from last logsig row -> q ----
  if (tid < 64) xls[tid] = logsig[((size_t)b*T_ + (T_-1))*CIN + tid];
  __syncthreads();
  float h0 = bip[tid]     + dot_ld4(Wip + (size_t)tid*CIN,       xls, CIN/4);
  float h1 = bip[tid+256] + dot_ld4(Wip + (size_t)(tid+256)*CIN, xls, CIN/4);
  ln_stats(h0, h1, red, ms, tid);
  hln[tid]     = (h0-ms[0])*ms[1]*g_in[tid]     + b_in[tid];
  hln[tid+256] = (h1-ms[0])*ms[1]*g_in[tid+256] + b_in[tid+256];
  __syncthreads();
  tmp[tid]     = bq[tid]     + dot_ld4(Wq + (size_t)tid*HID,       hln, HID/4);
  tmp[tid+256] = bq[tid+256] + dot_ld4(Wq + (size_t)(tid+256)*HID, hln, HID/4);
  __syncthreads();
  if (tid < 8){
    float m = -1e30f; for (int e=0;e<64;e++) m = fmaxf(m, tmp[tid*64+e]);
    float s = 0.f;    for (int e=0;e<64;e++) s += expf(tmp[tid*64+e]-m);
    hm[tid] = m; hs[tid] = s;
  }
  __syncthreads();
  {
    float q0 = expf(tmp[tid]-hm[tid>>6]) / hs[tid>>6];
    float q1 = expf(tmp[tid+256]-hm[(tid+256)>>6]) / hs[(tid+256)>>6];
    qs[tid] = q0; qs[tid+256] = q1;
    qout[(size_t)b*HID+tid] = q0; qout[(size_t)b*HID+tid+256] = q1;
  }
  __syncthreads();

  // ---- init branch: init_proj -> h0 -> k0,v0 -> y_init ----
  if (tid < 128) xls[tid] = initial[(size_t)b*128 + tid];
  __syncthreads();
  if (tid < 64) ip[tid] = bi[tid] + dot_ld4(Wi + (size_t)tid*128, xls, 128/4);
  __syncthreads();
  h0 = bip[tid]     + dot_ld4(Wip + (size_t)tid*CIN,       ip, CIN/4);
  h1 = bip[tid+256] + dot_ld4(Wip + (size_t)(tid+256)*CIN, ip, CIN/4);
  ln_stats(h0, h1, red, ms, tid);
  hln[tid]     = (h0-ms[0])*ms[1]*g_in[tid]     + b_in[tid];
  hln[tid+256] = (h1-ms[0])*ms[1]*g_in[tid+256] + b_in[tid+256];
  __syncthreads();
  tmp[tid]     = bk[tid]     + dot_ld4(Wk + (size_t)tid*HID,       hln, HID/4);
  tmp[tid+256] = bk[tid+256] + dot_ld4(Wk + (size_t)(tid+256)*HID, hln, HID/4);
  v0s[tid]     = bv[tid]     + dot_ld4(Wv + (size_t)tid*HID,       hln, HID/4);
  v0s[tid+256] = bv[tid+256] + dot_ld4(Wv + (size_t)(tid+256)*HID, hln, HID/4);
  __syncthreads();
  if (tid < 8){
    float m = -1e30f; for (int e=0;e<64;e++) m = fmaxf(m, tmp[tid*64+e]);
    float s = 0.f;    for (int e=0;e<64;e++) s += expf(tmp[tid*64+e]-m);
    float a = 0.f;
    for (int e=0;e<64;e++) a += (expf(tmp[tid*64+e]-m)/s) * qs[tid*64+e];
    sal[tid] = a;
  }
  __syncthreads();
  yinit[(size_t)b*HID+tid]     = sal[tid>>6]       * v0s[tid];
  yinit[(size_t)b*HID+tid+256] = sal[(tid+256)>>6] * v0s[tid+256];
}

// ---------------- kernel A: Hln = LN(logsig @ Wip.T + bip) -> bf16 ----------------
__global__ __launch_bounds__(512) void k_hln(
    const float* __restrict__ logsig,
    const float* __restrict__ Wip, const float* __restrict__ bip,
    const float* __restrict__ g_in, const float* __restrict__ b_in,
    __hip_bfloat16* __restrict__ Hln)
{
  int b = blockIdx.x, tc = blockIdx.y, tid = threadIdx.x;
  __shared__ __align__(16) float xs[64][64];
  __shared__ float red[16]; __shared__ float ms[2];
  float w[64];
  {
    const float4* wr = (const float4*)(Wip + (size_t)tid*CIN);
    #pragma unroll
    for (int k=0;k<16;k++){ float4 t = wr[k]; w[4*k]=t.x; w[4*k+1]=t.y; w[4*k+2]=t.z; w[4*k+3]=t.w; }
  }
  float bj = bip[tid], gj = g_in[tid], bbj = b_in[tid];
  const float4* src = (const float4*)(logsig + ((size_t)b*T_ + tc*64)*CIN);
  for (int i = tid; i < 1024; i += 512){
    float4 t = src[i];
    int r = i>>4, c = (i&15)*4;
    xs[r][c]=t.x; xs[r][c+1]=t.y; xs[r][c+2]=t.z; xs[r][c+3]=t.w;
  }
  __syncthreads();
  int lane = tid & 63, wid = tid >> 6;
  for (int r = 0; r < 64; r++){
    float acc = bj;
    #pragma unroll
    for (int k4 = 0; k4 < 16; k4++){
      float4 xv = *(const float4*)&xs[r][k4*4];
      acc += w[4*k4]*xv.x + w[4*k4+1]*xv.y + w[4*k4+2]*xv.z + w[4*k4+3]*xv.w;
    }
    float s = acc, s2 = acc*acc;
    #pragma unroll
    for (int o = 32; o; o >>= 1){ s += __shfl_xor(s,o); s2 += __shfl_xor(s2,o); }
    if (lane == 0){ red[wid] = s; red[8+wid] = s2; }
    __syncthreads();
    if (tid == 0){
      float S=0.f, S2=0.f;
      #pragma unroll
      for (int i=0;i<8;i++){ S += red[i]; S2 += red[8+i]; }
      float m = S*(1.f/512.f), var = S2*(1.f/512.f) - m*m;
      ms[0] = m; ms[1] = rsqrtf(var + 1e-5f);
    }
    __syncthreads();
    float o = (acc - ms[0]) * ms[1] * gj + bbj;
    Hln[((size_t)b*T_ + tc*64 + r)*HID + tid] = __float2bfloat16(o);
    __syncthreads();
  }
}

// ---------------- kernel B: MFMA score GEMM + fused softmax + (k.q) -> alpha ----------------
__global__ __launch_bounds__(512) void k_score(
    const __hip_bfloat16* __restrict__ Hln,   // (B*T, 512) bf16
    const __hip_bfloat16* __restrict__ Wkb,   // (512, 512) bf16
    const float* __restrict__ bk,
    const float* __restrict__ qws,            // (B, 512)
    float* __restrict__ alpha)                // (B*T, 8)
{
  int b = blockIdx.x, tc = blockIdx.y;
  int tid = threadIdx.x;
  int w  = tid >> 6;        // wave = head
  int l  = tid & 63;
  int lr = l & 15;
  int lg = l >> 4;

  const __hip_bfloat16* Abase = Hln + ((size_t)b*T_ + tc*64)*HID;
  const __hip_bfloat16* Bbase = Wkb + (size_t)(w*64)*HID;

  f32x4 acc[4][4];
  #pragma unroll
  for (int i=0;i<4;i++)
    #pragma unroll
    for (int j=0;j<4;j++) acc[i][j] = (f32x4){0.f,0.f,0.f,0.f};

  for (int kk = 0; kk < HID; kk += 32){
    bf16x8 af[4], bfr[4];
    #pragma unroll
    for (int i=0;i<4;i++)
      af[i] = *(const bf16x8*)(Abase + (size_t)(i*16 + lr)*HID + kk + lg*8);
    #pragma unroll
    for (int j=0;j<4;j++)
      bfr[j] = *(const bf16x8*)(Bbase + (size_t)(j*16 + lr)*HID + kk + lg*8);
    #pragma unroll
    for (int i=0;i<4;i++)
      #pragma unroll
      for (int j=0;j<4;j++)
        acc[i][j] = __builtin_amdgcn_mfma_f32_16x16x32_bf16(af[i], bfr[j], acc[i][j], 0,0,0);
  }

  float bkv[4], qv[4];
  #pragma unroll
  for (int j=0;j<4;j++){
    bkv[j] = bk[w*64 + j*16 + lr];
    qv[j]  = qws[(size_t)b*HID + w*64 + j*16 + lr];
  }
  #pragma unroll
  for (int i=0;i<4;i++){
    #pragma unroll
    for (int r=0;r<4;r++){
      float v0 = acc[i][0][r]+bkv[0], v1 = acc[i][1][r]+bkv[1];
      float v2 = acc[i][2][r]+bkv[2], v3 = acc[i][3][r]+bkv[3];
      float mx = fmaxf(fmaxf(v0,v1),fmaxf(v2,v3));
      #pragma unroll
      for (int o=1;o<16;o<<=1) mx = fmaxf(mx, __shfl_xor(mx,o));
      float e0=__expf(v0-mx), e1=__expf(v1-mx), e2=__expf(v2-mx), e3=__expf(v3-mx);
      float se = e0+e1+e2+e3;
      float sq = e0*qv[0]+e1*qv[1]+e2*qv[2]+e3*qv[3];
      #pragma unroll
      for (int o=1;o<16;o<<=1){ se += __shfl_xor(se,o); sq += __shfl_xor(sq,o); }
      if (lr == 0){
        int t = tc*64 + i*16 + lg*4 + r;
        float wt = (t == 0) ? (5.f/6.f) : ((t == T_-1) ? (1.f/6.f) : 1.f);
        alpha[((size_t)b*T_ + t)*NH + w] = wt * sq / se;
      }
    }
  }
}

// ---------------- kernel B2: u_bf[b,h,:] = sum_t alpha * Hln (bf16); Asum ----------------
__global__ __launch_bounds__(256) void k_u(
    const __hip_bfloat16* __restrict__ Hln,
    const float* __restrict__ alpha,
    __hip_bfloat16* __restrict__ u_bf, float* __restrict__ Asum)
{
  int b = blockIdx.x, tid = threadIdx.x;
  __shared__ float als[T_*NH];
  for (int i = tid; i < T_*NH; i += 256) als[i] = alpha[(size_t)b*T_*NH + i];
  __syncthreads();
  float uacc[8][2];
  #pragma unroll
  for (int h=0;h<8;h++){ uacc[h][0]=0.f; uacc[h][1]=0.f; }
  const unsigned* hb = (const unsigned*)(Hln + (size_t)b*T_*HID);
  for (int t = 0; t < T_; t++){
    unsigned xv = hb[(size_t)t*256 + tid];
    float x0 = bf2f(xv & 0xffffu), x1 = bf2f(xv >> 16);
    #pragma unroll
    for (int h=0;h<8;h++){
      float a = als[t*8+h];
      uacc[h][0] += a*x0; uacc[h][1] += a*x1;
    }
  }
  unsigned* ub = (unsigned*)u_bf;
  #pragma unroll
  for (int h=0;h<8;h++){
    unsigned p0 = ((unsigned)__bfloat16_as_ushort(__float2bfloat16(uacc[h][0])));
    unsigned p1 = ((unsigned)__bfloat16_as_ushort(__float2bfloat16(uacc[h][1])));
    ub[(((size_t)b*NH+h)*HID >> 1) + tid] = p0 | (p1 << 16);
  }
  if (tid < 8){
    float s = 0.f;
    for (int t=0;t<T_;t++) s += als[t*8+tid];
    Asum[(size_t)b*NH + tid] = s;
  }
}

// ---------------- kernel C1: yh = u @ Wv_h^T + yinit + bv*Asum -> bf16 ----------------
__global__ __launch_bounds__(256) void k_yhead(
    const __hip_bfloat16* __restrict__ u_bf,   // (B,8,512)
    const __hip_bfloat16* __restrict__ Wvb,    // (512,512)
    const float* __restrict__ bv, const float* __restrict__ Asum,
    const float* __restrict__ yinit,
    __hip_bfloat16* __restrict__ yh)           // (B,512) bf16
{
  int mb = blockIdx.x, h = blockIdx.y;
  int tid = threadIdx.x;
  int w = tid >> 6, l = tid & 63, lr = l & 15, lg = l >> 4;
  int row0 = mb*64 + w*16;
  const __hip_bfloat16* Abase = u_bf + ((size_t)(row0 + lr)*NH + h)*HID;
  const __hip_bfloat16* Bbase = Wvb + (size_t)(h*64)*HID;
  f32x4 acc[4];
  #pragma unroll
  for (int j=0;j<4;j++) acc[j] = (f32x4){0.f,0.f,0.f,0.f};
  for (int kk = 0; kk < HID; kk += 32){
    bf16x8 af = *(const bf16x8*)(Abase + kk + lg*8);
    #pragma unroll
    for (int j=0;j<4;j++){
      bf16x8 bfr = *(const bf16x8*)(Bbase + (size_t)(j*16 + lr)*HID + kk + lg*8);
      acc[j] = __builtin_amdgcn_mfma_f32_16x16x32_bf16(af, bfr, acc[j], 0,0,0);
    }
  }
  #pragma unroll
  for (int j=0;j<4;j++){
    int col = h*64 + j*16 + lr;
    float bvc = bv[col];
    #pragma unroll
    for (int r=0;r<4;r++){
      int row = row0 + lg*4 + r;
      float v = acc[j][r] + yinit[(size_t)row*HID + col] + bvc*Asum[(size_t)row*NH + h];
      yh[(size_t)row*HID + col] = __float2bfloat16(v);
    }
  }
}

// ---------------- kernel C1b: yo = yh @ Wo^T + bo (f32 out) ----------------
__global__ __launch_bounds__(256) void k_yo(
    const __hip_bfloat16* __restrict__ yh,   // (B,512)
    const __hip_bfloat16* __restrict__ Wob,  // (512,512)
    const float* __restrict__ bo,
    float* __restrict__ yo)                  // (B,512)
{
  int mb = blockIdx.x, nb = blockIdx.y;
  int tid = threadIdx.x;
  int w = tid >> 6, l = tid & 63, lr = l & 15, lg = l >> 4;
  int row0 = mb*64 + w*16;
  const __hip_bfloat16* Abase = yh + (size_t)(row0 + lr)*HID;
  const __hip_bfloat16* Bbase = Wob + (size_t)(nb*64)*HID;
  f32x4 acc[4];
  #pragma unroll
  for (int j=0;j<4;j++) acc[j] = (f32x4){0.f,0.f,0.f,0.f};
  for (int kk = 0; kk < HID; kk += 32){
    bf16x8 af = *(const bf16x8*)(Abase + kk + lg*8);
    #pragma unroll
    for (int j=0;j<4;j++){
      bf16x8 bfr = *(const bf16x8*)(Bbase + (size_t)(j*16 + lr)*HID + kk + lg*8);
      acc[j] = __builtin_amdgcn_mfma_f32_16x16x32_bf16(af, bfr, acc[j], 0,0,0);
    }
  }
  #pragma unroll
  for (int j=0;j<4;j++){
    int col = nb*64 + j*16 + lr;
    float bc = bo[col];
    #pragma unroll
    for (int r=0;r<4;r++){
      int row = row0 + lg*4 + r;
      yo[(size_t)row*HID + col] = acc[j][r] + bc;
    }
  }
}

// ---------------- kernel C2: row LN of yo -> yln bf16 ----------------
__global__ __launch_bounds__(256) void k_ln2(
    const float* __restrict__ yo,
    const float* __restrict__ g_ff, const float* __restrict__ b_ff,
    __hip_bfloat16* __restrict__ yln)
{
  int tid = threadIdx.x;
  int row = blockIdx.x*32 + (tid >> 3), sub = tid & 7;
  const float4* yr = (const float4*)(yo + (size_t)row*HID) + sub*16;
  float4 v[16];
  float s = 0.f, s2 = 0.f;
  #pragma unroll
  for (int k=0;k<16;k++){
    v[k] = yr[k];
    s  += v[k].x+v[k].y+v[k].z+v[k].w;
    s2 += v[k].x*v[k].x+v[k].y*v[k].y+v[k].z*v[k].z+v[k].w*v[k].w;
  }
  #pragma unroll
  for (int o=1;o<8;o<<=1){ s += __shfl_xor(s,o); s2 += __shfl_xor(s2,o); }
  float m = s*(1.f/512.f), rs = rsqrtf(s2*(1.f/512.f) - m*m + 1e-5f);
  #pragma unroll
  for (int k=0;k<16;k++){
    int c = sub*64 + k*4;
    float o0 = (v[k].x-m)*rs*g_ff[c]   + b_ff[c];
    float o1 = (v[k].y-m)*rs*g_ff[c+1] + b_ff[c+1];
    float o2 = (v[k].z-m)*rs*g_ff[c+2] + b_ff[c+2];
    float o3 = (v[k].w-m)*rs*g_ff[c+3] + b_ff[c+3];
    yln[(size_t)row*HID + c]   = __float2bfloat16(o0);
    yln[(size_t)row*HID + c+1] = __float2bfloat16(o1);
    yln[(size_t)row*HID + c+2] = __float2bfloat16(o2);
    yln[(size_t)row*HID + c+3] = __float2bfloat16(o3);
  }
}

// ---------------- kernel C3: a1 = relu(yln @ W1^T + b1) bf16 ----------------
__global__ __launch_bounds__(256) void k_ff1(
    const __hip_bfloat16* __restrict__ yln,  // (B,512)
    const __hip_bfloat16* __restrict__ W1b,  // (2048,512)
    const float* __restrict__ b1,
    __hip_bfloat16* __restrict__ a1b)        // (B,2048)
{
  int mb = blockIdx.x, nb = blockIdx.y;
  int tid = threadIdx.x;
  int w = tid >> 6, l = tid & 63, lr = l & 15, lg = l >> 4;
  int row0 = mb*64 + w*16;
  const __hip_bfloat16* Abase = yln + (size_t)(row0 + lr)*HID;
  const __hip_bfloat16* Bbase = W1b + (size_t)(nb*64)*HID;
  f32x4 acc[4];
  #pragma unroll
  for (int j=0;j<4;j++) acc[j] = (f32x4){0.f,0.f,0.f,0.f};
  for (int kk = 0; kk < HID; kk += 32){
    bf16x8 af = *(const bf16x8*)(Abase + kk + lg*8);
    #pragma unroll
    for (int j=0;j<4;j++){
      bf16x8 bfr = *(const bf16x8*)(Bbase + (size_t)(j*16 + lr)*HID + kk + lg*8);
      acc[j] = __builtin_amdgcn_mfma_f32_16x16x32_bf16(af, bfr, acc[j], 0,0,0);
    }
  }
  #pragma unroll
  for (int j=0;j<4;j++){
    int col = nb*64 + j*16 + lr;
    float bc = b1[col];
    #pragma unroll
    for (int r=0;r<4;r++){
      int row = row0 + lg*4 + r;
      a1b[(size_t)row*FFD + col] = __float2bfloat16(fmaxf(acc[j][r] + bc, 0.f));
    }
  }
}

// ---------------- kernel C4: y2 = a1 @ W2^T + b2 + yo ----------------
__global__ __launch_bounds__(256) void k_ff2(
    const __hip_bfloat16* __restrict__ a1b,  // (B,2048)
    const __hip_bfloat16* __restrict__ W2b,  // (512,2048)
    const float* __restrict__ b2,
    const float* __restrict__ yo,
    float* __restrict__ y2)                  // (B,512)
{
  int mb = blockIdx.x, nb = blockIdx.y;
  int tid = threadIdx.x;
  int w = tid >> 6, l = tid & 63, lr = l & 15, lg = l >> 4;
  int row0 = mb*64 + w*16;
  const __hip_bfloat16* Abase = a1b + (size_t)(row0 + lr)*FFD;
  const __hip_bfloat16* Bbase = W2b + (size_t)(nb*64)*FFD;
  f32x4 acc[4];
  #pragma unroll
  for (int j=0;j<4;j++) acc[j] = (f32x4){0.f,0.f,0.f,0.f};
  for (int kk = 0; kk < FFD; kk += 32){
    bf16x8 af = *(const bf16x8*)(Abase + kk + lg*8);
    #pragma unroll
    for (int j=0;j<4;j++){
      bf16x8 bfr = *(const bf16x8*)(Bbase + (size_t)(j*16 + lr)*FFD + kk + lg*8);
      acc[j] = __builtin_amdgcn_mfma_f32_16x16x32_bf16(af, bfr, acc[j], 0,0,0);
    }
  }
  #pragma unroll
  for (int j=0;j<4;j++){
    int col = nb*64 + j*16 + lr;
    float bc = b2[col];
    #pragma unroll
    for (int r=0;r<4;r++){
      int row = row0 + lg*4 + r;
      y2[(size_t)row*HID + col] = acc[j][r] + bc + yo[(size_t)row*HID + col];
    }
  }
}

// ---------------- kernel C5: out = y2 @ Wf^T + bf ----------------
__global__ __launch_bounds__(256) void k_final(
    const float* __restrict__ y2,
    const float* __restrict__ Wf, const float* __restrict__ bfv,
    float* __restrict__ out)
{
  int tid = threadIdx.x;
  int b0 = blockIdx.x*64;
  for (int i = tid; i < 64*OUTD; i += 256){
    int r = b0 + i/OUTD, c = i%OUTD;
    out[(size_t)r*OUTD + c] = bfv[c] + dot_ld4(Wf + (size_t)c*HID, y2 + (size_t)r*HID, HID/4);
  }
}

extern "C" void kernel_launch(void* const* d_in, const int* in_sizes, int n_in,
                              void* d_out, int out_size, void* d_ws, size_t ws_size,
                              hipStream_t stream)
{
  const float* initial = (const float*)d_in[0];
  const float* logsig  = (const float*)d_in[1];
  const float* Wi  = (const float*)d_in[2];  const float* bi  = (const float*)d_in[3];
  const float* Wip = (const float*)d_in[4];  const float* bip = (const float*)d_in[5];
  const float* g_in= (const float*)d_in[6];  const float* b_in= (const float*)d_in[7];
  const float* Wk  = (const float*)d_in[8];  const float* bk  = (const float*)d_in[9];
  const float* Wv  = (const float*)d_in[10]; const float* bv  = (const float*)d_in[11];
  const float* Wq  = (const float*)d_in[12]; const float* bq  = (const float*)d_in[13];
  const float* Wo  = (const float*)d_in[14]; const float* bo  = (const float*)d_in[15];
  const float* g_ff= (const float*)d_in[16]; const float* b_ff= (const float*)d_in[17];
  const float* W1  = (const float*)d_in[18]; const float* b1  = (const float*)d_in[19];
  const float* W2  = (const float*)d_in[20]; const float* b2  = (const float*)d_in[21];
  const float* Wf  = (const float*)d_in[22]; const float* bf  = (const float*)d_in[23];
  float* out = (float*)d_out;

  char* ws = (char*)d_ws;
  const size_t MB = 1<<20;
  float* qws   = (float*)(ws);                             // 512 KB
  float* yinit = (float*)(ws + 512*1024);                  // 512 KB
  float* alpha = (float*)(ws + 1*MB);                      // 2 MB
  __hip_bfloat16* u_bf = (__hip_bfloat16*)(ws + 3*MB);     // 2 MB
  float* Asum  = (float*)(ws + 5*MB);                      // 8 KB
  __hip_bfloat16* Wkb = (__hip_bfloat16*)(ws + 5*MB + 512*1024);  // 512 KB
  __hip_bfloat16* Wvb = (__hip_bfloat16*)(ws + 6*MB);      // 512 KB
  __hip_bfloat16* W1b = (__hip_bfloat16*)(ws + 6*MB + 512*1024);  // 2 MB
  __hip_bfloat16* W2b = (__hip_bfloat16*)(ws + 8*MB + 512*1024);  // 2 MB
  float* y2    = (float*)(ws + 10*MB + 512*1024);          // 512 KB
  __hip_bfloat16* yln = (__hip_bfloat16*)(ws + 11*MB);     // 256 KB
  __hip_bfloat16* a1b = (__hip_bfloat16*)(ws + 11*MB + 512*1024); // 1 MB
  __hip_bfloat16* Wob = (__hip_bfloat16*)(ws + 13*MB);     // 512 KB
  __hip_bfloat16* yh  = (__hip_bfloat16*)(ws + 13*MB + 512*1024); // 256 KB
  float* yo    = (float*)(ws + 14*MB);                     // 512 KB
  __hip_bfloat16* Hln = (__hip_bfloat16*)(ws + 16*MB);     // 64 MB

  k_cvt<<<dim3((HID*HID)/256), 256, 0, stream>>>(Wk, Wkb);
  k_cvt<<<dim3((HID*HID)/256), 256, 0, stream>>>(Wv, Wvb);
  k_cvt<<<dim3((HID*HID)/256), 256, 0, stream>>>(Wo, Wob);
  k_cvt<<<dim3((FFD*HID)/256), 256, 0, stream>>>(W1, W1b);
  k_cvt<<<dim3((HID*FFD)/256), 256, 0, stream>>>(W2, W2b);
  k_init<<<B_, 256, 0, stream>>>(initial, logsig, Wi, bi, Wip, bip, g_in, b_in,
                                 Wk, bk, Wv, bv, Wq, bq, qws, yinit);
  k_hln<<<dim3(B_, 4), 512, 0, stream>>>(logsig, Wip, bip, g_in, b_in, Hln);
  k_score<<<dim3(B_, 4), 512, 0, stream>>>(Hln, Wkb, bk, qws, alpha);
  k_u<<<B_, 256, 0, stream>>>(Hln, alpha, u_bf, Asum);
  k_yhead<<<dim3(B_/64, NH), 256, 0, stream>>>(u_bf, Wvb, bv, Asum, yinit, yh);
  k_yo<<<dim3(B_/64, HID/64), 256, 0, stream>>>(yh, Wob, bo, yo);
  k_ln2<<<dim3(B_/32), 256, 0, stream>>>(yo, g_ff, b_ff, yln);
  k_ff1<<<dim3(B_/64, FFD/64), 256, 0, stream>>>(yln, W1b, b1, a1b);
  k_ff2<<<dim3(B_/64, HID/64), 256, 0, stream>>>(a1b, W2b, b2, yo, y2);
  k_final<<<dim3(B_/64), 256, 0, stream>>>(y2, Wf, bf, out);
}

// Round 5
// 458.540 us; speedup vs baseline: 2.9562x; 1.2810x over previous
//
#include <hip/hip_runtime.h>
#include <hip/hip_bf16.h>
#include <math.h>

#define B_ 256
#define T_ 256
#define CIN 64
#define HID 512
#define NH 8
#define HD 64
#define FFD 2048
#define OUTD 10

typedef __bf16 bf16x8 __attribute__((ext_vector_type(8)));
typedef float f32x4 __attribute__((ext_vector_type(4)));

__device__ __forceinline__ float bf2f(unsigned u){
  union { unsigned i; float f; } c; c.i = u << 16; return c.f;
}
__device__ __forceinline__ unsigned pk2(float a, float b){
  return ((unsigned)__bfloat16_as_ushort(__float2bfloat16(a))) |
         (((unsigned)__bfloat16_as_ushort(__float2bfloat16(b))) << 16);
}

// LN stats over 512 values held as (v0 at tid, v1 at tid+256), 256 threads.
__device__ __forceinline__ void ln_stats(float v0, float v1, float* red, float* ms, int tid){
  float s = v0 + v1, s2 = v0*v0 + v1*v1;
  #pragma unroll
  for (int o = 32; o; o >>= 1){ s += __shfl_xor(s, o); s2 += __shfl_xor(s2, o); }
  int lane = tid & 63, wid = tid >> 6;
  if (lane == 0){ red[wid] = s; red[4+wid] = s2; }
  __syncthreads();
  if (tid == 0){
    float S = red[0]+red[1]+red[2]+red[3];
    float S2 = red[4]+red[5]+red[6]+red[7];
    float m = S * (1.f/512.f);
    float var = S2 * (1.f/512.f) - m*m;
    ms[0] = m; ms[1] = rsqrtf(var + 1e-5f);
  }
  __syncthreads();
}

__device__ __forceinline__ float dot_ld4(const float* __restrict__ w, const float* x, int n4){
  float acc = 0.f;
  const float4* w4 = (const float4*)w;
  const float4* x4 = (const float4*)x;
  for (int k = 0; k < n4; k++){
    float4 a = w4[k], b = x4[k];
    acc += a.x*b.x + a.y*b.y + a.z*b.z + a.w*b.w;
  }
  return acc;
}

// ---------------- prep: f32 -> bf16 ----------------
__global__ __launch_bounds__(256) void k_cvt(const float* __restrict__ src,
                                             __hip_bfloat16* __restrict__ dst){
  int i = blockIdx.x*256 + threadIdx.x;
  dst[i] = __float2bfloat16(src[i]);
}

// ---------------- kernel 1: q (B,512) and y_init = (k0.q) v0 ----------------
__global__ __launch_bounds__(256) void k_init(
    const float* __restrict__ initial, const float* __restrict__ logsig,
    const float* __restrict__ Wi, const float* __restrict__ bi,
    const float* __restrict__ Wip, const float* __restrict__ bip,
    const float* __restrict__ g_in, const float* __restrict__ b_in,
    const float* __restrict__ Wk, const float* __restrict__ bk,
    const float* __restrict__ Wv, const float* __restrict__ bv,
    const float* __restrict__ Wq, const float* __restrict__ bq,
    float* __restrict__ qout, float* __restrict__ yinit)
{
  int b = blockIdx.x, tid = threadIdx.x;
  __shared__ __align__(16) float xls[128];
  __shared__ __align__(16) float hln[512];
  __shared__ __align__(16) float tmp[512];
  __shared__ __align__(16) float v0s[512];
  __shared__ __align__(16) float qs[512];
  __shared__ __align__(16) float ip[64];
  __shared__ float red[8]; __shared__ float ms[2];
  __shared__ float hm[8], hs[8], sal[8];

  // ---- hq from last logsig row -> q ----
  if (tid < 64) xls[tid] = logsig[((size_t)b*T_ + (T_-1))*CIN + tid];
  __syncthreads();
  float h0 = bip[tid]     + dot_ld4(Wip + (size_t)tid*CIN,       xls, CIN/4);
  float h1 = bip[tid+256] + dot_ld4(Wip + (size_t)(tid+256)*CIN, xls, CIN/4);
  ln_stats(h0, h1, red, ms, tid);
  hln[tid]     = (h0-ms[0])*ms[1]*g_in[tid]     + b_in[tid];
  hln[tid+256] = (h1-ms[0])*ms[1]*g_in[tid+256] + b_in[tid+256];
  __syncthreads();
  tmp[tid]     = bq[tid]     + dot_ld4(Wq + (size_t)tid*HID,       hln, HID/4);
  tmp[tid+256] = bq[tid+256] + dot_ld4(Wq + (size_t)(tid+256)*HID, hln, HID/4);
  __syncthreads();
  if (tid < 8){
    float m = -1e30f; for (int e=0;e<64;e++) m = fmaxf(m, tmp[tid*64+e]);
    float s = 0.f;    for (int e=0;e<64;e++) s += expf(tmp[tid*64+e]-m);
    hm[tid] = m; hs[tid] = s;
  }
  __syncthreads();
  {
    float q0 = expf(tmp[tid]-hm[tid>>6]) / hs[tid>>6];
    float q1 = expf(tmp[tid+256]-hm[(tid+256)>>6]) / hs[(tid+256)>>6];
    qs[tid] = q0; qs[tid+256] = q1;
    qout[(size_t)b*HID+tid] = q0; qout[(size_t)b*HID+tid+256] = q1;
  }
  __syncthreads();

  // ---- init branch: init_proj -> h0 -> k0,v0 -> y_init ----
  if (tid < 128) xls[tid] = initial[(size_t)b*128 + tid];
  __syncthreads();
  if (tid < 64) ip[tid] = bi[tid] + dot_ld4(Wi + (size_t)tid*128, xls, 128/4);
  __syncthreads();
  h0 = bip[tid]     + dot_ld4(Wip + (size_t)tid*CIN,       ip, CIN/4);
  h1 = bip[tid+256] + dot_ld4(Wip + (size_t)(tid+256)*CIN, ip, CIN/4);
  ln_stats(h0, h1, red, ms, tid);
  hln[tid]     = (h0-ms[0])*ms[1]*g_in[tid]     + b_in[tid];
  hln[tid+256] = (h1-ms[0])*ms[1]*g_in[tid+256] + b_in[tid+256];
  __syncthreads();
  tmp[tid]     = bk[tid]     + dot_ld4(Wk + (size_t)tid*HID,       hln, HID/4);
  tmp[tid+256] = bk[tid+256] + dot_ld4(Wk + (size_t)(tid+256)*HID, hln, HID/4);
  v0s[tid]     = bv[tid]     + dot_ld4(Wv + (size_t)tid*HID,       hln, HID/4);
  v0s[tid+256] = bv[tid+256] + dot_ld4(Wv + (size_t)(tid+256)*HID, hln, HID/4);
  __syncthreads();
  if (tid < 8){
    float m = -1e30f; for (int e=0;e<64;e++) m = fmaxf(m, tmp[tid*64+e]);
    float s = 0.f;    for (int e=0;e<64;e++) s += expf(tmp[tid*64+e]-m);
    float a = 0.f;
    for (int e=0;e<64;e++) a += (expf(tmp[tid*64+e]-m)/s) * qs[tid*64+e];
    sal[tid] = a;
  }
  __syncthreads();
  yinit[(size_t)b*HID+tid]     = sal[tid>>6]       * v0s[tid];
  yinit[(size_t)b*HID+tid+256] = sal[(tid+256)>>6] * v0s[tid+256];
}

// ---------------- kernel A: Hln = LN(logsig @ Wip.T + bip) -> bf16  (MFMA) ----------------
// Block: 64 rows of (B*T). 512 threads = 8 waves; wave w owns output cols w*64..w*64+63.
__global__ __launch_bounds__(512) void k_hln(
    const float* __restrict__ logsig,
    const __hip_bfloat16* __restrict__ Wipb,   // (512,64) bf16
    const float* __restrict__ bip,
    const float* __restrict__ g_in, const float* __restrict__ b_in,
    __hip_bfloat16* __restrict__ Hln)
{
  int blk = blockIdx.x;
  int tid = threadIdx.x;
  int w = tid >> 6, l = tid & 63, lr = l & 15, lg = l >> 4;
  __shared__ __align__(16) __hip_bfloat16 xs[64][88];   // padded: 176B row stride
  __shared__ float red[64][8][2];
  __shared__ float ms2[64][2];

  // stage + convert x tile (64 rows x 64) f32 -> bf16; thread t handles 8 elems
  {
    const float* srow = logsig + (size_t)blk*64*CIN + (size_t)(tid>>3)*CIN + (tid&7)*8;
    float4 a = *(const float4*)(srow);
    float4 b = *(const float4*)(srow+4);
    uint4 p = { pk2(a.x,a.y), pk2(a.z,a.w), pk2(b.x,b.y), pk2(b.z,b.w) };
    *(uint4*)(&xs[tid>>3][(tid&7)*8]) = p;
  }
  __syncthreads();

  f32x4 acc[4][4];
  #pragma unroll
  for (int i=0;i<4;i++)
    #pragma unroll
    for (int j=0;j<4;j++) acc[i][j] = (f32x4){0.f,0.f,0.f,0.f};

  #pragma unroll
  for (int kk = 0; kk < CIN; kk += 32){
    bf16x8 af[4], bfr[4];
    #pragma unroll
    for (int i=0;i<4;i++)
      af[i] = *(const bf16x8*)(&xs[i*16 + lr][kk + lg*8]);
    #pragma unroll
    for (int j=0;j<4;j++)
      bfr[j] = *(const bf16x8*)(Wipb + (size_t)(w*64 + j*16 + lr)*CIN + kk + lg*8);
    #pragma unroll
    for (int i=0;i<4;i++)
      #pragma unroll
      for (int j=0;j<4;j++)
        acc[i][j] = __builtin_amdgcn_mfma_f32_16x16x32_bf16(af[i], bfr[j], acc[i][j], 0,0,0);
  }

  float bipv[4], gv[4], bbv[4];
  #pragma unroll
  for (int j=0;j<4;j++){
    int col = w*64 + j*16 + lr;
    bipv[j] = bip[col]; gv[j] = g_in[col]; bbv[j] = b_in[col];
  }
  // per-row stats: lane partial over 4 cols, reduce over 16-lane group, cross-wave via LDS
  #pragma unroll
  for (int i=0;i<4;i++){
    #pragma unroll
    for (int r=0;r<4;r++){
      float s = 0.f, s2 = 0.f;
      #pragma unroll
      for (int j=0;j<4;j++){ float v = acc[i][j][r] + bipv[j]; s += v; s2 += v*v; }
      #pragma unroll
      for (int o=1;o<16;o<<=1){ s += __shfl_xor(s,o); s2 += __shfl_xor(s2,o); }
      if (lr == 0){ int row = i*16 + lg*4 + r; red[row][w][0] = s; red[row][w][1] = s2; }
    }
  }
  __syncthreads();
  if (tid < 64){
    float S = 0.f, S2 = 0.f;
    #pragma unroll
    for (int k=0;k<8;k++){ S += red[tid][k][0]; S2 += red[tid][k][1]; }
    float m = S*(1.f/512.f), var = S2*(1.f/512.f) - m*m;
    ms2[tid][0] = m; ms2[tid][1] = rsqrtf(var + 1e-5f);
  }
  __syncthreads();
  #pragma unroll
  for (int i=0;i<4;i++){
    #pragma unroll
    for (int r=0;r<4;r++){
      int row = i*16 + lg*4 + r;
      float m = ms2[row][0], rs = ms2[row][1];
      size_t base = ((size_t)blk*64 + row)*HID;
      #pragma unroll
      for (int j=0;j<4;j++){
        int col = w*64 + j*16 + lr;
        float v = acc[i][j][r] + bipv[j];
        Hln[base + col] = __float2bfloat16((v - m)*rs*gv[j] + bbv[j]);
      }
    }
  }
}

// ---------------- kernel B: MFMA score GEMM + fused softmax + (k.q) -> alpha ----------------
__global__ __launch_bounds__(512) void k_score(
    const __hip_bfloat16* __restrict__ Hln,   // (B*T, 512) bf16
    const __hip_bfloat16* __restrict__ Wkb,   // (512, 512) bf16
    const float* __restrict__ bk,
    const float* __restrict__ qws,            // (B, 512)
    float* __restrict__ alpha)                // (B*T, 8)
{
  int b = blockIdx.x, tc = blockIdx.y;
  int tid = threadIdx.x;
  int w  = tid >> 6;        // wave = head
  int l  = tid & 63;
  int lr = l & 15;
  int lg = l >> 4;

  const __hip_bfloat16* Abase = Hln + ((size_t)b*T_ + tc*64)*HID;
  const __hip_bfloat16* Bbase = Wkb + (size_t)(w*64)*HID;

  f32x4 acc[4][4];
  #pragma unroll
  for (int i=0;i<4;i++)
    #pragma unroll
    for (int j=0;j<4;j++) acc[i][j] = (f32x4){0.f,0.f,0.f,0.f};

  for (int kk = 0; kk < HID; kk += 32){
    bf16x8 af[4], bfr[4];
    #pragma unroll
    for (int i=0;i<4;i++)
      af[i] = *(const bf16x8*)(Abase + (size_t)(i*16 + lr)*HID + kk + lg*8);
    #pragma unroll
    for (int j=0;j<4;j++)
      bfr[j] = *(const bf16x8*)(Bbase + (size_t)(j*16 + lr)*HID + kk + lg*8);
    #pragma unroll
    for (int i=0;i<4;i++)
      #pragma unroll
      for (int j=0;j<4;j++)
        acc[i][j] = __builtin_amdgcn_mfma_f32_16x16x32_bf16(af[i], bfr[j], acc[i][j], 0,0,0);
  }

  float bkv[4], qv[4];
  #pragma unroll
  for (int j=0;j<4;j++){
    bkv[j] = bk[w*64 + j*16 + lr];
    qv[j]  = qws[(size_t)b*HID + w*64 + j*16 + lr];
  }
  #pragma unroll
  for (int i=0;i<4;i++){
    #pragma unroll
    for (int r=0;r<4;r++){
      float v0 = acc[i][0][r]+bkv[0], v1 = acc[i][1][r]+bkv[1];
      float v2 = acc[i][2][r]+bkv[2], v3 = acc[i][3][r]+bkv[3];
      float mx = fmaxf(fmaxf(v0,v1),fmaxf(v2,v3));
      #pragma unroll
      for (int o=1;o<16;o<<=1) mx = fmaxf(mx, __shfl_xor(mx,o));
      float e0=__expf(v0-mx), e1=__expf(v1-mx), e2=__expf(v2-mx), e3=__expf(v3-mx);
      float se = e0+e1+e2+e3;
      float sq = e0*qv[0]+e1*qv[1]+e2*qv[2]+e3*qv[3];
      #pragma unroll
      for (int o=1;o<16;o<<=1){ se += __shfl_xor(se,o); sq += __shfl_xor(sq,o); }
      if (lr == 0){
        int t = tc*64 + i*16 + lg*4 + r;
        float wt = (t == 0) ? (5.f/6.f) : ((t == T_-1) ? (1.f/6.f) : 1.f);
        alpha[((size_t)b*T_ + t)*NH + w] = wt * sq / se;
      }
    }
  }
}

// ---------------- kernel B2: u_bf[b,h,:] = sum_t alpha * Hln (bf16); Asum ----------------
__global__ __launch_bounds__(256) void k_u(
    const __hip_bfloat16* __restrict__ Hln,
    const float* __restrict__ alpha,
    __hip_bfloat16* __restrict__ u_bf, float* __restrict__ Asum)
{
  int b = blockIdx.x, tid = threadIdx.x;
  __shared__ float als[T_*NH];
  for (int i = tid; i < T_*NH; i += 256) als[i] = alpha[(size_t)b*T_*NH + i];
  __syncthreads();
  float uacc[8][2];
  #pragma unroll
  for (int h=0;h<8;h++){ uacc[h][0]=0.f; uacc[h][1]=0.f; }
  const unsigned* hb = (const unsigned*)(Hln + (size_t)b*T_*HID);
  for (int t = 0; t < T_; t++){
    unsigned xv = hb[(size_t)t*256 + tid];
    float x0 = bf2f(xv & 0xffffu), x1 = bf2f(xv >> 16);
    #pragma unroll
    for (int h=0;h<8;h++){
      float a = als[t*8+h];
      uacc[h][0] += a*x0; uacc[h][1] += a*x1;
    }
  }
  unsigned* ub = (unsigned*)u_bf;
  #pragma unroll
  for (int h=0;h<8;h++){
    unsigned p0 = ((unsigned)__bfloat16_as_ushort(__float2bfloat16(uacc[h][0])));
    unsigned p1 = ((unsigned)__bfloat16_as_ushort(__float2bfloat16(uacc[h][1])));
    ub[(((size_t)b*NH+h)*HID >> 1) + tid] = p0 | (p1 << 16);
  }
  if (tid < 8){
    float s = 0.f;
    for (int t=0;t<T_;t++) s += als[t*8+tid];
    Asum[(size_t)b*NH + tid] = s;
  }
}

// ---------------- kernel C1: yh = u @ Wv_h^T + yinit + bv*Asum -> bf16 ----------------
__global__ __launch_bounds__(256) void k_yhead(
    const __hip_bfloat16* __restrict__ u_bf,   // (B,8,512)
    const __hip_bfloat16* __restrict__ Wvb,    // (512,512)
    const float* __restrict__ bv, const float* __restrict__ Asum,
    const float* __restrict__ yinit,
    __hip_bfloat16* __restrict__ yh)           // (B,512) bf16
{
  int mb = blockIdx.x, h = blockIdx.y;
  int tid = threadIdx.x;
  int w = tid >> 6, l = tid & 63, lr = l & 15, lg = l >> 4;
  int row0 = mb*64 + w*16;
  const __hip_bfloat16* Abase = u_bf + ((size_t)(row0 + lr)*NH + h)*HID;
  const __hip_bfloat16* Bbase = Wvb + (size_t)(h*64)*HID;
  f32x4 acc[4];
  #pragma unroll
  for (int j=0;j<4;j++) acc[j] = (f32x4){0.f,0.f,0.f,0.f};
  for (int kk = 0; kk < HID; kk += 32){
    bf16x8 af = *(const bf16x8*)(Abase + kk + lg*8);
    #pragma unroll
    for (int j=0;j<4;j++){
      bf16x8 bfr = *(const bf16x8*)(Bbase + (size_t)(j*16 + lr)*HID + kk + lg*8);
      acc[j] = __builtin_amdgcn_mfma_f32_16x16x32_bf16(af, bfr, acc[j], 0,0,0);
    }
  }
  #pragma unroll
  for (int j=0;j<4;j++){
    int col = h*64 + j*16 + lr;
    float bvc = bv[col];
    #pragma unroll
    for (int r=0;r<4;r++){
      int row = row0 + lg*4 + r;
      float v = acc[j][r] + yinit[(size_t)row*HID + col] + bvc*Asum[(size_t)row*NH + h];
      yh[(size_t)row*HID + col] = __float2bfloat16(v);
    }
  }
}

// ---------------- kernel C1b: yo = yh @ Wo^T + bo (f32 out) ----------------
__global__ __launch_bounds__(256) void k_yo(
    const __hip_bfloat16* __restrict__ yh,   // (B,512)
    const __hip_bfloat16* __restrict__ Wob,  // (512,512)
    const float* __restrict__ bo,
    float* __restrict__ yo)                  // (B,512)
{
  int mb = blockIdx.x, nb = blockIdx.y;
  int tid = threadIdx.x;
  int w = tid >> 6, l = tid & 63, lr = l & 15, lg = l >> 4;
  int row0 = mb*64 + w*16;
  const __hip_bfloat16* Abase = yh + (size_t)(row0 + lr)*HID;
  const __hip_bfloat16* Bbase = Wob + (size_t)(nb*64)*HID;
  f32x4 acc[4];
  #pragma unroll
  for (int j=0;j<4;j++) acc[j] = (f32x4){0.f,0.f,0.f,0.f};
  for (int kk = 0; kk < HID; kk += 32){
    bf16x8 af = *(const bf16x8*)(Abase + kk + lg*8);
    #pragma unroll
    for (int j=0;j<4;j++){
      bf16x8 bfr = *(const bf16x8*)(Bbase + (size_t)(j*16 + lr)*HID + kk + lg*8);
      acc[j] = __builtin_amdgcn_mfma_f32_16x16x32_bf16(af, bfr, acc[j], 0,0,0);
    }
  }
  #pragma unroll
  for (int j=0;j<4;j++){
    int col = nb*64 + j*16 + lr;
    float bc = bo[col];
    #pragma unroll
    for (int r=0;r<4;r++){
      int row = row0 + lg*4 + r;
      yo[(size_t)row*HID + col] = acc[j][r] + bc;
    }
  }
}

// ---------------- kernel C2: row LN of yo -> yln bf16 ----------------
__global__ __launch_bounds__(256) void k_ln2(
    const float* __restrict__ yo,
    const float* __restrict__ g_ff, const float* __restrict__ b_ff,
    __hip_bfloat16* __restrict__ yln)
{
  int tid = threadIdx.x;
  int row = blockIdx.x*32 + (tid >> 3), sub = tid & 7;
  const float4* yr = (const float4*)(yo + (size_t)row*HID) + sub*16;
  float4 v[16];
  float s = 0.f, s2 = 0.f;
  #pragma unroll
  for (int k=0;k<16;k++){
    v[k] = yr[k];
    s  += v[k].x+v[k].y+v[k].z+v[k].w;
    s2 += v[k].x*v[k].x+v[k].y*v[k].y+v[k].z*v[k].z+v[k].w*v[k].w;
  }
  #pragma unroll
  for (int o=1;o<8;o<<=1){ s += __shfl_xor(s,o); s2 += __shfl_xor(s2,o); }
  float m = s*(1.f/512.f), rs = rsqrtf(s2*(1.f/512.f) - m*m + 1e-5f);
  #pragma unroll
  for (int k=0;k<16;k++){
    int c = sub*64 + k*4;
    float o0 = (v[k].x-m)*rs*g_ff[c]   + b_ff[c];
    float o1 = (v[k].y-m)*rs*g_ff[c+1] + b_ff[c+1];
    float o2 = (v[k].z-m)*rs*g_ff[c+2] + b_ff[c+2];
    float o3 = (v[k].w-m)*rs*g_ff[c+3] + b_ff[c+3];
    yln[(size_t)row*HID + c]   = __float2bfloat16(o0);
    yln[(size_t)row*HID + c+1] = __float2bfloat16(o1);
    yln[(size_t)row*HID + c+2] = __float2bfloat16(o2);
    yln[(size_t)row*HID + c+3] = __float2bfloat16(o3);
  }
}

// ---------------- kernel C3: a1 = relu(yln @ W1^T + b1) bf16 ----------------
__global__ __launch_bounds__(256) void k_ff1(
    const __hip_bfloat16* __restrict__ yln,  // (B,512)
    const __hip_bfloat16* __restrict__ W1b,  // (2048,512)
    const float* __restrict__ b1,
    __hip_bfloat16* __restrict__ a1b)        // (B,2048)
{
  int mb = blockIdx.x, nb = blockIdx.y;
  int tid = threadIdx.x;
  int w = tid >> 6, l = tid & 63, lr = l & 15, lg = l >> 4;
  int row0 = mb*64 + w*16;
  const __hip_bfloat16* Abase = yln + (size_t)(row0 + lr)*HID;
  const __hip_bfloat16* Bbase = W1b + (size_t)(nb*64)*HID;
  f32x4 acc[4];
  #pragma unroll
  for (int j=0;j<4;j++) acc[j] = (f32x4){0.f,0.f,0.f,0.f};
  for (int kk = 0; kk < HID; kk += 32){
    bf16x8 af = *(const bf16x8*)(Abase + kk + lg*8);
    #pragma unroll
    for (int j=0;j<4;j++){
      bf16x8 bfr = *(const bf16x8*)(Bbase + (size_t)(j*16 + lr)*HID + kk + lg*8);
      acc[j] = __builtin_amdgcn_mfma_f32_16x16x32_bf16(af, bfr, acc[j], 0,0,0);
    }
  }
  #pragma unroll
  for (int j=0;j<4;j++){
    int col = nb*64 + j*16 + lr;
    float bc = b1[col];
    #pragma unroll
    for (int r=0;r<4;r++){
      int row = row0 + lg*4 + r;
      a1b[(size_t)row*FFD + col] = __float2bfloat16(fmaxf(acc[j][r] + bc, 0.f));
    }
  }
}

// ---------------- kernel C4: y2 = a1 @ W2^T + b2 + yo ----------------
__global__ __launch_bounds__(256) void k_ff2(
    const __hip_bfloat16* __restrict__ a1b,  // (B,2048)
    const __hip_bfloat16* __restrict__ W2b,  // (512,2048)
    const float* __restrict__ b2,
    const float* __restrict__ yo,
    float* __restrict__ y2)                  // (B,512)
{
  int mb = blockIdx.x, nb = blockIdx.y;
  int tid = threadIdx.x;
  int w = tid >> 6, l = tid & 63, lr = l & 15, lg = l >> 4;
  int row0 = mb*64 + w*16;
  const __hip_bfloat16* Abase = a1b + (size_t)(row0 + lr)*FFD;
  const __hip_bfloat16* Bbase = W2b + (size_t)(nb*64)*FFD;
  f32x4 acc[4];
  #pragma unroll
  for (int j=0;j<4;j++) acc[j] = (f32x4){0.f,0.f,0.f,0.f};
  for (int kk = 0; kk < FFD; kk += 32){
    bf16x8 af = *(const bf16x8*)(Abase + kk + lg*8);
    #pragma unroll
    for (int j=0;j<4;j++){
      bf16x8 bfr = *(const bf16x8*)(Bbase + (size_t)(j*16 + lr)*FFD + kk + lg*8);
      acc[j] = __builtin_amdgcn_mfma_f32_16x16x32_bf16(af, bfr, acc[j], 0,0,0);
    }
  }
  #pragma unroll
  for (int j=0;j<4;j++){
    int col = nb*64 + j*16 + lr;
    float bc = b2[col];
    #pragma unroll
    for (int r=0;r<4;r++){
      int row = row0 + lg*4 + r;
      y2[(size_t)row*HID + col] = acc[j][r] + bc + yo[(size_t)row*HID + col];
    }
  }
}

// ---------------- kernel C5: out = y2 @ Wf^T + bf ----------------
__global__ __launch_bounds__(256) void k_final(
    const float* __restrict__ y2,
    const float* __restrict__ Wf, const float* __restrict__ bfv,
    float* __restrict__ out)
{
  int tid = threadIdx.x;
  int b0 = blockIdx.x*64;
  for (int i = tid; i < 64*OUTD; i += 256){
    int r = b0 + i/OUTD, c = i%OUTD;
    out[(size_t)r*OUTD + c] = bfv[c] + dot_ld4(Wf + (size_t)c*HID, y2 + (size_t)r*HID, HID/4);
  }
}

extern "C" void kernel_launch(void* const* d_in, const int* in_sizes, int n_in,
                              void* d_out, int out_size, void* d_ws, size_t ws_size,
                              hipStream_t stream)
{
  const float* initial = (const float*)d_in[0];
  const float* logsig  = (const float*)d_in[1];
  const float* Wi  = (const float*)d_in[2];  const float* bi  = (const float*)d_in[3];
  const float* Wip = (const float*)d_in[4];  const float* bip = (const float*)d_in[5];
  const float* g_in= (const float*)d_in[6];  const float* b_in= (const float*)d_in[7];
  const float* Wk  = (const float*)d_in[8];  const float* bk  = (const float*)d_in[9];
  const float* Wv  = (const float*)d_in[10]; const float* bv  = (const float*)d_in[11];
  const float* Wq  = (const float*)d_in[12]; const float* bq  = (const float*)d_in[13];
  const float* Wo  = (const float*)d_in[14]; const float* bo  = (const float*)d_in[15];
  const float* g_ff= (const float*)d_in[16]; const float* b_ff= (const float*)d_in[17];
  const float* W1  = (const float*)d_in[18]; const float* b1  = (const float*)d_in[19];
  const float* W2  = (const float*)d_in[20]; const float* b2  = (const float*)d_in[21];
  const float* Wf  = (const float*)d_in[22]; const float* bf  = (const float*)d_in[23];
  float* out = (float*)d_out;

  char* ws = (char*)d_ws;
  const size_t MB = 1<<20;
  float* qws   = (float*)(ws);                             // 512 KB
  float* yinit = (float*)(ws + 512*1024);                  // 512 KB
  float* alpha = (float*)(ws + 1*MB);                      // 2 MB
  __hip_bfloat16* u_bf = (__hip_bfloat16*)(ws + 3*MB);     // 2 MB
  float* Asum  = (float*)(ws + 5*MB);                      // 8 KB
  __hip_bfloat16* Wkb = (__hip_bfloat16*)(ws + 5*MB + 512*1024);  // 512 KB
  __hip_bfloat16* Wvb = (__hip_bfloat16*)(ws + 6*MB);      // 512 KB
  __hip_bfloat16* W1b = (__hip_bfloat16*)(ws + 6*MB + 512*1024);  // 2 MB
  __hip_bfloat16* W2b = (__hip_bfloat16*)(ws + 8*MB + 512*1024);  // 2 MB
  float* y2    = (float*)(ws + 10*MB + 512*1024);          // 512 KB
  __hip_bfloat16* yln = (__hip_bfloat16*)(ws + 11*MB);     // 256 KB
  __hip_bfloat16* a1b = (__hip_bfloat16*)(ws + 11*MB + 512*1024); // 1 MB
  __hip_bfloat16* Wob = (__hip_bfloat16*)(ws + 13*MB);     // 512 KB
  __hip_bfloat16* yh  = (__hip_bfloat16*)(ws + 13*MB + 512*1024); // 256 KB
  float* yo    = (float*)(ws + 14*MB);                     // 512 KB
  __hip_bfloat16* Wipb = (__hip_bfloat16*)(ws + 15*MB);    // 64 KB
  __hip_bfloat16* Hln = (__hip_bfloat16*)(ws + 16*MB);     // 64 MB

  k_cvt<<<dim3((HID*HID)/256), 256, 0, stream>>>(Wk, Wkb);
  k_cvt<<<dim3((HID*HID)/256), 256, 0, stream>>>(Wv, Wvb);
  k_cvt<<<dim3((HID*HID)/256), 256, 0, stream>>>(Wo, Wob);
  k_cvt<<<dim3((FFD*HID)/256), 256, 0, stream>>>(W1, W1b);
  k_cvt<<<dim3((HID*FFD)/256), 256, 0, stream>>>(W2, W2b);
  k_cvt<<<dim3((HID*CIN)/256), 256, 0, stream>>>(Wip, Wipb);
  k_init<<<B_, 256, 0, stream>>>(initial, logsig, Wi, bi, Wip, bip, g_in, b_in,
                                 Wk, bk, Wv, bv, Wq, bq, qws, yinit);
  k_hln<<<dim3((B_*T_)/64), 512, 0, stream>>>(logsig, Wipb, bip, g_in, b_in, Hln);
  k_score<<<dim3(B_, 4), 512, 0, stream>>>(Hln, Wkb, bk, qws, alpha);
  k_u<<<B_, 256, 0, stream>>>(Hln, alpha, u_bf, Asum);
  k_yhead<<<dim3(B_/64, NH), 256, 0, stream>>>(u_bf, Wvb, bv, Asum, yinit, yh);
  k_yo<<<dim3(B_/64, HID/64), 256, 0, stream>>>(yh, Wob, bo, yo);
  k_ln2<<<dim3(B_/32), 256, 0, stream>>>(yo, g_ff, b_ff, yln);
  k_ff1<<<dim3(B_/64, FFD/64), 256, 0, stream>>>(yln, W1b, b1, a1b);
  k_ff2<<<dim3(B_/64, HID/64), 256, 0, stream>>>(a1b, W2b, b2, yo, y2);
  k_final<<<dim3(B_/64), 256, 0, stream>>>(y2, Wf, bf, out);
}

// Round 6
// 379.069 us; speedup vs baseline: 3.5760x; 1.2096x over previous
//
#include <hip/hip_runtime.h>
#include <hip/hip_bf16.h>
#include <math.h>

#define B_ 256
#define T_ 256
#define CIN 64
#define HID 512
#define NH 8
#define HD 64
#define FFD 2048
#define OUTD 10

typedef __bf16 bf16x8 __attribute__((ext_vector_type(8)));
typedef float f32x4 __attribute__((ext_vector_type(4)));

// swizzled LDS byte offset for the 64x512 bf16 Hs tile (row stride 1024B)
#define HSOFF(r,c) (((r)<<10) + ((((c)<<1)) ^ ((((r)&7))<<4)))

__device__ __forceinline__ float bf2f(unsigned u){
  union { unsigned i; float f; } c; c.i = u << 16; return c.f;
}
__device__ __forceinline__ unsigned pk2(float a, float b){
  return ((unsigned)__bfloat16_as_ushort(__float2bfloat16(a))) |
         (((unsigned)__bfloat16_as_ushort(__float2bfloat16(b))) << 16);
}

// LN stats over 512 values held as (v0 at tid, v1 at tid+256), 256 threads.
__device__ __forceinline__ void ln_stats(float v0, float v1, float* red, float* ms, int tid){
  float s = v0 + v1, s2 = v0*v0 + v1*v1;
  #pragma unroll
  for (int o = 32; o; o >>= 1){ s += __shfl_xor(s, o); s2 += __shfl_xor(s2, o); }
  int lane = tid & 63, wid = tid >> 6;
  if (lane == 0){ red[wid] = s; red[4+wid] = s2; }
  __syncthreads();
  if (tid == 0){
    float S = red[0]+red[1]+red[2]+red[3];
    float S2 = red[4]+red[5]+red[6]+red[7];
    float m = S * (1.f/512.f);
    float var = S2 * (1.f/512.f) - m*m;
    ms[0] = m; ms[1] = rsqrtf(var + 1e-5f);
  }
  __syncthreads();
}

__device__ __forceinline__ float dot_ld4(const float* __restrict__ w, const float* x, int n4){
  float acc = 0.f;
  const float4* w4 = (const float4*)w;
  const float4* x4 = (const float4*)x;
  for (int k = 0; k < n4; k++){
    float4 a = w4[k], b = x4[k];
    acc += a.x*b.x + a.y*b.y + a.z*b.z + a.w*b.w;
  }
  return acc;
}

// ---------------- prep: f32 -> bf16 ----------------
__global__ __launch_bounds__(256) void k_cvt(const float* __restrict__ src,
                                             __hip_bfloat16* __restrict__ dst){
  int i = blockIdx.x*256 + threadIdx.x;
  dst[i] = __float2bfloat16(src[i]);
}

// ---------------- kernel 1: q (B,512) and y_init = (k0.q) v0 ----------------
__global__ __launch_bounds__(256) void k_init(
    const float* __restrict__ initial, const float* __restrict__ logsig,
    const float* __restrict__ Wi, const float* __restrict__ bi,
    const float* __restrict__ Wip, const float* __restrict__ bip,
    const float* __restrict__ g_in, const float* __restrict__ b_in,
    const float* __restrict__ Wk, const float* __restrict__ bk,
    const float* __restrict__ Wv, const float* __restrict__ bv,
    const float* __restrict__ Wq, const float* __restrict__ bq,
    float* __restrict__ qout, float* __restrict__ yinit)
{
  int b = blockIdx.x, tid = threadIdx.x;
  __shared__ __align__(16) float xls[128];
  __shared__ __align__(16) float hln[512];
  __shared__ __align__(16) float tmp[512];
  __shared__ __align__(16) float v0s[512];
  __shared__ __align__(16) float qs[512];
  __shared__ __align__(16) float ip[64];
  __shared__ float red[8]; __shared__ float ms[2];
  __shared__ float hm[8], hs[8], sal[8];

  // ---- hq from last logsig row -> q ----
  if (tid < 64) xls[tid] = logsig[((size_t)b*T_ + (T_-1))*CIN + tid];
  __syncthreads();
  float h0 = bip[tid]     + dot_ld4(Wip + (size_t)tid*CIN,       xls, CIN/4);
  float h1 = bip[tid+256] + dot_ld4(Wip + (size_t)(tid+256)*CIN, xls, CIN/4);
  ln_stats(h0, h1, red, ms, tid);
  hln[tid]     = (h0-ms[0])*ms[1]*g_in[tid]     + b_in[tid];
  hln[tid+256] = (h1-ms[0])*ms[1]*g_in[tid+256] + b_in[tid+256];
  __syncthreads();
  tmp[tid]     = bq[tid]     + dot_ld4(Wq + (size_t)tid*HID,       hln, HID/4);
  tmp[tid+256] = bq[tid+256] + dot_ld4(Wq + (size_t)(tid+256)*HID, hln, HID/4);
  __syncthreads();
  if (tid < 8){
    float m = -1e30f; for (int e=0;e<64;e++) m = fmaxf(m, tmp[tid*64+e]);
    float s = 0.f;    for (int e=0;e<64;e++) s += expf(tmp[tid*64+e]-m);
    hm[tid] = m; hs[tid] = s;
  }
  __syncthreads();
  {
    float q0 = expf(tmp[tid]-hm[tid>>6]) / hs[tid>>6];
    float q1 = expf(tmp[tid+256]-hm[(tid+256)>>6]) / hs[(tid+256)>>6];
    qs[tid] = q0; qs[tid+256] = q1;
    qout[(size_t)b*HID+tid] = q0; qout[(size_t)b*HID+tid+256] = q1;
  }
  __syncthreads();

  // ---- init branch: init_proj -> h0 -> k0,v0 -> y_init ----
  if (tid < 128) xls[tid] = initial[(size_t)b*128 + tid];
  __syncthreads();
  if (tid < 64) ip[tid] = bi[tid] + dot_ld4(Wi + (size_t)tid*128, xls, 128/4);
  __syncthreads();
  h0 = bip[tid]     + dot_ld4(Wip + (size_t)tid*CIN,       ip, CIN/4);
  h1 = bip[tid+256] + dot_ld4(Wip + (size_t)(tid+256)*CIN, ip, CIN/4);
  ln_stats(h0, h1, red, ms, tid);
  hln[tid]     = (h0-ms[0])*ms[1]*g_in[tid]     + b_in[tid];
  hln[tid+256] = (h1-ms[0])*ms[1]*g_in[tid+256] + b_in[tid+256];
  __syncthreads();
  tmp[tid]     = bk[tid]     + dot_ld4(Wk + (size_t)tid*HID,       hln, HID/4);
  tmp[tid+256] = bk[tid+256] + dot_ld4(Wk + (size_t)(tid+256)*HID, hln, HID/4);
  v0s[tid]     = bv[tid]     + dot_ld4(Wv + (size_t)tid*HID,       hln, HID/4);
  v0s[tid+256] = bv[tid+256] + dot_ld4(Wv + (size_t)(tid+256)*HID, hln, HID/4);
  __syncthreads();
  if (tid < 8){
    float m = -1e30f; for (int e=0;e<64;e++) m = fmaxf(m, tmp[tid*64+e]);
    float s = 0.f;    for (int e=0;e<64;e++) s += expf(tmp[tid*64+e]-m);
    float a = 0.f;
    for (int e=0;e<64;e++) a += (expf(tmp[tid*64+e]-m)/s) * qs[tid*64+e];
    sal[tid] = a;
  }
  __syncthreads();
  yinit[(size_t)b*HID+tid]     = sal[tid>>6]       * v0s[tid];
  yinit[(size_t)b*HID+tid+256] = sal[(tid+256)>>6] * v0s[tid+256];
}

// ---------------- FUSED kernel: hln (MFMA+LN, LDS-resident) + score + softmax.q + partial-u ----
// Block: (b, tc). 512 threads = 8 waves; wave w = head w (phase 2/4) and col-slice w (phase 1).
__global__ __launch_bounds__(512, 4) void k_fused(
    const float* __restrict__ logsig,
    const __hip_bfloat16* __restrict__ Wipb,   // (512,64) bf16
    const float* __restrict__ bip,
    const float* __restrict__ g_in, const float* __restrict__ b_in,
    const __hip_bfloat16* __restrict__ Wkb,    // (512,512) bf16
    const float* __restrict__ bk,
    const float* __restrict__ qws,             // (B,512)
    float* __restrict__ up,                    // (B,NH,4,512) f32 partial u
    float* __restrict__ Asp)                   // (B,NH,4) partial alpha-sum
{
  int b = blockIdx.x, tc = blockIdx.y;
  int tid = threadIdx.x;
  int w = tid >> 6, l = tid & 63, lr = l & 15, lg = l >> 4;
  __shared__ __align__(16) char Hs[64*1024];     // 64 rows x 512 bf16, swizzled
  __shared__ float red[64][8][2];
  __shared__ float ms2[64][2];
  __shared__ float als[64][8];

  // ---- stage logsig x-tile (64x64 f32 -> bf16) into Hs cols 0..64 ----
  {
    int row = tid >> 3, cc = (tid & 7)*8;
    const float* srow = logsig + ((size_t)b*T_ + tc*64 + row)*CIN + cc;
    float4 a = *(const float4*)(srow);
    float4 c = *(const float4*)(srow+4);
    uint4 p = { pk2(a.x,a.y), pk2(a.z,a.w), pk2(c.x,c.y), pk2(c.z,c.w) };
    *(uint4*)(Hs + HSOFF(row, cc)) = p;
  }
  __syncthreads();

  // ---- phase 1: Hpre = x @ Wip^T  (wave w -> cols w*64..w*64+63) ----
  f32x4 acc[4][4];
  #pragma unroll
  for (int i=0;i<4;i++)
    #pragma unroll
    for (int j=0;j<4;j++) acc[i][j] = (f32x4){0.f,0.f,0.f,0.f};
  #pragma unroll
  for (int kk = 0; kk < CIN; kk += 32){
    bf16x8 af[4], bfr[4];
    #pragma unroll
    for (int i=0;i<4;i++)
      af[i] = *(const bf16x8*)(Hs + HSOFF(i*16 + lr, kk + lg*8));
    #pragma unroll
    for (int j=0;j<4;j++)
      bfr[j] = *(const bf16x8*)(Wipb + (size_t)(w*64 + j*16 + lr)*CIN + kk + lg*8);
    #pragma unroll
    for (int i=0;i<4;i++)
      #pragma unroll
      for (int j=0;j<4;j++)
        acc[i][j] = __builtin_amdgcn_mfma_f32_16x16x32_bf16(af[i], bfr[j], acc[i][j], 0,0,0);
  }
  float bipv[4], gv[4], bbv[4];
  #pragma unroll
  for (int j=0;j<4;j++){
    int col = w*64 + j*16 + lr;
    bipv[j] = bip[col]; gv[j] = g_in[col]; bbv[j] = b_in[col];
  }
  // per-row stats
  #pragma unroll
  for (int i=0;i<4;i++){
    #pragma unroll
    for (int r=0;r<4;r++){
      float s = 0.f, s2 = 0.f;
      #pragma unroll
      for (int j=0;j<4;j++){ float v = acc[i][j][r] + bipv[j]; s += v; s2 += v*v; }
      #pragma unroll
      for (int o=1;o<16;o<<=1){ s += __shfl_xor(s,o); s2 += __shfl_xor(s2,o); }
      if (lr == 0){ int row = i*16 + lg*4 + r; red[row][w][0] = s; red[row][w][1] = s2; }
    }
  }
  __syncthreads();
  if (tid < 64){
    float S = 0.f, S2 = 0.f;
    #pragma unroll
    for (int k=0;k<8;k++){ S += red[tid][k][0]; S2 += red[tid][k][1]; }
    float m = S*(1.f/512.f), var = S2*(1.f/512.f) - m*m;
    ms2[tid][0] = m; ms2[tid][1] = rsqrtf(var + 1e-5f);
  }
  __syncthreads();
  // write normalized bf16 tile into Hs (overwrites staged x region too)
  #pragma unroll
  for (int i=0;i<4;i++){
    #pragma unroll
    for (int r=0;r<4;r++){
      int row = i*16 + lg*4 + r;
      float m = ms2[row][0], rs = ms2[row][1];
      #pragma unroll
      for (int j=0;j<4;j++){
        int col = w*64 + j*16 + lr;
        float v = (acc[i][j][r] + bipv[j] - m)*rs*gv[j] + bbv[j];
        *(unsigned short*)(Hs + HSOFF(row, col)) =
            __bfloat16_as_ushort(__float2bfloat16(v));
      }
    }
  }
  __syncthreads();

  // ---- phase 2: scores S = Hln @ Wk_h^T (wave w = head w), A from LDS ----
  #pragma unroll
  for (int i=0;i<4;i++)
    #pragma unroll
    for (int j=0;j<4;j++) acc[i][j] = (f32x4){0.f,0.f,0.f,0.f};
  const __hip_bfloat16* Bbase = Wkb + (size_t)(w*64)*HID;
  for (int kk = 0; kk < HID; kk += 32){
    bf16x8 af[4], bfr[4];
    #pragma unroll
    for (int i=0;i<4;i++)
      af[i] = *(const bf16x8*)(Hs + HSOFF(i*16 + lr, kk + lg*8));
    #pragma unroll
    for (int j=0;j<4;j++)
      bfr[j] = *(const bf16x8*)(Bbase + (size_t)(j*16 + lr)*HID + kk + lg*8);
    #pragma unroll
    for (int i=0;i<4;i++)
      #pragma unroll
      for (int j=0;j<4;j++)
        acc[i][j] = __builtin_amdgcn_mfma_f32_16x16x32_bf16(af[i], bfr[j], acc[i][j], 0,0,0);
  }

  // ---- phase 3: per-row softmax over head cols, dot q, RK4 weight -> als ----
  {
    float bkv[4], qv[4];
    #pragma unroll
    for (int j=0;j<4;j++){
      bkv[j] = bk[w*64 + j*16 + lr];
      qv[j]  = qws[(size_t)b*HID + w*64 + j*16 + lr];
    }
    #pragma unroll
    for (int i=0;i<4;i++){
      #pragma unroll
      for (int r=0;r<4;r++){
        float v0 = acc[i][0][r]+bkv[0], v1 = acc[i][1][r]+bkv[1];
        float v2 = acc[i][2][r]+bkv[2], v3 = acc[i][3][r]+bkv[3];
        float mx = fmaxf(fmaxf(v0,v1),fmaxf(v2,v3));
        #pragma unroll
        for (int o=1;o<16;o<<=1) mx = fmaxf(mx, __shfl_xor(mx,o));
        float e0=__expf(v0-mx), e1=__expf(v1-mx), e2=__expf(v2-mx), e3=__expf(v3-mx);
        float se = e0+e1+e2+e3;
        float sq = e0*qv[0]+e1*qv[1]+e2*qv[2]+e3*qv[3];
        #pragma unroll
        for (int o=1;o<16;o<<=1){ se += __shfl_xor(se,o); sq += __shfl_xor(sq,o); }
        if (lr == 0){
          int row = i*16 + lg*4 + r;
          int t = tc*64 + row;
          float wt = (t == 0) ? (5.f/6.f) : ((t == T_-1) ? (1.f/6.f) : 1.f);
          als[row][w] = wt * sq / se;
        }
      }
    }
  }
  __syncthreads();

  // ---- phase 4: partial u for head w over this 64-row chunk; partial Asum ----
  {
    float ua[8];
    #pragma unroll
    for (int e=0;e<8;e++) ua[e] = 0.f;
    for (int r = 0; r < 64; r++){
      uint4 hv = *(const uint4*)(Hs + HSOFF(r, l*8));
      float a = als[r][w];
      ua[0] += a*bf2f(hv.x & 0xffffu); ua[1] += a*bf2f(hv.x >> 16);
      ua[2] += a*bf2f(hv.y & 0xffffu); ua[3] += a*bf2f(hv.y >> 16);
      ua[4] += a*bf2f(hv.z & 0xffffu); ua[5] += a*bf2f(hv.z >> 16);
      ua[6] += a*bf2f(hv.w & 0xffffu); ua[7] += a*bf2f(hv.w >> 16);
    }
    float* dst = up + ((((size_t)b*NH + w)*4 + tc)*HID) + l*8;
    *(float4*)(dst)   = (float4){ua[0],ua[1],ua[2],ua[3]};
    *(float4*)(dst+4) = (float4){ua[4],ua[5],ua[6],ua[7]};
    float s = als[l][w];
    #pragma unroll
    for (int o=1;o<64;o<<=1) s += __shfl_xor(s,o);
    if (l == 0) Asp[(((size_t)b*NH + w)*4) + tc] = s;
  }
}

// ---------------- reduce partials: u_bf (bf16) and Asum ----------------
__global__ __launch_bounds__(256) void k_ured(
    const float* __restrict__ up, const float* __restrict__ Asp,
    __hip_bfloat16* __restrict__ u_bf, float* __restrict__ Asum)
{
  int bh = blockIdx.x, tid = threadIdx.x;
  size_t base = (size_t)bh*4*HID;
  float s0 = 0.f, s1 = 0.f;
  #pragma unroll
  for (int c=0;c<4;c++){
    s0 += up[base + (size_t)c*HID + 2*tid];
    s1 += up[base + (size_t)c*HID + 2*tid+1];
  }
  ((unsigned*)u_bf)[(size_t)bh*(HID/2) + tid] = pk2(s0, s1);
  if (tid == 0)
    Asum[bh] = Asp[(size_t)bh*4] + Asp[(size_t)bh*4+1] + Asp[(size_t)bh*4+2] + Asp[(size_t)bh*4+3];
}

// ---------------- kernel C1: yh = u @ Wv_h^T + yinit + bv*Asum -> bf16 ----------------
__global__ __launch_bounds__(256) void k_yhead(
    const __hip_bfloat16* __restrict__ u_bf,   // (B,8,512)
    const __hip_bfloat16* __restrict__ Wvb,    // (512,512)
    const float* __restrict__ bv, const float* __restrict__ Asum,
    const float* __restrict__ yinit,
    __hip_bfloat16* __restrict__ yh)           // (B,512) bf16
{
  int mb = blockIdx.x, h = blockIdx.y;
  int tid = threadIdx.x;
  int w = tid >> 6, l = tid & 63, lr = l & 15, lg = l >> 4;
  int row0 = mb*64 + w*16;
  const __hip_bfloat16* Abase = u_bf + ((size_t)(row0 + lr)*NH + h)*HID;
  const __hip_bfloat16* Bbase = Wvb + (size_t)(h*64)*HID;
  f32x4 acc[4];
  #pragma unroll
  for (int j=0;j<4;j++) acc[j] = (f32x4){0.f,0.f,0.f,0.f};
  for (int kk = 0; kk < HID; kk += 32){
    bf16x8 af = *(const bf16x8*)(Abase + kk + lg*8);
    #pragma unroll
    for (int j=0;j<4;j++){
      bf16x8 bfr = *(const bf16x8*)(Bbase + (size_t)(j*16 + lr)*HID + kk + lg*8);
      acc[j] = __builtin_amdgcn_mfma_f32_16x16x32_bf16(af, bfr, acc[j], 0,0,0);
    }
  }
  #pragma unroll
  for (int j=0;j<4;j++){
    int col = h*64 + j*16 + lr;
    float bvc = bv[col];
    #pragma unroll
    for (int r=0;r<4;r++){
      int row = row0 + lg*4 + r;
      float v = acc[j][r] + yinit[(size_t)row*HID + col] + bvc*Asum[(size_t)row*NH + h];
      yh[(size_t)row*HID + col] = __float2bfloat16(v);
    }
  }
}

// ---------------- kernel C1b: yo = yh @ Wo^T + bo (f32 out) ----------------
__global__ __launch_bounds__(256) void k_yo(
    const __hip_bfloat16* __restrict__ yh,   // (B,512)
    const __hip_bfloat16* __restrict__ Wob,  // (512,512)
    const float* __restrict__ bo,
    float* __restrict__ yo)                  // (B,512)
{
  int mb = blockIdx.x, nb = blockIdx.y;
  int tid = threadIdx.x;
  int w = tid >> 6, l = tid & 63, lr = l & 15, lg = l >> 4;
  int row0 = mb*64 + w*16;
  const __hip_bfloat16* Abase = yh + (size_t)(row0 + lr)*HID;
  const __hip_bfloat16* Bbase = Wob + (size_t)(nb*64)*HID;
  f32x4 acc[4];
  #pragma unroll
  for (int j=0;j<4;j++) acc[j] = (f32x4){0.f,0.f,0.f,0.f};
  for (int kk = 0; kk < HID; kk += 32){
    bf16x8 af = *(const bf16x8*)(Abase + kk + lg*8);
    #pragma unroll
    for (int j=0;j<4;j++){
      bf16x8 bfr = *(const bf16x8*)(Bbase + (size_t)(j*16 + lr)*HID + kk + lg*8);
      acc[j] = __builtin_amdgcn_mfma_f32_16x16x32_bf16(af, bfr, acc[j], 0,0,0);
    }
  }
  #pragma unroll
  for (int j=0;j<4;j++){
    int col = nb*64 + j*16 + lr;
    float bc = bo[col];
    #pragma unroll
    for (int r=0;r<4;r++){
      int row = row0 + lg*4 + r;
      yo[(size_t)row*HID + col] = acc[j][r] + bc;
    }
  }
}

// ---------------- kernel C2: row LN of yo -> yln bf16 ----------------
__global__ __launch_bounds__(256) void k_ln2(
    const float* __restrict__ yo,
    const float* __restrict__ g_ff, const float* __restrict__ b_ff,
    __hip_bfloat16* __restrict__ yln)
{
  int tid = threadIdx.x;
  int row = blockIdx.x*32 + (tid >> 3), sub = tid & 7;
  const float4* yr = (const float4*)(yo + (size_t)row*HID) + sub*16;
  float4 v[16];
  float s = 0.f, s2 = 0.f;
  #pragma unroll
  for (int k=0;k<16;k++){
    v[k] = yr[k];
    s  += v[k].x+v[k].y+v[k].z+v[k].w;
    s2 += v[k].x*v[k].x+v[k].y*v[k].y+v[k].z*v[k].z+v[k].w*v[k].w;
  }
  #pragma unroll
  for (int o=1;o<8;o<<=1){ s += __shfl_xor(s,o); s2 += __shfl_xor(s2,o); }
  float m = s*(1.f/512.f), rs = rsqrtf(s2*(1.f/512.f) - m*m + 1e-5f);
  #pragma unroll
  for (int k=0;k<16;k++){
    int c = sub*64 + k*4;
    float o0 = (v[k].x-m)*rs*g_ff[c]   + b_ff[c];
    float o1 = (v[k].y-m)*rs*g_ff[c+1] + b_ff[c+1];
    float o2 = (v[k].z-m)*rs*g_ff[c+2] + b_ff[c+2];
    float o3 = (v[k].w-m)*rs*g_ff[c+3] + b_ff[c+3];
    yln[(size_t)row*HID + c]   = __float2bfloat16(o0);
    yln[(size_t)row*HID + c+1] = __float2bfloat16(o1);
    yln[(size_t)row*HID + c+2] = __float2bfloat16(o2);
    yln[(size_t)row*HID + c+3] = __float2bfloat16(o3);
  }
}

// ---------------- kernel C3: a1 = relu(yln @ W1^T + b1) bf16 ----------------
__global__ __launch_bounds__(256) void k_ff1(
    const __hip_bfloat16* __restrict__ yln,  // (B,512)
    const __hip_bfloat16* __restrict__ W1b,  // (2048,512)
    const float* __restrict__ b1,
    __hip_bfloat16* __restrict__ a1b)        // (B,2048)
{
  int mb = blockIdx.x, nb = blockIdx.y;
  int tid = threadIdx.x;
  int w = tid >> 6, l = tid & 63, lr = l & 15, lg = l >> 4;
  int row0 = mb*64 + w*16;
  const __hip_bfloat16* Abase = yln + (size_t)(row0 + lr)*HID;
  const __hip_bfloat16* Bbase = W1b + (size_t)(nb*64)*HID;
  f32x4 acc[4];
  #pragma unroll
  for (int j=0;j<4;j++) acc[j] = (f32x4){0.f,0.f,0.f,0.f};
  for (int kk = 0; kk < HID; kk += 32){
    bf16x8 af = *(const bf16x8*)(Abase + kk + lg*8);
    #pragma unroll
    for (int j=0;j<4;j++){
      bf16x8 bfr = *(const bf16x8*)(Bbase + (size_t)(j*16 + lr)*HID + kk + lg*8);
      acc[j] = __builtin_amdgcn_mfma_f32_16x16x32_bf16(af, bfr, acc[j], 0,0,0);
    }
  }
  #pragma unroll
  for (int j=0;j<4;j++){
    int col = nb*64 + j*16 + lr;
    float bc = b1[col];
    #pragma unroll
    for (int r=0;r<4;r++){
      int row = row0 + lg*4 + r;
      a1b[(size_t)row*FFD + col] = __float2bfloat16(fmaxf(acc[j][r] + bc, 0.f));
    }
  }
}

// ---------------- kernel C4: y2 = a1 @ W2^T + b2 + yo ----------------
__global__ __launch_bounds__(256) void k_ff2(
    const __hip_bfloat16* __restrict__ a1b,  // (B,2048)
    const __hip_bfloat16* __restrict__ W2b,  // (512,2048)
    const float* __restrict__ b2,
    const float* __restrict__ yo,
    float* __restrict__ y2)                  // (B,512)
{
  int mb = blockIdx.x, nb = blockIdx.y;
  int tid = threadIdx.x;
  int w = tid >> 6, l = tid & 63, lr = l & 15, lg = l >> 4;
  int row0 = mb*64 + w*16;
  const __hip_bfloat16* Abase = a1b + (size_t)(row0 + lr)*FFD;
  const __hip_bfloat16* Bbase = W2b + (size_t)(nb*64)*FFD;
  f32x4 acc[4];
  #pragma unroll
  for (int j=0;j<4;j++) acc[j] = (f32x4){0.f,0.f,0.f,0.f};
  for (int kk = 0; kk < FFD; kk += 32){
    bf16x8 af = *(const bf16x8*)(Abase + kk + lg*8);
    #pragma unroll
    for (int j=0;j<4;j++){
      bf16x8 bfr = *(const bf16x8*)(Bbase + (size_t)(j*16 + lr)*FFD + kk + lg*8);
      acc[j] = __builtin_amdgcn_mfma_f32_16x16x32_bf16(af, bfr, acc[j], 0,0,0);
    }
  }
  #pragma unroll
  for (int j=0;j<4;j++){
    int col = nb*64 + j*16 + lr;
    float bc = b2[col];
    #pragma unroll
    for (int r=0;r<4;r++){
      int row = row0 + lg*4 + r;
      y2[(size_t)row*HID + col] = acc[j][r] + bc + yo[(size_t)row*HID + col];
    }
  }
}

// ---------------- kernel C5: out = y2 @ Wf^T + bf ----------------
__global__ __launch_bounds__(256) void k_final(
    const float* __restrict__ y2,
    const float* __restrict__ Wf, const float* __restrict__ bfv,
    float* __restrict__ out)
{
  int tid = threadIdx.x;
  int b0 = blockIdx.x*64;
  for (int i = tid; i < 64*OUTD; i += 256){
    int r = b0 + i/OUTD, c = i%OUTD;
    out[(size_t)r*OUTD + c] = bfv[c] + dot_ld4(Wf + (size_t)c*HID, y2 + (size_t)r*HID, HID/4);
  }
}

extern "C" void kernel_launch(void* const* d_in, const int* in_sizes, int n_in,
                              void* d_out, int out_size, void* d_ws, size_t ws_size,
                              hipStream_t stream)
{
  const float* initial = (const float*)d_in[0];
  const float* logsig  = (const float*)d_in[1];
  const float* Wi  = (const float*)d_in[2];  const float* bi  = (const float*)d_in[3];
  const float* Wip = (const float*)d_in[4];  const float* bip = (const float*)d_in[5];
  const float* g_in= (const float*)d_in[6];  const float* b_in= (const float*)d_in[7];
  const float* Wk  = (const float*)d_in[8];  const float* bk  = (const float*)d_in[9];
  const float* Wv  = (const float*)d_in[10]; const float* bv  = (const float*)d_in[11];
  const float* Wq  = (const float*)d_in[12]; const float* bq  = (const float*)d_in[13];
  const float* Wo  = (const float*)d_in[14]; const float* bo  = (const float*)d_in[15];
  const float* g_ff= (const float*)d_in[16]; const float* b_ff= (const float*)d_in[17];
  const float* W1  = (const float*)d_in[18]; const float* b1  = (const float*)d_in[19];
  const float* W2  = (const float*)d_in[20]; const float* b2  = (const float*)d_in[21];
  const float* Wf  = (const float*)d_in[22]; const float* bf  = (const float*)d_in[23];
  float* out = (float*)d_out;

  char* ws = (char*)d_ws;
  const size_t MB = 1<<20;
  float* qws   = (float*)(ws);                             // 512 KB
  float* yinit = (float*)(ws + 512*1024);                  // 512 KB
  __hip_bfloat16* u_bf = (__hip_bfloat16*)(ws + 3*MB);     // 2 MB
  float* Asum  = (float*)(ws + 5*MB);                      // 8 KB
  __hip_bfloat16* Wkb = (__hip_bfloat16*)(ws + 5*MB + 512*1024);  // 512 KB
  __hip_bfloat16* Wvb = (__hip_bfloat16*)(ws + 6*MB);      // 512 KB
  __hip_bfloat16* W1b = (__hip_bfloat16*)(ws + 6*MB + 512*1024);  // 2 MB
  __hip_bfloat16* W2b = (__hip_bfloat16*)(ws + 8*MB + 512*1024);  // 2 MB
  float* y2    = (float*)(ws + 10*MB + 512*1024);          // 512 KB
  __hip_bfloat16* yln = (__hip_bfloat16*)(ws + 11*MB);     // 256 KB
  __hip_bfloat16* a1b = (__hip_bfloat16*)(ws + 11*MB + 512*1024); // 1 MB
  __hip_bfloat16* Wob = (__hip_bfloat16*)(ws + 13*MB);     // 512 KB
  __hip_bfloat16* yh  = (__hip_bfloat16*)(ws + 13*MB + 512*1024); // 256 KB
  float* yo    = (float*)(ws + 14*MB);                     // 512 KB
  __hip_bfloat16* Wipb = (__hip_bfloat16*)(ws + 15*MB);    // 64 KB
  float* up    = (float*)(ws + 16*MB);                     // 16 MB
  float* Asp   = (float*)(ws + 33*MB);                     // 32 KB

  k_cvt<<<dim3((HID*HID)/256), 256, 0, stream>>>(Wk, Wkb);
  k_cvt<<<dim3((HID*HID)/256), 256, 0, stream>>>(Wv, Wvb);
  k_cvt<<<dim3((HID*HID)/256), 256, 0, stream>>>(Wo, Wob);
  k_cvt<<<dim3((FFD*HID)/256), 256, 0, stream>>>(W1, W1b);
  k_cvt<<<dim3((HID*FFD)/256), 256, 0, stream>>>(W2, W2b);
  k_cvt<<<dim3((HID*CIN)/256), 256, 0, stream>>>(Wip, Wipb);
  k_init<<<B_, 256, 0, stream>>>(initial, logsig, Wi, bi, Wip, bip, g_in, b_in,
                                 Wk, bk, Wv, bv, Wq, bq, qws, yinit);
  k_fused<<<dim3(B_, 4), 512, 0, stream>>>(logsig, Wipb, bip, g_in, b_in,
                                           Wkb, bk, qws, up, Asp);
  k_ured<<<dim3(B_*NH), 256, 0, stream>>>(up, Asp, u_bf, Asum);
  k_yhead<<<dim3(B_/64, NH), 256, 0, stream>>>(u_bf, Wvb, bv, Asum, yinit, yh);
  k_yo<<<dim3(B_/64, HID/64), 256, 0, stream>>>(yh, Wob, bo, yo);
  k_ln2<<<dim3(B_/32), 256, 0, stream>>>(yo, g_ff, b_ff, yln);
  k_ff1<<<dim3(B_/64, FFD/64), 256, 0, stream>>>(yln, W1b, b1, a1b);
  k_ff2<<<dim3(B_/64, HID/64), 256, 0, stream>>>(a1b, W2b, b2, yo, y2);
  k_final<<<dim3(B_/64), 256, 0, stream>>>(y2, Wf, bf, out);
}

// Round 7
// 359.832 us; speedup vs baseline: 3.7672x; 1.0535x over previous
//
#include <hip/hip_runtime.h>
#include <hip/hip_bf16.h>
#include <math.h>

#define B_ 256
#define T_ 256
#define CIN 64
#define HID 512
#define NH 8
#define HD 64
#define FFD 2048
#define OUTD 10

typedef __bf16 bf16x8 __attribute__((ext_vector_type(8)));
typedef float f32x4 __attribute__((ext_vector_type(4)));

// swizzled LDS byte offset for the 64x512 bf16 Hs tile (row stride 1024B)
#define HSOFF(r,c) (((r)<<10) + ((((c)<<1)) ^ ((((r)&7))<<4)))

__device__ __forceinline__ float bf2f(unsigned u){
  union { unsigned i; float f; } c; c.i = u << 16; return c.f;
}
__device__ __forceinline__ unsigned pk2(float a, float b){
  return ((unsigned)__bfloat16_as_ushort(__float2bfloat16(a))) |
         (((unsigned)__bfloat16_as_ushort(__float2bfloat16(b))) << 16);
}

// LN stats over 512 values held as (v0 at tid, v1 at tid+256), 256 threads.
__device__ __forceinline__ void ln_stats(float v0, float v1, float* red, float* ms, int tid){
  float s = v0 + v1, s2 = v0*v0 + v1*v1;
  #pragma unroll
  for (int o = 32; o; o >>= 1){ s += __shfl_xor(s, o); s2 += __shfl_xor(s2, o); }
  int lane = tid & 63, wid = tid >> 6;
  if (lane == 0){ red[wid] = s; red[4+wid] = s2; }
  __syncthreads();
  if (tid == 0){
    float S = red[0]+red[1]+red[2]+red[3];
    float S2 = red[4]+red[5]+red[6]+red[7];
    float m = S * (1.f/512.f);
    float var = S2 * (1.f/512.f) - m*m;
    ms[0] = m; ms[1] = rsqrtf(var + 1e-5f);
  }
  __syncthreads();
}

__device__ __forceinline__ float dot_ld4(const float* __restrict__ w, const float* x, int n4){
  float acc = 0.f;
  const float4* w4 = (const float4*)w;
  const float4* x4 = (const float4*)x;
  for (int k = 0; k < n4; k++){
    float4 a = w4[k], b = x4[k];
    acc += a.x*b.x + a.y*b.y + a.z*b.z + a.w*b.w;
  }
  return acc;
}

// ---------------- prep: all six f32 -> bf16 weight conversions in one launch ----------------
#define CW_KV  (HID*HID)            // 262144
#define CW_IP  (HID*CIN)            // 32768
#define CW_FF  (FFD*HID)            // 1048576
#define CVT_TOT (3*CW_KV + 2*CW_FF + CW_IP)
__global__ __launch_bounds__(256) void k_cvt6(
    const float* __restrict__ Wk, const float* __restrict__ Wv,
    const float* __restrict__ Wo, const float* __restrict__ W1,
    const float* __restrict__ W2, const float* __restrict__ Wip,
    __hip_bfloat16* __restrict__ Wkb, __hip_bfloat16* __restrict__ Wvb,
    __hip_bfloat16* __restrict__ Wob, __hip_bfloat16* __restrict__ W1b,
    __hip_bfloat16* __restrict__ W2b, __hip_bfloat16* __restrict__ Wipb)
{
  int i = blockIdx.x*256 + threadIdx.x;
  if (i < CW_KV)                    { Wkb[i] = __float2bfloat16(Wk[i]); return; }
  i -= CW_KV;
  if (i < CW_KV)                    { Wvb[i] = __float2bfloat16(Wv[i]); return; }
  i -= CW_KV;
  if (i < CW_KV)                    { Wob[i] = __float2bfloat16(Wo[i]); return; }
  i -= CW_KV;
  if (i < CW_FF)                    { W1b[i] = __float2bfloat16(W1[i]); return; }
  i -= CW_FF;
  if (i < CW_FF)                    { W2b[i] = __float2bfloat16(W2[i]); return; }
  i -= CW_FF;
  if (i < CW_IP)                    { Wipb[i] = __float2bfloat16(Wip[i]); }
}

// ---------------- kernel 1: q (B,512) and y_init = (k0.q) v0 ----------------
__global__ __launch_bounds__(256) void k_init(
    const float* __restrict__ initial, const float* __restrict__ logsig,
    const float* __restrict__ Wi, const float* __restrict__ bi,
    const float* __restrict__ Wip, const float* __restrict__ bip,
    const float* __restrict__ g_in, const float* __restrict__ b_in,
    const float* __restrict__ Wk, const float* __restrict__ bk,
    const float* __restrict__ Wv, const float* __restrict__ bv,
    const float* __restrict__ Wq, const float* __restrict__ bq,
    float* __restrict__ qout, float* __restrict__ yinit)
{
  int b = blockIdx.x, tid = threadIdx.x;
  __shared__ __align__(16) float xls[128];
  __shared__ __align__(16) float hln[512];
  __shared__ __align__(16) float tmp[512];
  __shared__ __align__(16) float v0s[512];
  __shared__ __align__(16) float qs[512];
  __shared__ __align__(16) float ip[64];
  __shared__ float red[8]; __shared__ float ms[2];
  __shared__ float hm[8], hs[8], sal[8];

  // ---- hq from last logsig row -> q ----
  if (tid < 64) xls[tid] = logsig[((size_t)b*T_ + (T_-1))*CIN + tid];
  __syncthreads();
  float h0 = bip[tid]     + dot_ld4(Wip + (size_t)tid*CIN,       xls, CIN/4);
  float h1 = bip[tid+256] + dot_ld4(Wip + (size_t)(tid+256)*CIN, xls, CIN/4);
  ln_stats(h0, h1, red, ms, tid);
  hln[tid]     = (h0-ms[0])*ms[1]*g_in[tid]     + b_in[tid];
  hln[tid+256] = (h1-ms[0])*ms[1]*g_in[tid+256] + b_in[tid+256];
  __syncthreads();
  tmp[tid]     = bq[tid]     + dot_ld4(Wq + (size_t)tid*HID,       hln, HID/4);
  tmp[tid+256] = bq[tid+256] + dot_ld4(Wq + (size_t)(tid+256)*HID, hln, HID/4);
  __syncthreads();
  if (tid < 8){
    float m = -1e30f; for (int e=0;e<64;e++) m = fmaxf(m, tmp[tid*64+e]);
    float s = 0.f;    for (int e=0;e<64;e++) s += expf(tmp[tid*64+e]-m);
    hm[tid] = m; hs[tid] = s;
  }
  __syncthreads();
  {
    float q0 = expf(tmp[tid]-hm[tid>>6]) / hs[tid>>6];
    float q1 = expf(tmp[tid+256]-hm[(tid+256)>>6]) / hs[(tid+256)>>6];
    qs[tid] = q0; qs[tid+256] = q1;
    qout[(size_t)b*HID+tid] = q0; qout[(size_t)b*HID+tid+256] = q1;
  }
  __syncthreads();

  // ---- init branch: init_proj -> h0 -> k0,v0 -> y_init ----
  if (tid < 128) xls[tid] = initial[(size_t)b*128 + tid];
  __syncthreads();
  if (tid < 64) ip[tid] = bi[tid] + dot_ld4(Wi + (size_t)tid*128, xls, 128/4);
  __syncthreads();
  h0 = bip[tid]     + dot_ld4(Wip + (size_t)tid*CIN,       ip, CIN/4);
  h1 = bip[tid+256] + dot_ld4(Wip + (size_t)(tid+256)*CIN, ip, CIN/4);
  ln_stats(h0, h1, red, ms, tid);
  hln[tid]     = (h0-ms[0])*ms[1]*g_in[tid]     + b_in[tid];
  hln[tid+256] = (h1-ms[0])*ms[1]*g_in[tid+256] + b_in[tid+256];
  __syncthreads();
  tmp[tid]     = bk[tid]     + dot_ld4(Wk + (size_t)tid*HID,       hln, HID/4);
  tmp[tid+256] = bk[tid+256] + dot_ld4(Wk + (size_t)(tid+256)*HID, hln, HID/4);
  v0s[tid]     = bv[tid]     + dot_ld4(Wv + (size_t)tid*HID,       hln, HID/4);
  v0s[tid+256] = bv[tid+256] + dot_ld4(Wv + (size_t)(tid+256)*HID, hln, HID/4);
  __syncthreads();
  if (tid < 8){
    float m = -1e30f; for (int e=0;e<64;e++) m = fmaxf(m, tmp[tid*64+e]);
    float s = 0.f;    for (int e=0;e<64;e++) s += expf(tmp[tid*64+e]-m);
    float a = 0.f;
    for (int e=0;e<64;e++) a += (expf(tmp[tid*64+e]-m)/s) * qs[tid*64+e];
    sal[tid] = a;
  }
  __syncthreads();
  yinit[(size_t)b*HID+tid]     = sal[tid>>6]       * v0s[tid];
  yinit[(size_t)b*HID+tid+256] = sal[(tid+256)>>6] * v0s[tid+256];
}

// ---------------- FUSED kernel: hln (MFMA+LN) + score + softmax.q + MFMA partial-u ----------
// Block: (b, tc). 512 threads = 8 waves; wave w = head w (phase 2) and col-slice w (1,4).
__global__ __launch_bounds__(512, 4) void k_fused(
    const float* __restrict__ logsig,
    const __hip_bfloat16* __restrict__ Wipb,   // (512,64) bf16
    const float* __restrict__ bip,
    const float* __restrict__ g_in, const float* __restrict__ b_in,
    const __hip_bfloat16* __restrict__ Wkb,    // (512,512) bf16
    const float* __restrict__ bk,
    const float* __restrict__ qws,             // (B,512)
    float* __restrict__ up,                    // (B,NH,4,512) f32 partial u
    float* __restrict__ Asp)                   // (B,NH,4) partial alpha-sum
{
  int b = blockIdx.x, tc = blockIdx.y;
  int tid = threadIdx.x;
  int w = tid >> 6, l = tid & 63, lr = l & 15, lg = l >> 4;
  __shared__ __align__(16) char Hs[64*1024];     // 64 rows x 512 bf16, swizzled
  __shared__ float red[64][8][2];
  __shared__ float ms2[64][2];
  __shared__ float als[64][8];
  __shared__ unsigned short als_bt[2][16][64];   // alpha^T bf16 hi/lo (rows 8-15 unused)

  // ---- stage logsig x-tile (64x64 f32 -> bf16) into Hs cols 0..64 ----
  {
    int row = tid >> 3, cc = (tid & 7)*8;
    const float* srow = logsig + ((size_t)b*T_ + tc*64 + row)*CIN + cc;
    float4 a = *(const float4*)(srow);
    float4 c = *(const float4*)(srow+4);
    uint4 p = { pk2(a.x,a.y), pk2(a.z,a.w), pk2(c.x,c.y), pk2(c.z,c.w) };
    *(uint4*)(Hs + HSOFF(row, cc)) = p;
  }
  __syncthreads();

  // ---- phase 1: Hpre = x @ Wip^T  (wave w -> cols w*64..w*64+63) ----
  f32x4 acc[4][4];
  #pragma unroll
  for (int i=0;i<4;i++)
    #pragma unroll
    for (int j=0;j<4;j++) acc[i][j] = (f32x4){0.f,0.f,0.f,0.f};
  #pragma unroll
  for (int kk = 0; kk < CIN; kk += 32){
    bf16x8 af[4], bfr[4];
    #pragma unroll
    for (int i=0;i<4;i++)
      af[i] = *(const bf16x8*)(Hs + HSOFF(i*16 + lr, kk + lg*8));
    #pragma unroll
    for (int j=0;j<4;j++)
      bfr[j] = *(const bf16x8*)(Wipb + (size_t)(w*64 + j*16 + lr)*CIN + kk + lg*8);
    #pragma unroll
    for (int i=0;i<4;i++)
      #pragma unroll
      for (int j=0;j<4;j++)
        acc[i][j] = __builtin_amdgcn_mfma_f32_16x16x32_bf16(af[i], bfr[j], acc[i][j], 0,0,0);
  }
  float bipv[4], gv[4], bbv[4];
  #pragma unroll
  for (int j=0;j<4;j++){
    int col = w*64 + j*16 + lr;
    bipv[j] = bip[col]; gv[j] = g_in[col]; bbv[j] = b_in[col];
  }
  // per-row stats
  #pragma unroll
  for (int i=0;i<4;i++){
    #pragma unroll
    for (int r=0;r<4;r++){
      float s = 0.f, s2 = 0.f;
      #pragma unroll
      for (int j=0;j<4;j++){ float v = acc[i][j][r] + bipv[j]; s += v; s2 += v*v; }
      #pragma unroll
      for (int o=1;o<16;o<<=1){ s += __shfl_xor(s,o); s2 += __shfl_xor(s2,o); }
      if (lr == 0){ int row = i*16 + lg*4 + r; red[row][w][0] = s; red[row][w][1] = s2; }
    }
  }
  __syncthreads();
  if (tid < 64){
    float S = 0.f, S2 = 0.f;
    #pragma unroll
    for (int k=0;k<8;k++){ S += red[tid][k][0]; S2 += red[tid][k][1]; }
    float m = S*(1.f/512.f), var = S2*(1.f/512.f) - m*m;
    ms2[tid][0] = m; ms2[tid][1] = rsqrtf(var + 1e-5f);
  }
  __syncthreads();
  // write normalized bf16 tile into Hs
  #pragma unroll
  for (int i=0;i<4;i++){
    #pragma unroll
    for (int r=0;r<4;r++){
      int row = i*16 + lg*4 + r;
      float m = ms2[row][0], rs = ms2[row][1];
      #pragma unroll
      for (int j=0;j<4;j++){
        int col = w*64 + j*16 + lr;
        float v = (acc[i][j][r] + bipv[j] - m)*rs*gv[j] + bbv[j];
        *(unsigned short*)(Hs + HSOFF(row, col)) =
            __bfloat16_as_ushort(__float2bfloat16(v));
      }
    }
  }
  __syncthreads();

  // ---- phase 2: scores S = Hln @ Wk_h^T (wave w = head w), A from LDS ----
  #pragma unroll
  for (int i=0;i<4;i++)
    #pragma unroll
    for (int j=0;j<4;j++) acc[i][j] = (f32x4){0.f,0.f,0.f,0.f};
  const __hip_bfloat16* Bbase = Wkb + (size_t)(w*64)*HID;
  for (int kk = 0; kk < HID; kk += 32){
    bf16x8 af[4], bfr[4];
    #pragma unroll
    for (int i=0;i<4;i++)
      af[i] = *(const bf16x8*)(Hs + HSOFF(i*16 + lr, kk + lg*8));
    #pragma unroll
    for (int j=0;j<4;j++)
      bfr[j] = *(const bf16x8*)(Bbase + (size_t)(j*16 + lr)*HID + kk + lg*8);
    #pragma unroll
    for (int i=0;i<4;i++)
      #pragma unroll
      for (int j=0;j<4;j++)
        acc[i][j] = __builtin_amdgcn_mfma_f32_16x16x32_bf16(af[i], bfr[j], acc[i][j], 0,0,0);
  }

  // ---- phase 3: per-row softmax over head cols, dot q, RK4 weight -> als (+bf16 hi/lo T) ----
  {
    float bkv[4], qv[4];
    #pragma unroll
    for (int j=0;j<4;j++){
      bkv[j] = bk[w*64 + j*16 + lr];
      qv[j]  = qws[(size_t)b*HID + w*64 + j*16 + lr];
    }
    #pragma unroll
    for (int i=0;i<4;i++){
      #pragma unroll
      for (int r=0;r<4;r++){
        float v0 = acc[i][0][r]+bkv[0], v1 = acc[i][1][r]+bkv[1];
        float v2 = acc[i][2][r]+bkv[2], v3 = acc[i][3][r]+bkv[3];
        float mx = fmaxf(fmaxf(v0,v1),fmaxf(v2,v3));
        #pragma unroll
        for (int o=1;o<16;o<<=1) mx = fmaxf(mx, __shfl_xor(mx,o));
        float e0=__expf(v0-mx), e1=__expf(v1-mx), e2=__expf(v2-mx), e3=__expf(v3-mx);
        float se = e0+e1+e2+e3;
        float sq = e0*qv[0]+e1*qv[1]+e2*qv[2]+e3*qv[3];
        #pragma unroll
        for (int o=1;o<16;o<<=1){ se += __shfl_xor(se,o); sq += __shfl_xor(sq,o); }
        if (lr == 0){
          int row = i*16 + lg*4 + r;
          int t = tc*64 + row;
          float wt = (t == 0) ? (5.f/6.f) : ((t == T_-1) ? (1.f/6.f) : 1.f);
          float alpha = wt * sq / se;
          als[row][w] = alpha;
          __hip_bfloat16 ah = __float2bfloat16(alpha);
          float rem = alpha - __bfloat162float(ah);
          als_bt[0][w][row] = __bfloat16_as_ushort(ah);
          als_bt[1][w][row] = __bfloat16_as_ushort(__float2bfloat16(rem));
        }
      }
    }
  }
  __syncthreads();

  // ---- phase 4: u = alpha^T @ H via MFMA (M=8 heads, N=64 cols/wave, K=64 rows) ----
  {
    f32x4 uacc[4];
    #pragma unroll
    for (int t=0;t<4;t++) uacc[t] = (f32x4){0.f,0.f,0.f,0.f};
    #pragma unroll
    for (int ks=0; ks<2; ks++){
      bf16x8 afh = *(const bf16x8*)&als_bt[0][lr][ks*32 + lg*8];
      bf16x8 afl = *(const bf16x8*)&als_bt[1][lr][ks*32 + lg*8];
      #pragma unroll
      for (int t=0;t<4;t++){
        int col = w*64 + t*16 + lr;
        union { unsigned u[4]; bf16x8 v; } bb;
        #pragma unroll
        for (int j2=0;j2<4;j2++){
          int r0 = ks*32 + lg*8 + 2*j2;
          unsigned lo = *(const unsigned short*)(Hs + HSOFF(r0,   col));
          unsigned hi = *(const unsigned short*)(Hs + HSOFF(r0+1, col));
          bb.u[j2] = lo | (hi << 16);
        }
        uacc[t] = __builtin_amdgcn_mfma_f32_16x16x32_bf16(afh, bb.v, uacc[t], 0,0,0);
        uacc[t] = __builtin_amdgcn_mfma_f32_16x16x32_bf16(afl, bb.v, uacc[t], 0,0,0);
      }
    }
    if (lg < 2){
      #pragma unroll
      for (int t=0;t<4;t++){
        #pragma unroll
        for (int rr=0; rr<4; rr++){
          int h = lg*4 + rr;
          up[((((size_t)b*NH + h)*4 + tc)*HID) + w*64 + t*16 + lr] = uacc[t][rr];
        }
      }
    }
    float s = als[l][w];
    #pragma unroll
    for (int o=1;o<64;o<<=1) s += __shfl_xor(s,o);
    if (l == 0) Asp[(((size_t)b*NH + w)*4) + tc] = s;
  }
}

// ---------------- reduce partials: u_bf (bf16) and Asum ----------------
__global__ __launch_bounds__(256) void k_ured(
    const float* __restrict__ up, const float* __restrict__ Asp,
    __hip_bfloat16* __restrict__ u_bf, float* __restrict__ Asum)
{
  int bh = blockIdx.x, tid = threadIdx.x;
  size_t base = (size_t)bh*4*HID;
  float s0 = 0.f, s1 = 0.f;
  #pragma unroll
  for (int c=0;c<4;c++){
    s0 += up[base + (size_t)c*HID + 2*tid];
    s1 += up[base + (size_t)c*HID + 2*tid+1];
  }
  ((unsigned*)u_bf)[(size_t)bh*(HID/2) + tid] = pk2(s0, s1);
  if (tid == 0)
    Asum[bh] = Asp[(size_t)bh*4] + Asp[(size_t)bh*4+1] + Asp[(size_t)bh*4+2] + Asp[(size_t)bh*4+3];
}

// ---------------- kernel C1: yh = u @ Wv_h^T + yinit + bv*Asum -> bf16 ----------------
__global__ __launch_bounds__(256) void k_yhead(
    const __hip_bfloat16* __restrict__ u_bf,   // (B,8,512)
    const __hip_bfloat16* __restrict__ Wvb,    // (512,512)
    const float* __restrict__ bv, const float* __restrict__ Asum,
    const float* __restrict__ yinit,
    __hip_bfloat16* __restrict__ yh)           // (B,512) bf16
{
  int mb = blockIdx.x, h = blockIdx.y;
  int tid = threadIdx.x;
  int w = tid >> 6, l = tid & 63, lr = l & 15, lg = l >> 4;
  int row0 = mb*64 + w*16;
  const __hip_bfloat16* Abase = u_bf + ((size_t)(row0 + lr)*NH + h)*HID;
  const __hip_bfloat16* Bbase = Wvb + (size_t)(h*64)*HID;
  f32x4 acc[4];
  #pragma unroll
  for (int j=0;j<4;j++) acc[j] = (f32x4){0.f,0.f,0.f,0.f};
  for (int kk = 0; kk < HID; kk += 32){
    bf16x8 af = *(const bf16x8*)(Abase + kk + lg*8);
    #pragma unroll
    for (int j=0;j<4;j++){
      bf16x8 bfr = *(const bf16x8*)(Bbase + (size_t)(j*16 + lr)*HID + kk + lg*8);
      acc[j] = __builtin_amdgcn_mfma_f32_16x16x32_bf16(af, bfr, acc[j], 0,0,0);
    }
  }
  #pragma unroll
  for (int j=0;j<4;j++){
    int col = h*64 + j*16 + lr;
    float bvc = bv[col];
    #pragma unroll
    for (int r=0;r<4;r++){
      int row = row0 + lg*4 + r;
      float v = acc[j][r] + yinit[(size_t)row*HID + col] + bvc*Asum[(size_t)row*NH + h];
      yh[(size_t)row*HID + col] = __float2bfloat16(v);
    }
  }
}

// ---------------- kernel C1b: yo = yh @ Wo^T + bo (f32 out) ----------------
__global__ __launch_bounds__(256) void k_yo(
    const __hip_bfloat16* __restrict__ yh,   // (B,512)
    const __hip_bfloat16* __restrict__ Wob,  // (512,512)
    const float* __restrict__ bo,
    float* __restrict__ yo)                  // (B,512)
{
  int mb = blockIdx.x, nb = blockIdx.y;
  int tid = threadIdx.x;
  int w = tid >> 6, l = tid & 63, lr = l & 15, lg = l >> 4;
  int row0 = mb*64 + w*16;
  const __hip_bfloat16* Abase = yh + (size_t)(row0 + lr)*HID;
  const __hip_bfloat16* Bbase = Wob + (size_t)(nb*64)*HID;
  f32x4 acc[4];
  #pragma unroll
  for (int j=0;j<4;j++) acc[j] = (f32x4){0.f,0.f,0.f,0.f};
  for (int kk = 0; kk < HID; kk += 32){
    bf16x8 af = *(const bf16x8*)(Abase + kk + lg*8);
    #pragma unroll
    for (int j=0;j<4;j++){
      bf16x8 bfr = *(const bf16x8*)(Bbase + (size_t)(j*16 + lr)*HID + kk + lg*8);
      acc[j] = __builtin_amdgcn_mfma_f32_16x16x32_bf16(af, bfr, acc[j], 0,0,0);
    }
  }
  #pragma unroll
  for (int j=0;j<4;j++){
    int col = nb*64 + j*16 + lr;
    float bc = bo[col];
    #pragma unroll
    for (int r=0;r<4;r++){
      int row = row0 + lg*4 + r;
      yo[(size_t)row*HID + col] = acc[j][r] + bc;
    }
  }
}

// ---------------- kernel C2: row LN of yo -> yln bf16 ----------------
__global__ __launch_bounds__(256) void k_ln2(
    const float* __restrict__ yo,
    const float* __restrict__ g_ff, const float* __restrict__ b_ff,
    __hip_bfloat16* __restrict__ yln)
{
  int tid = threadIdx.x;
  int row = blockIdx.x*32 + (tid >> 3), sub = tid & 7;
  const float4* yr = (const float4*)(yo + (size_t)row*HID) + sub*16;
  float4 v[16];
  float s = 0.f, s2 = 0.f;
  #pragma unroll
  for (int k=0;k<16;k++){
    v[k] = yr[k];
    s  += v[k].x+v[k].y+v[k].z+v[k].w;
    s2 += v[k].x*v[k].x+v[k].y*v[k].y+v[k].z*v[k].z+v[k].w*v[k].w;
  }
  #pragma unroll
  for (int o=1;o<8;o<<=1){ s += __shfl_xor(s,o); s2 += __shfl_xor(s2,o); }
  float m = s*(1.f/512.f), rs = rsqrtf(s2*(1.f/512.f) - m*m + 1e-5f);
  #pragma unroll
  for (int k=0;k<16;k++){
    int c = sub*64 + k*4;
    float o0 = (v[k].x-m)*rs*g_ff[c]   + b_ff[c];
    float o1 = (v[k].y-m)*rs*g_ff[c+1] + b_ff[c+1];
    float o2 = (v[k].z-m)*rs*g_ff[c+2] + b_ff[c+2];
    float o3 = (v[k].w-m)*rs*g_ff[c+3] + b_ff[c+3];
    yln[(size_t)row*HID + c]   = __float2bfloat16(o0);
    yln[(size_t)row*HID + c+1] = __float2bfloat16(o1);
    yln[(size_t)row*HID + c+2] = __float2bfloat16(o2);
    yln[(size_t)row*HID + c+3] = __float2bfloat16(o3);
  }
}

// ---------------- kernel C3: a1 = relu(yln @ W1^T + b1) bf16 ----------------
__global__ __launch_bounds__(256) void k_ff1(
    const __hip_bfloat16* __restrict__ yln,  // (B,512)
    const __hip_bfloat16* __restrict__ W1b,  // (2048,512)
    const float* __restrict__ b1,
    __hip_bfloat16* __restrict__ a1b)        // (B,2048)
{
  int mb = blockIdx.x, nb = blockIdx.y;
  int tid = threadIdx.x;
  int w = tid >> 6, l = tid & 63, lr = l & 15, lg = l >> 4;
  int row0 = mb*64 + w*16;
  const __hip_bfloat16* Abase = yln + (size_t)(row0 + lr)*HID;
  const __hip_bfloat16* Bbase = W1b + (size_t)(nb*64)*HID;
  f32x4 acc[4];
  #pragma unroll
  for (int j=0;j<4;j++) acc[j] = (f32x4){0.f,0.f,0.f,0.f};
  for (int kk = 0; kk < HID; kk += 32){
    bf16x8 af = *(const bf16x8*)(Abase + kk + lg*8);
    #pragma unroll
    for (int j=0;j<4;j++){
      bf16x8 bfr = *(const bf16x8*)(Bbase + (size_t)(j*16 + lr)*HID + kk + lg*8);
      acc[j] = __builtin_amdgcn_mfma_f32_16x16x32_bf16(af, bfr, acc[j], 0,0,0);
    }
  }
  #pragma unroll
  for (int j=0;j<4;j++){
    int col = nb*64 + j*16 + lr;
    float bc = b1[col];
    #pragma unroll
    for (int r=0;r<4;r++){
      int row = row0 + lg*4 + r;
      a1b[(size_t)row*FFD + col] = __float2bfloat16(fmaxf(acc[j][r] + bc, 0.f));
    }
  }
}

// ---------------- kernel C4: y2 = a1 @ W2^T + b2 + yo ----------------
__global__ __launch_bounds__(256) void k_ff2(
    const __hip_bfloat16* __restrict__ a1b,  // (B,2048)
    const __hip_bfloat16* __restrict__ W2b,  // (512,2048)
    const float* __restrict__ b2,
    const float* __restrict__ yo,
    float* __restrict__ y2)                  // (B,512)
{
  int mb = blockIdx.x, nb = blockIdx.y;
  int tid = threadIdx.x;
  int w = tid >> 6, l = tid & 63, lr = l & 15, lg = l >> 4;
  int row0 = mb*64 + w*16;
  const __hip_bfloat16* Abase = a1b + (size_t)(row0 + lr)*FFD;
  const __hip_bfloat16* Bbase = W2b + (size_t)(nb*64)*FFD;
  f32x4 acc[4];
  #pragma unroll
  for (int j=0;j<4;j++) acc[j] = (f32x4){0.f,0.f,0.f,0.f};
  for (int kk = 0; kk < FFD; kk += 32){
    bf16x8 af = *(const bf16x8*)(Abase + kk + lg*8);
    #pragma unroll
    for (int j=0;j<4;j++){
      bf16x8 bfr = *(const bf16x8*)(Bbase + (size_t)(j*16 + lr)*FFD + kk + lg*8);
      acc[j] = __builtin_amdgcn_mfma_f32_16x16x32_bf16(af, bfr, acc[j], 0,0,0);
    }
  }
  #pragma unroll
  for (int j=0;j<4;j++){
    int col = nb*64 + j*16 + lr;
    float bc = b2[col];
    #pragma unroll
    for (int r=0;r<4;r++){
      int row = row0 + lg*4 + r;
      y2[(size_t)row*HID + col] = acc[j][r] + bc + yo[(size_t)row*HID + col];
    }
  }
}

// ---------------- kernel C5: out = y2 @ Wf^T + bf ----------------
__global__ __launch_bounds__(256) void k_final(
    const float* __restrict__ y2,
    const float* __restrict__ Wf, const float* __restrict__ bfv,
    float* __restrict__ out)
{
  int tid = threadIdx.x;
  int b0 = blockIdx.x*64;
  for (int i = tid; i < 64*OUTD; i += 256){
    int r = b0 + i/OUTD, c = i%OUTD;
    out[(size_t)r*OUTD + c] = bfv[c] + dot_ld4(Wf + (size_t)c*HID, y2 + (size_t)r*HID, HID/4);
  }
}

extern "C" void kernel_launch(void* const* d_in, const int* in_sizes, int n_in,
                              void* d_out, int out_size, void* d_ws, size_t ws_size,
                              hipStream_t stream)
{
  const float* initial = (const float*)d_in[0];
  const float* logsig  = (const float*)d_in[1];
  const float* Wi  = (const float*)d_in[2];  const float* bi  = (const float*)d_in[3];
  const float* Wip = (const float*)d_in[4];  const float* bip = (const float*)d_in[5];
  const float* g_in= (const float*)d_in[6];  const float* b_in= (const float*)d_in[7];
  const float* Wk  = (const float*)d_in[8];  const float* bk  = (const float*)d_in[9];
  const float* Wv  = (const float*)d_in[10]; const float* bv  = (const float*)d_in[11];
  const float* Wq  = (const float*)d_in[12]; const float* bq  = (const float*)d_in[13];
  const float* Wo  = (const float*)d_in[14]; const float* bo  = (const float*)d_in[15];
  const float* g_ff= (const float*)d_in[16]; const float* b_ff= (const float*)d_in[17];
  const float* W1  = (const float*)d_in[18]; const float* b1  = (const float*)d_in[19];
  const float* W2  = (const float*)d_in[20]; const float* b2  = (const float*)d_in[21];
  const float* Wf  = (const float*)d_in[22]; const float* bf  = (const float*)d_in[23];
  float* out = (float*)d_out;

  char* ws = (char*)d_ws;
  const size_t MB = 1<<20;
  float* qws   = (float*)(ws);                             // 512 KB
  float* yinit = (float*)(ws + 512*1024);                  // 512 KB
  __hip_bfloat16* u_bf = (__hip_bfloat16*)(ws + 3*MB);     // 2 MB
  float* Asum  = (float*)(ws + 5*MB);                      // 8 KB
  __hip_bfloat16* Wkb = (__hip_bfloat16*)(ws + 5*MB + 512*1024);  // 512 KB
  __hip_bfloat16* Wvb = (__hip_bfloat16*)(ws + 6*MB);      // 512 KB
  __hip_bfloat16* W1b = (__hip_bfloat16*)(ws + 6*MB + 512*1024);  // 2 MB
  __hip_bfloat16* W2b = (__hip_bfloat16*)(ws + 8*MB + 512*1024);  // 2 MB
  float* y2    = (float*)(ws + 10*MB + 512*1024);          // 512 KB
  __hip_bfloat16* yln = (__hip_bfloat16*)(ws + 11*MB);     // 256 KB
  __hip_bfloat16* a1b = (__hip_bfloat16*)(ws + 11*MB + 512*1024); // 1 MB
  __hip_bfloat16* Wob = (__hip_bfloat16*)(ws + 13*MB);     // 512 KB
  __hip_bfloat16* yh  = (__hip_bfloat16*)(ws + 13*MB + 512*1024); // 256 KB
  float* yo    = (float*)(ws + 14*MB);                     // 512 KB
  __hip_bfloat16* Wipb = (__hip_bfloat16*)(ws + 15*MB);    // 64 KB
  float* up    = (float*)(ws + 16*MB);                     // 16 MB
  float* Asp   = (float*)(ws + 33*MB);                     // 32 KB

  k_cvt6<<<dim3((CVT_TOT + 255)/256), 256, 0, stream>>>(
      Wk, Wv, Wo, W1, W2, Wip, Wkb, Wvb, Wob, W1b, W2b, Wipb);
  k_init<<<B_, 256, 0, stream>>>(initial, logsig, Wi, bi, Wip, bip, g_in, b_in,
                                 Wk, bk, Wv, bv, Wq, bq, qws, yinit);
  k_fused<<<dim3(B_, 4), 512, 0, stream>>>(logsig, Wipb, bip, g_in, b_in,
                                           Wkb, bk, qws, up, Asp);
  k_ured<<<dim3(B_*NH), 256, 0, stream>>>(up, Asp, u_bf, Asum);
  k_yhead<<<dim3(B_/64, NH), 256, 0, stream>>>(u_bf, Wvb, bv, Asum, yinit, yh);
  k_yo<<<dim3(B_/64, HID/64), 256, 0, stream>>>(yh, Wob, bo, yo);
  k_ln2<<<dim3(B_/32), 256, 0, stream>>>(yo, g_ff, b_ff, yln);
  k_ff1<<<dim3(B_/64, FFD/64), 256, 0, stream>>>(yln, W1b, b1, a1b);
  k_ff2<<<dim3(B_/64, HID/64), 256, 0, stream>>>(a1b, W2b, b2, yo, y2);
  k_final<<<dim3(B_/64), 256, 0, stream>>>(y2, Wf, bf, out);
}

// Round 8
// 341.499 us; speedup vs baseline: 3.9694x; 1.0537x over previous
//
#include <hip/hip_runtime.h>
#include <hip/hip_bf16.h>
#include <math.h>

#define B_ 256
#define T_ 256
#define CIN 64
#define HID 512
#define NH 8
#define HD 64
#define FFD 2048
#define OUTD 10

typedef __bf16 bf16x8 __attribute__((ext_vector_type(8)));
typedef float f32x4 __attribute__((ext_vector_type(4)));

// swizzled LDS byte offset for the 64x512 bf16 Hs tile (row stride 1024B)
#define HSOFF(r,c) (((r)<<10) + ((((c)<<1)) ^ ((((r)&7))<<4)))

__device__ __forceinline__ float bf2f(unsigned u){
  union { unsigned i; float f; } c; c.i = u << 16; return c.f;
}
__device__ __forceinline__ unsigned pk2(float a, float b){
  return ((unsigned)__bfloat16_as_ushort(__float2bfloat16(a))) |
         (((unsigned)__bfloat16_as_ushort(__float2bfloat16(b))) << 16);
}

__device__ __forceinline__ float dot_ld4(const float* __restrict__ w, const float* x, int n4){
  float acc = 0.f;
  const float4* w4 = (const float4*)w;
  const float4* x4 = (const float4*)x;
  for (int k = 0; k < n4; k++){
    float4 a = w4[k], b = x4[k];
    acc += a.x*b.x + a.y*b.y + a.z*b.z + a.w*b.w;
  }
  return acc;
}

// ---------------- prep: all eight f32 -> bf16 weight conversions in one launch --------------
#define CW_KV  (HID*HID)            // 262144
#define CW_IP  (HID*CIN)            // 32768
#define CW_FF  (FFD*HID)            // 1048576
#define CW_I   (CIN*128)            // 8192
#define CVT_TOT (4*CW_KV + 2*CW_FF + CW_IP + CW_I)
__global__ __launch_bounds__(256) void k_cvt8(
    const float* __restrict__ Wk, const float* __restrict__ Wv,
    const float* __restrict__ Wo, const float* __restrict__ W1,
    const float* __restrict__ W2, const float* __restrict__ Wip,
    const float* __restrict__ Wq, const float* __restrict__ Wi,
    __hip_bfloat16* __restrict__ Wkb, __hip_bfloat16* __restrict__ Wvb,
    __hip_bfloat16* __restrict__ Wob, __hip_bfloat16* __restrict__ W1b,
    __hip_bfloat16* __restrict__ W2b, __hip_bfloat16* __restrict__ Wipb,
    __hip_bfloat16* __restrict__ Wqb, __hip_bfloat16* __restrict__ Wib)
{
  int i = blockIdx.x*256 + threadIdx.x;
  if (i < CW_KV) { Wkb[i]  = __float2bfloat16(Wk[i]);  return; }  i -= CW_KV;
  if (i < CW_KV) { Wvb[i]  = __float2bfloat16(Wv[i]);  return; }  i -= CW_KV;
  if (i < CW_KV) { Wob[i]  = __float2bfloat16(Wo[i]);  return; }  i -= CW_KV;
  if (i < CW_FF) { W1b[i]  = __float2bfloat16(W1[i]);  return; }  i -= CW_FF;
  if (i < CW_FF) { W2b[i]  = __float2bfloat16(W2[i]);  return; }  i -= CW_FF;
  if (i < CW_IP) { Wipb[i] = __float2bfloat16(Wip[i]); return; }  i -= CW_IP;
  if (i < CW_KV) { Wqb[i]  = __float2bfloat16(Wq[i]);  return; }  i -= CW_KV;
  if (i < CW_I)  { Wib[i]  = __float2bfloat16(Wi[i]); }
}

// ---- shared building block: A(64x64 in Hs cols 0..64) @ Wip^T + LN -> Hs (64x512 bf16) ----
__device__ __forceinline__ void proj_ln(
    char* Hs, const __hip_bfloat16* __restrict__ Wipb,
    const float* __restrict__ bip, const float* __restrict__ g_in,
    const float* __restrict__ b_in,
    float (*red)[8][2], float (*ms2)[2],
    int tid, int w, int lr, int lg)
{
  f32x4 acc[4][4];
  #pragma unroll
  for (int i=0;i<4;i++)
    #pragma unroll
    for (int j=0;j<4;j++) acc[i][j] = (f32x4){0.f,0.f,0.f,0.f};
  #pragma unroll
  for (int kk = 0; kk < CIN; kk += 32){
    bf16x8 af[4], bfr[4];
    #pragma unroll
    for (int i=0;i<4;i++)
      af[i] = *(const bf16x8*)(Hs + HSOFF(i*16 + lr, kk + lg*8));
    #pragma unroll
    for (int j=0;j<4;j++)
      bfr[j] = *(const bf16x8*)(Wipb + (size_t)(w*64 + j*16 + lr)*CIN + kk + lg*8);
    #pragma unroll
    for (int i=0;i<4;i++)
      #pragma unroll
      for (int j=0;j<4;j++)
        acc[i][j] = __builtin_amdgcn_mfma_f32_16x16x32_bf16(af[i], bfr[j], acc[i][j], 0,0,0);
  }
  float bipv[4], gv[4], bbv[4];
  #pragma unroll
  for (int j=0;j<4;j++){
    int col = w*64 + j*16 + lr;
    bipv[j] = bip[col]; gv[j] = g_in[col]; bbv[j] = b_in[col];
  }
  #pragma unroll
  for (int i=0;i<4;i++){
    #pragma unroll
    for (int r=0;r<4;r++){
      float s = 0.f, s2 = 0.f;
      #pragma unroll
      for (int j=0;j<4;j++){ float v = acc[i][j][r] + bipv[j]; s += v; s2 += v*v; }
      #pragma unroll
      for (int o=1;o<16;o<<=1){ s += __shfl_xor(s,o); s2 += __shfl_xor(s2,o); }
      if (lr == 0){ int row = i*16 + lg*4 + r; red[row][w][0] = s; red[row][w][1] = s2; }
    }
  }
  __syncthreads();
  if (tid < 64){
    float S = 0.f, S2 = 0.f;
    #pragma unroll
    for (int k=0;k<8;k++){ S += red[tid][k][0]; S2 += red[tid][k][1]; }
    float m = S*(1.f/512.f), var = S2*(1.f/512.f) - m*m;
    ms2[tid][0] = m; ms2[tid][1] = rsqrtf(var + 1e-5f);
  }
  __syncthreads();
  #pragma unroll
  for (int i=0;i<4;i++){
    #pragma unroll
    for (int r=0;r<4;r++){
      int row = i*16 + lg*4 + r;
      float m = ms2[row][0], rs = ms2[row][1];
      #pragma unroll
      for (int j=0;j<4;j++){
        int col = w*64 + j*16 + lr;
        float v = (acc[i][j][r] + bipv[j] - m)*rs*gv[j] + bbv[j];
        *(unsigned short*)(Hs + HSOFF(row, col)) =
            __bfloat16_as_ushort(__float2bfloat16(v));
      }
    }
  }
  __syncthreads();
}

// ---- shared building block: acc = Hs(64x512) @ Bmat_h^T (K=512), A from LDS ----
__device__ __forceinline__ void gemm512_lds(
    const char* Hs, const __hip_bfloat16* __restrict__ Bmat,
    f32x4 acc[4][4], int lr, int lg)
{
  #pragma unroll
  for (int i=0;i<4;i++)
    #pragma unroll
    for (int j=0;j<4;j++) acc[i][j] = (f32x4){0.f,0.f,0.f,0.f};
  for (int kk = 0; kk < HID; kk += 32){
    bf16x8 af[4], bfr[4];
    #pragma unroll
    for (int i=0;i<4;i++)
      af[i] = *(const bf16x8*)(Hs + HSOFF(i*16 + lr, kk + lg*8));
    #pragma unroll
    for (int j=0;j<4;j++)
      bfr[j] = *(const bf16x8*)(Bmat + (size_t)(j*16 + lr)*HID + kk + lg*8);
    #pragma unroll
    for (int i=0;i<4;i++)
      #pragma unroll
      for (int j=0;j<4;j++)
        acc[i][j] = __builtin_amdgcn_mfma_f32_16x16x32_bf16(af[i], bfr[j], acc[i][j], 0,0,0);
  }
}

// ---------------- k_pre: batched init path (q, yinit) via MFMA, 64 batch rows/block --------
__global__ __launch_bounds__(512) void k_pre(
    const float* __restrict__ initial, const float* __restrict__ logsig,
    const __hip_bfloat16* __restrict__ Wib,  const float* __restrict__ bi,
    const __hip_bfloat16* __restrict__ Wipb, const float* __restrict__ bip,
    const float* __restrict__ g_in, const float* __restrict__ b_in,
    const __hip_bfloat16* __restrict__ Wqb, const float* __restrict__ bq,
    const __hip_bfloat16* __restrict__ Wkb, const float* __restrict__ bk,
    const __hip_bfloat16* __restrict__ Wvb, const float* __restrict__ bv,
    float* __restrict__ qout, float* __restrict__ yinit)
{
  int b0 = blockIdx.x*64;
  int tid = threadIdx.x;
  int w = tid >> 6, l = tid & 63, lr = l & 15, lg = l >> 4;
  __shared__ __align__(16) char Hs[64*1024];
  __shared__ float red[64][8][2];
  __shared__ float ms2[64][2];
  __shared__ float salS[64][8];
  f32x4 acc[4][4];

  // ---- phase A: stage xlast (64 batch rows x 64) -> Hs cols 0..64, then hq = LN(x@Wip^T) ----
  {
    int row = tid >> 3, cc = (tid & 7)*8;
    const float* srow = logsig + ((size_t)(b0+row)*T_ + (T_-1))*CIN + cc;
    float4 a = *(const float4*)(srow);
    float4 c = *(const float4*)(srow+4);
    uint4 p = { pk2(a.x,a.y), pk2(a.z,a.w), pk2(c.x,c.y), pk2(c.z,c.w) };
    *(uint4*)(Hs + HSOFF(row, cc)) = p;
  }
  __syncthreads();
  proj_ln(Hs, Wipb, bip, g_in, b_in, red, ms2, tid, w, lr, lg);

  // ---- phase B: q = softmax_h(hq @ Wq_h^T + bq); keep q in registers, write qout ----
  float qreg[4][4][4];
  gemm512_lds(Hs, Wqb + (size_t)(w*64)*HID, acc, lr, lg);
  {
    float bqv[4];
    #pragma unroll
    for (int j=0;j<4;j++) bqv[j] = bq[w*64 + j*16 + lr];
    #pragma unroll
    for (int i=0;i<4;i++){
      #pragma unroll
      for (int r=0;r<4;r++){
        float v0 = acc[i][0][r]+bqv[0], v1 = acc[i][1][r]+bqv[1];
        float v2 = acc[i][2][r]+bqv[2], v3 = acc[i][3][r]+bqv[3];
        float mx = fmaxf(fmaxf(v0,v1),fmaxf(v2,v3));
        #pragma unroll
        for (int o=1;o<16;o<<=1) mx = fmaxf(mx, __shfl_xor(mx,o));
        float e0=__expf(v0-mx), e1=__expf(v1-mx), e2=__expf(v2-mx), e3=__expf(v3-mx);
        float se = e0+e1+e2+e3;
        #pragma unroll
        for (int o=1;o<16;o<<=1) se += __shfl_xor(se,o);
        float inv = 1.f/se;
        float q0=e0*inv, q1=e1*inv, q2=e2*inv, q3=e3*inv;
        qreg[i][0][r]=q0; qreg[i][1][r]=q1; qreg[i][2][r]=q2; qreg[i][3][r]=q3;
        int row = i*16 + lg*4 + r;
        size_t base = (size_t)(b0+row)*HID + w*64 + lr;
        qout[base +  0] = q0; qout[base + 16] = q1;
        qout[base + 32] = q2; qout[base + 48] = q3;
      }
    }
  }
  __syncthreads();

  // ---- phase C: stage initial (64x128) -> Hs cols 64..192; ip = initial@Wi^T + bi -> cols 0..64
  {
    int row = tid >> 3, c0 = (tid & 7)*16;
    const float* srow = initial + (size_t)(b0+row)*128 + c0;
    float4 a0 = *(const float4*)(srow);
    float4 a1 = *(const float4*)(srow+4);
    float4 a2 = *(const float4*)(srow+8);
    float4 a3 = *(const float4*)(srow+12);
    uint4 p0 = { pk2(a0.x,a0.y), pk2(a0.z,a0.w), pk2(a1.x,a1.y), pk2(a1.z,a1.w) };
    uint4 p1 = { pk2(a2.x,a2.y), pk2(a2.z,a2.w), pk2(a3.x,a3.y), pk2(a3.z,a3.w) };
    *(uint4*)(Hs + HSOFF(row, 64 + c0))     = p0;
    *(uint4*)(Hs + HSOFF(row, 64 + c0 + 8)) = p1;
  }
  __syncthreads();
  if (w < 4){
    f32x4 acc2[4];
    #pragma unroll
    for (int j=0;j<4;j++) acc2[j] = (f32x4){0.f,0.f,0.f,0.f};
    #pragma unroll
    for (int kk = 0; kk < 128; kk += 32){
      bf16x8 af = *(const bf16x8*)(Hs + HSOFF(w*16 + lr, 64 + kk + lg*8));
      #pragma unroll
      for (int j=0;j<4;j++){
        bf16x8 bfr = *(const bf16x8*)(Wib + (size_t)(j*16 + lr)*128 + kk + lg*8);
        acc2[j] = __builtin_amdgcn_mfma_f32_16x16x32_bf16(af, bfr, acc2[j], 0,0,0);
      }
    }
    #pragma unroll
    for (int j=0;j<4;j++){
      int col = j*16 + lr;
      float bic = bi[col];
      #pragma unroll
      for (int r=0;r<4;r++){
        int row = w*16 + lg*4 + r;
        *(unsigned short*)(Hs + HSOFF(row, col)) =
            __bfloat16_as_ushort(__float2bfloat16(acc2[j][r] + bic));
      }
    }
  }
  __syncthreads();

  // ---- phase D: h0 = LN(ip @ Wip^T) -> Hs ----
  proj_ln(Hs, Wipb, bip, g_in, b_in, red, ms2, tid, w, lr, lg);

  // ---- phase E: k0 scores; sal = softmax(k0).q ----
  gemm512_lds(Hs, Wkb + (size_t)(w*64)*HID, acc, lr, lg);
  {
    float bkv[4];
    #pragma unroll
    for (int j=0;j<4;j++) bkv[j] = bk[w*64 + j*16 + lr];
    #pragma unroll
    for (int i=0;i<4;i++){
      #pragma unroll
      for (int r=0;r<4;r++){
        float v0 = acc[i][0][r]+bkv[0], v1 = acc[i][1][r]+bkv[1];
        float v2 = acc[i][2][r]+bkv[2], v3 = acc[i][3][r]+bkv[3];
        float mx = fmaxf(fmaxf(v0,v1),fmaxf(v2,v3));
        #pragma unroll
        for (int o=1;o<16;o<<=1) mx = fmaxf(mx, __shfl_xor(mx,o));
        float e0=__expf(v0-mx), e1=__expf(v1-mx), e2=__expf(v2-mx), e3=__expf(v3-mx);
        float se = e0+e1+e2+e3;
        float sq = e0*qreg[i][0][r]+e1*qreg[i][1][r]+e2*qreg[i][2][r]+e3*qreg[i][3][r];
        #pragma unroll
        for (int o=1;o<16;o<<=1){ se += __shfl_xor(se,o); sq += __shfl_xor(sq,o); }
        if (lr == 0) salS[i*16 + lg*4 + r][w] = sq/se;
      }
    }
  }
  __syncthreads();

  // ---- phase F: v0; yinit = sal * v0 ----
  gemm512_lds(Hs, Wvb + (size_t)(w*64)*HID, acc, lr, lg);
  {
    float bvv[4];
    #pragma unroll
    for (int j=0;j<4;j++) bvv[j] = bv[w*64 + j*16 + lr];
    #pragma unroll
    for (int i=0;i<4;i++){
      #pragma unroll
      for (int r=0;r<4;r++){
        int row = i*16 + lg*4 + r;
        float s = salS[row][w];
        size_t base = (size_t)(b0+row)*HID + w*64 + lr;
        yinit[base +  0] = s*(acc[i][0][r]+bvv[0]);
        yinit[base + 16] = s*(acc[i][1][r]+bvv[1]);
        yinit[base + 32] = s*(acc[i][2][r]+bvv[2]);
        yinit[base + 48] = s*(acc[i][3][r]+bvv[3]);
      }
    }
  }
}

// ---------------- FUSED kernel: hln (MFMA+LN) + score + softmax.q + MFMA partial-u ----------
__global__ __launch_bounds__(512, 4) void k_fused(
    const float* __restrict__ logsig,
    const __hip_bfloat16* __restrict__ Wipb,   // (512,64) bf16
    const float* __restrict__ bip,
    const float* __restrict__ g_in, const float* __restrict__ b_in,
    const __hip_bfloat16* __restrict__ Wkb,    // (512,512) bf16
    const float* __restrict__ bk,
    const float* __restrict__ qws,             // (B,512)
    float* __restrict__ up,                    // (B,NH,4,512) f32 partial u
    float* __restrict__ Asp)                   // (B,NH,4) partial alpha-sum
{
  int b = blockIdx.x, tc = blockIdx.y;
  int tid = threadIdx.x;
  int w = tid >> 6, l = tid & 63, lr = l & 15, lg = l >> 4;
  __shared__ __align__(16) char Hs[64*1024];     // 64 rows x 512 bf16, swizzled
  __shared__ float red[64][8][2];
  __shared__ float ms2[64][2];
  __shared__ float als[64][8];
  __shared__ unsigned short als_bt[2][16][64];   // alpha^T bf16 hi/lo (rows 8-15 unused)

  // ---- stage logsig x-tile (64x64 f32 -> bf16) into Hs cols 0..64 ----
  {
    int row = tid >> 3, cc = (tid & 7)*8;
    const float* srow = logsig + ((size_t)b*T_ + tc*64 + row)*CIN + cc;
    float4 a = *(const float4*)(srow);
    float4 c = *(const float4*)(srow+4);
    uint4 p = { pk2(a.x,a.y), pk2(a.z,a.w), pk2(c.x,c.y), pk2(c.z,c.w) };
    *(uint4*)(Hs + HSOFF(row, cc)) = p;
  }
  __syncthreads();

  // ---- phase 1: Hln = LN(x @ Wip^T + bip) ----
  proj_ln(Hs, Wipb, bip, g_in, b_in, red, ms2, tid, w, lr, lg);

  // ---- phase 2: scores S = Hln @ Wk_h^T (wave w = head w), A from LDS ----
  f32x4 acc[4][4];
  gemm512_lds(Hs, Wkb + (size_t)(w*64)*HID, acc, lr, lg);

  // ---- phase 3: per-row softmax over head cols, dot q, RK4 weight -> als (+bf16 hi/lo T) ----
  {
    float bkv[4], qv[4];
    #pragma unroll
    for (int j=0;j<4;j++){
      bkv[j] = bk[w*64 + j*16 + lr];
      qv[j]  = qws[(size_t)b*HID + w*64 + j*16 + lr];
    }
    #pragma unroll
    for (int i=0;i<4;i++){
      #pragma unroll
      for (int r=0;r<4;r++){
        float v0 = acc[i][0][r]+bkv[0], v1 = acc[i][1][r]+bkv[1];
        float v2 = acc[i][2][r]+bkv[2], v3 = acc[i][3][r]+bkv[3];
        float mx = fmaxf(fmaxf(v0,v1),fmaxf(v2,v3));
        #pragma unroll
        for (int o=1;o<16;o<<=1) mx = fmaxf(mx, __shfl_xor(mx,o));
        float e0=__expf(v0-mx), e1=__expf(v1-mx), e2=__expf(v2-mx), e3=__expf(v3-mx);
        float se = e0+e1+e2+e3;
        float sq = e0*qv[0]+e1*qv[1]+e2*qv[2]+e3*qv[3];
        #pragma unroll
        for (int o=1;o<16;o<<=1){ se += __shfl_xor(se,o); sq += __shfl_xor(sq,o); }
        if (lr == 0){
          int row = i*16 + lg*4 + r;
          int t = tc*64 + row;
          float wt = (t == 0) ? (5.f/6.f) : ((t == T_-1) ? (1.f/6.f) : 1.f);
          float alpha = wt * sq / se;
          als[row][w] = alpha;
          __hip_bfloat16 ah = __float2bfloat16(alpha);
          float rem = alpha - __bfloat162float(ah);
          als_bt[0][w][row] = __bfloat16_as_ushort(ah);
          als_bt[1][w][row] = __bfloat16_as_ushort(__float2bfloat16(rem));
        }
      }
    }
  }
  __syncthreads();

  // ---- phase 4: u = alpha^T @ H via MFMA (M=8 heads, N=64 cols/wave, K=64 rows) ----
  {
    f32x4 uacc[4];
    #pragma unroll
    for (int t=0;t<4;t++) uacc[t] = (f32x4){0.f,0.f,0.f,0.f};
    #pragma unroll
    for (int ks=0; ks<2; ks++){
      bf16x8 afh = *(const bf16x8*)&als_bt[0][lr][ks*32 + lg*8];
      bf16x8 afl = *(const bf16x8*)&als_bt[1][lr][ks*32 + lg*8];
      #pragma unroll
      for (int t=0;t<4;t++){
        int col = w*64 + t*16 + lr;
        union { unsigned u[4]; bf16x8 v; } bb;
        #pragma unroll
        for (int j2=0;j2<4;j2++){
          int r0 = ks*32 + lg*8 + 2*j2;
          unsigned lo = *(const unsigned short*)(Hs + HSOFF(r0,   col));
          unsigned hi = *(const unsigned short*)(Hs + HSOFF(r0+1, col));
          bb.u[j2] = lo | (hi << 16);
        }
        uacc[t] = __builtin_amdgcn_mfma_f32_16x16x32_bf16(afh, bb.v, uacc[t], 0,0,0);
        uacc[t] = __builtin_amdgcn_mfma_f32_16x16x32_bf16(afl, bb.v, uacc[t], 0,0,0);
      }
    }
    if (lg < 2){
      #pragma unroll
      for (int t=0;t<4;t++){
        #pragma unroll
        for (int rr=0; rr<4; rr++){
          int h = lg*4 + rr;
          up[((((size_t)b*NH + h)*4 + tc)*HID) + w*64 + t*16 + lr] = uacc[t][rr];
        }
      }
    }
    float s = als[l][w];
    #pragma unroll
    for (int o=1;o<64;o<<=1) s += __shfl_xor(s,o);
    if (l == 0) Asp[(((size_t)b*NH + w)*4) + tc] = s;
  }
}

// ---------------- reduce partials: u_bf (bf16) and Asum ----------------
__global__ __launch_bounds__(256) void k_ured(
    const float* __restrict__ up, const float* __restrict__ Asp,
    __hip_bfloat16* __restrict__ u_bf, float* __restrict__ Asum)
{
  int bh = blockIdx.x, tid = threadIdx.x;
  size_t base = (size_t)bh*4*HID;
  float s0 = 0.f, s1 = 0.f;
  #pragma unroll
  for (int c=0;c<4;c++){
    s0 += up[base + (size_t)c*HID + 2*tid];
    s1 += up[base + (size_t)c*HID + 2*tid+1];
  }
  ((unsigned*)u_bf)[(size_t)bh*(HID/2) + tid] = pk2(s0, s1);
  if (tid == 0)
    Asum[bh] = Asp[(size_t)bh*4] + Asp[(size_t)bh*4+1] + Asp[(size_t)bh*4+2] + Asp[(size_t)bh*4+3];
}

// ---------------- kernel C1: yh = u @ Wv_h^T + yinit + bv*Asum -> bf16 ----------------
__global__ __launch_bounds__(256) void k_yhead(
    const __hip_bfloat16* __restrict__ u_bf,   // (B,8,512)
    const __hip_bfloat16* __restrict__ Wvb,    // (512,512)
    const float* __restrict__ bv, const float* __restrict__ Asum,
    const float* __restrict__ yinit,
    __hip_bfloat16* __restrict__ yh)           // (B,512) bf16
{
  int mb = blockIdx.x, h = blockIdx.y;
  int tid = threadIdx.x;
  int w = tid >> 6, l = tid & 63, lr = l & 15, lg = l >> 4;
  int row0 = mb*64 + w*16;
  const __hip_bfloat16* Abase = u_bf + ((size_t)(row0 + lr)*NH + h)*HID;
  const __hip_bfloat16* Bbase = Wvb + (size_t)(h*64)*HID;
  f32x4 acc[4];
  #pragma unroll
  for (int j=0;j<4;j++) acc[j] = (f32x4){0.f,0.f,0.f,0.f};
  for (int kk = 0; kk < HID; kk += 32){
    bf16x8 af = *(const bf16x8*)(Abase + kk + lg*8);
    #pragma unroll
    for (int j=0;j<4;j++){
      bf16x8 bfr = *(const bf16x8*)(Bbase + (size_t)(j*16 + lr)*HID + kk + lg*8);
      acc[j] = __builtin_amdgcn_mfma_f32_16x16x32_bf16(af, bfr, acc[j], 0,0,0);
    }
  }
  #pragma unroll
  for (int j=0;j<4;j++){
    int col = h*64 + j*16 + lr;
    float bvc = bv[col];
    #pragma unroll
    for (int r=0;r<4;r++){
      int row = row0 + lg*4 + r;
      float v = acc[j][r] + yinit[(size_t)row*HID + col] + bvc*Asum[(size_t)row*NH + h];
      yh[(size_t)row*HID + col] = __float2bfloat16(v);
    }
  }
}

// ---------------- kernel C1b: yo = yh @ Wo^T + bo (f32 out) ----------------
__global__ __launch_bounds__(256) void k_yo(
    const __hip_bfloat16* __restrict__ yh,   // (B,512)
    const __hip_bfloat16* __restrict__ Wob,  // (512,512)
    const float* __restrict__ bo,
    float* __restrict__ yo)                  // (B,512)
{
  int mb = blockIdx.x, nb = blockIdx.y;
  int tid = threadIdx.x;
  int w = tid >> 6, l = tid & 63, lr = l & 15, lg = l >> 4;
  int row0 = mb*64 + w*16;
  const __hip_bfloat16* Abase = yh + (size_t)(row0 + lr)*HID;
  const __hip_bfloat16* Bbase = Wob + (size_t)(nb*64)*HID;
  f32x4 acc[4];
  #pragma unroll
  for (int j=0;j<4;j++) acc[j] = (f32x4){0.f,0.f,0.f,0.f};
  for (int kk = 0; kk < HID; kk += 32){
    bf16x8 af = *(const bf16x8*)(Abase + kk + lg*8);
    #pragma unroll
    for (int j=0;j<4;j++){
      bf16x8 bfr = *(const bf16x8*)(Bbase + (size_t)(j*16 + lr)*HID + kk + lg*8);
      acc[j] = __builtin_amdgcn_mfma_f32_16x16x32_bf16(af, bfr, acc[j], 0,0,0);
    }
  }
  #pragma unroll
  for (int j=0;j<4;j++){
    int col = nb*64 + j*16 + lr;
    float bc = bo[col];
    #pragma unroll
    for (int r=0;r<4;r++){
      int row = row0 + lg*4 + r;
      yo[(size_t)row*HID + col] = acc[j][r] + bc;
    }
  }
}

// ---------------- kernel C2: row LN of yo -> yln bf16 ----------------
__global__ __launch_bounds__(256) void k_ln2(
    const float* __restrict__ yo,
    const float* __restrict__ g_ff, const float* __restrict__ b_ff,
    __hip_bfloat16* __restrict__ yln)
{
  int tid = threadIdx.x;
  int row = blockIdx.x*32 + (tid >> 3), sub = tid & 7;
  const float4* yr = (const float4*)(yo + (size_t)row*HID) + sub*16;
  float4 v[16];
  float s = 0.f, s2 = 0.f;
  #pragma unroll
  for (int k=0;k<16;k++){
    v[k] = yr[k];
    s  += v[k].x+v[k].y+v[k].z+v[k].w;
    s2 += v[k].x*v[k].x+v[k].y*v[k].y+v[k].z*v[k].z+v[k].w*v[k].w;
  }
  #pragma unroll
  for (int o=1;o<8;o<<=1){ s += __shfl_xor(s,o); s2 += __shfl_xor(s2,o); }
  float m = s*(1.f/512.f), rs = rsqrtf(s2*(1.f/512.f) - m*m + 1e-5f);
  #pragma unroll
  for (int k=0;k<16;k++){
    int c = sub*64 + k*4;
    float o0 = (v[k].x-m)*rs*g_ff[c]   + b_ff[c];
    float o1 = (v[k].y-m)*rs*g_ff[c+1] + b_ff[c+1];
    float o2 = (v[k].z-m)*rs*g_ff[c+2] + b_ff[c+2];
    float o3 = (v[k].w-m)*rs*g_ff[c+3] + b_ff[c+3];
    yln[(size_t)row*HID + c]   = __float2bfloat16(o0);
    yln[(size_t)row*HID + c+1] = __float2bfloat16(o1);
    yln[(size_t)row*HID + c+2] = __float2bfloat16(o2);
    yln[(size_t)row*HID + c+3] = __float2bfloat16(o3);
  }
}

// ---------------- kernel C3: a1 = relu(yln @ W1^T + b1) bf16 ----------------
__global__ __launch_bounds__(256) void k_ff1(
    const __hip_bfloat16* __restrict__ yln,  // (B,512)
    const __hip_bfloat16* __restrict__ W1b,  // (2048,512)
    const float* __restrict__ b1,
    __hip_bfloat16* __restrict__ a1b)        // (B,2048)
{
  int mb = blockIdx.x, nb = blockIdx.y;
  int tid = threadIdx.x;
  int w = tid >> 6, l = tid & 63, lr = l & 15, lg = l >> 4;
  int row0 = mb*64 + w*16;
  const __hip_bfloat16* Abase = yln + (size_t)(row0 + lr)*HID;
  const __hip_bfloat16* Bbase = W1b + (size_t)(nb*64)*HID;
  f32x4 acc[4];
  #pragma unroll
  for (int j=0;j<4;j++) acc[j] = (f32x4){0.f,0.f,0.f,0.f};
  for (int kk = 0; kk < HID; kk += 32){
    bf16x8 af = *(const bf16x8*)(Abase + kk + lg*8);
    #pragma unroll
    for (int j=0;j<4;j++){
      bf16x8 bfr = *(const bf16x8*)(Bbase + (size_t)(j*16 + lr)*HID + kk + lg*8);
      acc[j] = __builtin_amdgcn_mfma_f32_16x16x32_bf16(af, bfr, acc[j], 0,0,0);
    }
  }
  #pragma unroll
  for (int j=0;j<4;j++){
    int col = nb*64 + j*16 + lr;
    float bc = b1[col];
    #pragma unroll
    for (int r=0;r<4;r++){
      int row = row0 + lg*4 + r;
      a1b[(size_t)row*FFD + col] = __float2bfloat16(fmaxf(acc[j][r] + bc, 0.f));
    }
  }
}

// ---------------- kernel C4: y2 = a1 @ W2^T + b2 + yo ----------------
__global__ __launch_bounds__(256) void k_ff2(
    const __hip_bfloat16* __restrict__ a1b,  // (B,2048)
    const __hip_bfloat16* __restrict__ W2b,  // (512,2048)
    const float* __restrict__ b2,
    const float* __restrict__ yo,
    float* __restrict__ y2)                  // (B,512)
{
  int mb = blockIdx.x, nb = blockIdx.y;
  int tid = threadIdx.x;
  int w = tid >> 6, l = tid & 63, lr = l & 15, lg = l >> 4;
  int row0 = mb*64 + w*16;
  const __hip_bfloat16* Abase = a1b + (size_t)(row0 + lr)*FFD;
  const __hip_bfloat16* Bbase = W2b + (size_t)(nb*64)*FFD;
  f32x4 acc[4];
  #pragma unroll
  for (int j=0;j<4;j++) acc[j] = (f32x4){0.f,0.f,0.f,0.f};
  for (int kk = 0; kk < FFD; kk += 32){
    bf16x8 af = *(const bf16x8*)(Abase + kk + lg*8);
    #pragma unroll
    for (int j=0;j<4;j++){
      bf16x8 bfr = *(const bf16x8*)(Bbase + (size_t)(j*16 + lr)*FFD + kk + lg*8);
      acc[j] = __builtin_amdgcn_mfma_f32_16x16x32_bf16(af, bfr, acc[j], 0,0,0);
    }
  }
  #pragma unroll
  for (int j=0;j<4;j++){
    int col = nb*64 + j*16 + lr;
    float bc = b2[col];
    #pragma unroll
    for (int r=0;r<4;r++){
      int row = row0 + lg*4 + r;
      y2[(size_t)row*HID + col] = acc[j][r] + bc + yo[(size_t)row*HID + col];
    }
  }
}

// ---------------- kernel C5: out = y2 @ Wf^T + bf ----------------
__global__ __launch_bounds__(256) void k_final(
    const float* __restrict__ y2,
    const float* __restrict__ Wf, const float* __restrict__ bfv,
    float* __restrict__ out)
{
  int tid = threadIdx.x;
  int b0 = blockIdx.x*64;
  for (int i = tid; i < 64*OUTD; i += 256){
    int r = b0 + i/OUTD, c = i%OUTD;
    out[(size_t)r*OUTD + c] = bfv[c] + dot_ld4(Wf + (size_t)c*HID, y2 + (size_t)r*HID, HID/4);
  }
}

extern "C" void kernel_launch(void* const* d_in, const int* in_sizes, int n_in,
                              void* d_out, int out_size, void* d_ws, size_t ws_size,
                              hipStream_t stream)
{
  const float* initial = (const float*)d_in[0];
  const float* logsig  = (const float*)d_in[1];
  const float* Wi  = (const float*)d_in[2];  const float* bi  = (const float*)d_in[3];
  const float* Wip = (const float*)d_in[4];  const float* bip = (const float*)d_in[5];
  const float* g_in= (const float*)d_in[6];  const float* b_in= (const float*)d_in[7];
  const float* Wk  = (const float*)d_in[8];  const float* bk  = (const float*)d_in[9];
  const float* Wv  = (const float*)d_in[10]; const float* bv  = (const float*)d_in[11];
  const float* Wq  = (const float*)d_in[12]; const float* bq  = (const float*)d_in[13];
  const float* Wo  = (const float*)d_in[14]; const float* bo  = (const float*)d_in[15];
  const float* g_ff= (const float*)d_in[16]; const float* b_ff= (const float*)d_in[17];
  const float* W1  = (const float*)d_in[18]; const float* b1  = (const float*)d_in[19];
  const float* W2  = (const float*)d_in[20]; const float* b2  = (const float*)d_in[21];
  const float* Wf  = (const float*)d_in[22]; const float* bf  = (const float*)d_in[23];
  float* out = (float*)d_out;

  char* ws = (char*)d_ws;
  const size_t MB = 1<<20;
  float* qws   = (float*)(ws);                             // 512 KB
  float* yinit = (float*)(ws + 512*1024);                  // 512 KB
  __hip_bfloat16* u_bf = (__hip_bfloat16*)(ws + 3*MB);     // 2 MB
  float* Asum  = (float*)(ws + 5*MB);                      // 8 KB
  __hip_bfloat16* Wkb = (__hip_bfloat16*)(ws + 5*MB + 512*1024);  // 512 KB
  __hip_bfloat16* Wvb = (__hip_bfloat16*)(ws + 6*MB);      // 512 KB
  __hip_bfloat16* W1b = (__hip_bfloat16*)(ws + 6*MB + 512*1024);  // 2 MB
  __hip_bfloat16* W2b = (__hip_bfloat16*)(ws + 8*MB + 512*1024);  // 2 MB
  float* y2    = (float*)(ws + 10*MB + 512*1024);          // 512 KB
  __hip_bfloat16* yln = (__hip_bfloat16*)(ws + 11*MB);     // 256 KB
  __hip_bfloat16* a1b = (__hip_bfloat16*)(ws + 11*MB + 512*1024); // 1 MB
  __hip_bfloat16* Wob = (__hip_bfloat16*)(ws + 13*MB);     // 512 KB
  __hip_bfloat16* yh  = (__hip_bfloat16*)(ws + 13*MB + 512*1024); // 256 KB
  float* yo    = (float*)(ws + 14*MB);                     // 512 KB
  __hip_bfloat16* Wipb = (__hip_bfloat16*)(ws + 15*MB);    // 64 KB
  float* up    = (float*)(ws + 16*MB);                     // 16 MB
  float* Asp   = (float*)(ws + 33*MB);                     // 32 KB
  __hip_bfloat16* Wqb = (__hip_bfloat16*)(ws + 34*MB);     // 512 KB
  __hip_bfloat16* Wib = (__hip_bfloat16*)(ws + 35*MB);     // 16 KB

  k_cvt8<<<dim3((CVT_TOT + 255)/256), 256, 0, stream>>>(
      Wk, Wv, Wo, W1, W2, Wip, Wq, Wi,
      Wkb, Wvb, Wob, W1b, W2b, Wipb, Wqb, Wib);
  k_pre<<<dim3(B_/64), 512, 0, stream>>>(initial, logsig, Wib, bi, Wipb, bip,
                                         g_in, b_in, Wqb, bq, Wkb, bk, Wvb, bv,
                                         qws, yinit);
  k_fused<<<dim3(B_, 4), 512, 0, stream>>>(logsig, Wipb, bip, g_in, b_in,
                                           Wkb, bk, qws, up, Asp);
  k_ured<<<dim3(B_*NH), 256, 0, stream>>>(up, Asp, u_bf, Asum);
  k_yhead<<<dim3(B_/64, NH), 256, 0, stream>>>(u_bf, Wvb, bv, Asum, yinit, yh);
  k_yo<<<dim3(B_/64, HID/64), 256, 0, stream>>>(yh, Wob, bo, yo);
  k_ln2<<<dim3(B_/32), 256, 0, stream>>>(yo, g_ff, b_ff, yln);
  k_ff1<<<dim3(B_/64, FFD/64), 256, 0, stream>>>(yln, W1b, b1, a1b);
  k_ff2<<<dim3(B_/64, HID/64), 256, 0, stream>>>(a1b, W2b, b2, yo, y2);
  k_final<<<dim3(B_/64), 256, 0, stream>>>(y2, Wf, bf, out);
}

// Round 9
// 334.762 us; speedup vs baseline: 4.0493x; 1.0201x over previous
//
#include <hip/hip_runtime.h>
#include <hip/hip_bf16.h>
#include <math.h>

#define B_ 256
#define T_ 256
#define CIN 64
#define HID 512
#define NH 8
#define HD 64
#define FFD 2048
#define OUTD 10

typedef __bf16 bf16x8 __attribute__((ext_vector_type(8)));
typedef float f32x4 __attribute__((ext_vector_type(4)));

// swizzled LDS byte offset for a [rows x 512] bf16 tile (row stride 1024B)
#define HSOFF(r,c) (((r)<<10) + ((((c)<<1)) ^ ((((r)&7))<<4)))

__device__ __forceinline__ float bf2f(unsigned u){
  union { unsigned i; float f; } c; c.i = u << 16; return c.f;
}
__device__ __forceinline__ unsigned pk2(float a, float b){
  return ((unsigned)__bfloat16_as_ushort(__float2bfloat16(a))) |
         (((unsigned)__bfloat16_as_ushort(__float2bfloat16(b))) << 16);
}

__device__ __forceinline__ float dot_ld4(const float* __restrict__ w, const float* x, int n4){
  float acc = 0.f;
  const float4* w4 = (const float4*)w;
  const float4* x4 = (const float4*)x;
  for (int k = 0; k < n4; k++){
    float4 a = w4[k], b = x4[k];
    acc += a.x*b.x + a.y*b.y + a.z*b.z + a.w*b.w;
  }
  return acc;
}

// ---------------- prep: all eight f32 -> bf16 weight conversions in one launch --------------
#define CW_KV  (HID*HID)            // 262144
#define CW_IP  (HID*CIN)            // 32768
#define CW_FF  (FFD*HID)            // 1048576
#define CW_I   (CIN*128)            // 8192
#define CVT_TOT (4*CW_KV + 2*CW_FF + CW_IP + CW_I)
__global__ __launch_bounds__(256) void k_cvt8(
    const float* __restrict__ Wk, const float* __restrict__ Wv,
    const float* __restrict__ Wo, const float* __restrict__ W1,
    const float* __restrict__ W2, const float* __restrict__ Wip,
    const float* __restrict__ Wq, const float* __restrict__ Wi,
    __hip_bfloat16* __restrict__ Wkb, __hip_bfloat16* __restrict__ Wvb,
    __hip_bfloat16* __restrict__ Wob, __hip_bfloat16* __restrict__ W1b,
    __hip_bfloat16* __restrict__ W2b, __hip_bfloat16* __restrict__ Wipb,
    __hip_bfloat16* __restrict__ Wqb, __hip_bfloat16* __restrict__ Wib)
{
  int i = blockIdx.x*256 + threadIdx.x;
  if (i < CW_KV) { Wkb[i]  = __float2bfloat16(Wk[i]);  return; }  i -= CW_KV;
  if (i < CW_KV) { Wvb[i]  = __float2bfloat16(Wv[i]);  return; }  i -= CW_KV;
  if (i < CW_KV) { Wob[i]  = __float2bfloat16(Wo[i]);  return; }  i -= CW_KV;
  if (i < CW_FF) { W1b[i]  = __float2bfloat16(W1[i]);  return; }  i -= CW_FF;
  if (i < CW_FF) { W2b[i]  = __float2bfloat16(W2[i]);  return; }  i -= CW_FF;
  if (i < CW_IP) { Wipb[i] = __float2bfloat16(Wip[i]); return; }  i -= CW_IP;
  if (i < CW_KV) { Wqb[i]  = __float2bfloat16(Wq[i]);  return; }  i -= CW_KV;
  if (i < CW_I)  { Wib[i]  = __float2bfloat16(Wi[i]); }
}

// ---- building block (M=64): A(64x64 in Hs cols 0..64) @ Wip^T + LN -> Hs (64x512 bf16) ----
__device__ __forceinline__ void proj_ln(
    char* Hs, const __hip_bfloat16* __restrict__ Wipb,
    const float* __restrict__ bip, const float* __restrict__ g_in,
    const float* __restrict__ b_in,
    float (*red)[8][2], float (*ms2)[2],
    int tid, int w, int lr, int lg)
{
  f32x4 acc[4][4];
  #pragma unroll
  for (int i=0;i<4;i++)
    #pragma unroll
    for (int j=0;j<4;j++) acc[i][j] = (f32x4){0.f,0.f,0.f,0.f};
  #pragma unroll
  for (int kk = 0; kk < CIN; kk += 32){
    bf16x8 af[4], bfr[4];
    #pragma unroll
    for (int i=0;i<4;i++)
      af[i] = *(const bf16x8*)(Hs + HSOFF(i*16 + lr, kk + lg*8));
    #pragma unroll
    for (int j=0;j<4;j++)
      bfr[j] = *(const bf16x8*)(Wipb + (size_t)(w*64 + j*16 + lr)*CIN + kk + lg*8);
    #pragma unroll
    for (int i=0;i<4;i++)
      #pragma unroll
      for (int j=0;j<4;j++)
        acc[i][j] = __builtin_amdgcn_mfma_f32_16x16x32_bf16(af[i], bfr[j], acc[i][j], 0,0,0);
  }
  float bipv[4], gv[4], bbv[4];
  #pragma unroll
  for (int j=0;j<4;j++){
    int col = w*64 + j*16 + lr;
    bipv[j] = bip[col]; gv[j] = g_in[col]; bbv[j] = b_in[col];
  }
  #pragma unroll
  for (int i=0;i<4;i++){
    #pragma unroll
    for (int r=0;r<4;r++){
      float s = 0.f, s2 = 0.f;
      #pragma unroll
      for (int j=0;j<4;j++){ float v = acc[i][j][r] + bipv[j]; s += v; s2 += v*v; }
      #pragma unroll
      for (int o=1;o<16;o<<=1){ s += __shfl_xor(s,o); s2 += __shfl_xor(s2,o); }
      if (lr == 0){ int row = i*16 + lg*4 + r; red[row][w][0] = s; red[row][w][1] = s2; }
    }
  }
  __syncthreads();
  if (tid < 64){
    float S = 0.f, S2 = 0.f;
    #pragma unroll
    for (int k=0;k<8;k++){ S += red[tid][k][0]; S2 += red[tid][k][1]; }
    float m = S*(1.f/512.f), var = S2*(1.f/512.f) - m*m;
    ms2[tid][0] = m; ms2[tid][1] = rsqrtf(var + 1e-5f);
  }
  __syncthreads();
  #pragma unroll
  for (int i=0;i<4;i++){
    #pragma unroll
    for (int r=0;r<4;r++){
      int row = i*16 + lg*4 + r;
      float m = ms2[row][0], rs = ms2[row][1];
      #pragma unroll
      for (int j=0;j<4;j++){
        int col = w*64 + j*16 + lr;
        float v = (acc[i][j][r] + bipv[j] - m)*rs*gv[j] + bbv[j];
        *(unsigned short*)(Hs + HSOFF(row, col)) =
            __bfloat16_as_ushort(__float2bfloat16(v));
      }
    }
  }
  __syncthreads();
}

// ---- building block (M=64): acc = Hs(64x512) @ Bmat^T (K=512), A from LDS ----
__device__ __forceinline__ void gemm512_lds(
    const char* Hs, const __hip_bfloat16* __restrict__ Bmat,
    f32x4 acc[4][4], int lr, int lg)
{
  #pragma unroll
  for (int i=0;i<4;i++)
    #pragma unroll
    for (int j=0;j<4;j++) acc[i][j] = (f32x4){0.f,0.f,0.f,0.f};
  for (int kk = 0; kk < HID; kk += 32){
    bf16x8 af[4], bfr[4];
    #pragma unroll
    for (int i=0;i<4;i++)
      af[i] = *(const bf16x8*)(Hs + HSOFF(i*16 + lr, kk + lg*8));
    #pragma unroll
    for (int j=0;j<4;j++)
      bfr[j] = *(const bf16x8*)(Bmat + (size_t)(j*16 + lr)*HID + kk + lg*8);
    #pragma unroll
    for (int i=0;i<4;i++)
      #pragma unroll
      for (int j=0;j<4;j++)
        acc[i][j] = __builtin_amdgcn_mfma_f32_16x16x32_bf16(af[i], bfr[j], acc[i][j], 0,0,0);
  }
}

// ---- building block (M=16): A(16x64 in Hs cols 0..64) @ Wip^T + LN -> Hs (16x512 bf16) ----
__device__ __forceinline__ void proj_ln16(
    char* Hs, const __hip_bfloat16* __restrict__ Wipb,
    const float* __restrict__ bip, const float* __restrict__ g_in,
    const float* __restrict__ b_in,
    float (*red)[8][2], float (*ms2)[2],
    int tid, int w, int lr, int lg)
{
  f32x4 acc[4];
  #pragma unroll
  for (int j=0;j<4;j++) acc[j] = (f32x4){0.f,0.f,0.f,0.f};
  #pragma unroll
  for (int kk = 0; kk < CIN; kk += 32){
    bf16x8 af = *(const bf16x8*)(Hs + HSOFF(lr, kk + lg*8));
    #pragma unroll
    for (int j=0;j<4;j++){
      bf16x8 bfr = *(const bf16x8*)(Wipb + (size_t)(w*64 + j*16 + lr)*CIN + kk + lg*8);
      acc[j] = __builtin_amdgcn_mfma_f32_16x16x32_bf16(af, bfr, acc[j], 0,0,0);
    }
  }
  float bipv[4], gv[4], bbv[4];
  #pragma unroll
  for (int j=0;j<4;j++){
    int col = w*64 + j*16 + lr;
    bipv[j] = bip[col]; gv[j] = g_in[col]; bbv[j] = b_in[col];
  }
  #pragma unroll
  for (int r=0;r<4;r++){
    float s = 0.f, s2 = 0.f;
    #pragma unroll
    for (int j=0;j<4;j++){ float v = acc[j][r] + bipv[j]; s += v; s2 += v*v; }
    #pragma unroll
    for (int o=1;o<16;o<<=1){ s += __shfl_xor(s,o); s2 += __shfl_xor(s2,o); }
    if (lr == 0){ int row = lg*4 + r; red[row][w][0] = s; red[row][w][1] = s2; }
  }
  __syncthreads();
  if (tid < 16){
    float S = 0.f, S2 = 0.f;
    #pragma unroll
    for (int k=0;k<8;k++){ S += red[tid][k][0]; S2 += red[tid][k][1]; }
    float m = S*(1.f/512.f), var = S2*(1.f/512.f) - m*m;
    ms2[tid][0] = m; ms2[tid][1] = rsqrtf(var + 1e-5f);
  }
  __syncthreads();
  #pragma unroll
  for (int r=0;r<4;r++){
    int row = lg*4 + r;
    float m = ms2[row][0], rs = ms2[row][1];
    #pragma unroll
    for (int j=0;j<4;j++){
      int col = w*64 + j*16 + lr;
      float v = (acc[j][r] + bipv[j] - m)*rs*gv[j] + bbv[j];
      *(unsigned short*)(Hs + HSOFF(row, col)) =
          __bfloat16_as_ushort(__float2bfloat16(v));
    }
  }
  __syncthreads();
}

// ---- building block (M=16): acc = Hs(16x512) @ Bmat^T (K=512) ----
__device__ __forceinline__ void gemm512_lds16(
    const char* Hs, const __hip_bfloat16* __restrict__ Bmat,
    f32x4 acc[4], int lr, int lg)
{
  #pragma unroll
  for (int j=0;j<4;j++) acc[j] = (f32x4){0.f,0.f,0.f,0.f};
  for (int kk = 0; kk < HID; kk += 32){
    bf16x8 af = *(const bf16x8*)(Hs + HSOFF(lr, kk + lg*8));
    #pragma unroll
    for (int j=0;j<4;j++){
      bf16x8 bfr = *(const bf16x8*)(Bmat + (size_t)(j*16 + lr)*HID + kk + lg*8);
      acc[j] = __builtin_amdgcn_mfma_f32_16x16x32_bf16(af, bfr, acc[j], 0,0,0);
    }
  }
}

// ---------------- k_pre: batched init path (q, yinit), 16 blocks x 16 batch rows ----------
__global__ __launch_bounds__(512) void k_pre(
    const float* __restrict__ initial, const float* __restrict__ logsig,
    const __hip_bfloat16* __restrict__ Wib,  const float* __restrict__ bi,
    const __hip_bfloat16* __restrict__ Wipb, const float* __restrict__ bip,
    const float* __restrict__ g_in, const float* __restrict__ b_in,
    const __hip_bfloat16* __restrict__ Wqb, const float* __restrict__ bq,
    const __hip_bfloat16* __restrict__ Wkb, const float* __restrict__ bk,
    const __hip_bfloat16* __restrict__ Wvb, const float* __restrict__ bv,
    float* __restrict__ qout, float* __restrict__ yinit)
{
  int b0 = blockIdx.x*16;
  int tid = threadIdx.x;
  int w = tid >> 6, l = tid & 63, lr = l & 15, lg = l >> 4;
  __shared__ __align__(16) char Hs[16*1024];
  __shared__ float red[16][8][2];
  __shared__ float ms2[16][2];
  __shared__ float salS[16][8];
  f32x4 acc[4];

  // ---- phase A: stage xlast (16 rows x 64 cols) -> Hs; hq = LN(x @ Wip^T) ----
  {
    int row = tid >> 5, c = (tid & 31)*2;
    const float* s = logsig + ((size_t)(b0+row)*T_ + (T_-1))*CIN + c;
    float2 a = *(const float2*)s;
    *(unsigned*)(Hs + HSOFF(row, c)) = pk2(a.x, a.y);
  }
  __syncthreads();
  proj_ln16(Hs, Wipb, bip, g_in, b_in, red, ms2, tid, w, lr, lg);

  // ---- phase B: q = softmax_h(hq @ Wq_h^T + bq), kept in registers ----
  float qreg[4][4];   // [j][r]
  gemm512_lds16(Hs, Wqb + (size_t)(w*64)*HID, acc, lr, lg);
  {
    float bqv[4];
    #pragma unroll
    for (int j=0;j<4;j++) bqv[j] = bq[w*64 + j*16 + lr];
    #pragma unroll
    for (int r=0;r<4;r++){
      float v0 = acc[0][r]+bqv[0], v1 = acc[1][r]+bqv[1];
      float v2 = acc[2][r]+bqv[2], v3 = acc[3][r]+bqv[3];
      float mx = fmaxf(fmaxf(v0,v1),fmaxf(v2,v3));
      #pragma unroll
      for (int o=1;o<16;o<<=1) mx = fmaxf(mx, __shfl_xor(mx,o));
      float e0=__expf(v0-mx), e1=__expf(v1-mx), e2=__expf(v2-mx), e3=__expf(v3-mx);
      float se = e0+e1+e2+e3;
      #pragma unroll
      for (int o=1;o<16;o<<=1) se += __shfl_xor(se,o);
      float inv = 1.f/se;
      qreg[0][r]=e0*inv; qreg[1][r]=e1*inv; qreg[2][r]=e2*inv; qreg[3][r]=e3*inv;
      int row = lg*4 + r;
      size_t base = (size_t)(b0+row)*HID + w*64 + lr;
      qout[base +  0] = qreg[0][r]; qout[base + 16] = qreg[1][r];
      qout[base + 32] = qreg[2][r]; qout[base + 48] = qreg[3][r];
    }
  }
  __syncthreads();

  // ---- phase C: stage initial (16x128) -> Hs cols 64..192; ip = initial@Wi^T+bi -> cols 0..64
  {
    int row = tid >> 5, c = (tid & 31)*4;
    const float* s = initial + (size_t)(b0+row)*128 + c;
    float4 a = *(const float4*)s;
    uint2 p = { pk2(a.x,a.y), pk2(a.z,a.w) };
    *(uint2*)(Hs + HSOFF(row, 64 + c)) = p;
  }
  __syncthreads();
  if (w < 4){
    f32x4 a2 = (f32x4){0.f,0.f,0.f,0.f};
    #pragma unroll
    for (int kk = 0; kk < 128; kk += 32){
      bf16x8 af = *(const bf16x8*)(Hs + HSOFF(lr, 64 + kk + lg*8));
      bf16x8 bfr = *(const bf16x8*)(Wib + (size_t)(w*16 + lr)*128 + kk + lg*8);
      a2 = __builtin_amdgcn_mfma_f32_16x16x32_bf16(af, bfr, a2, 0,0,0);
    }
    float bic = bi[w*16 + lr];
    #pragma unroll
    for (int r=0;r<4;r++){
      *(unsigned short*)(Hs + HSOFF(lg*4 + r, w*16 + lr)) =
          __bfloat16_as_ushort(__float2bfloat16(a2[r] + bic));
    }
  }
  __syncthreads();

  // ---- phase D: h0 = LN(ip @ Wip^T) -> Hs ----
  proj_ln16(Hs, Wipb, bip, g_in, b_in, red, ms2, tid, w, lr, lg);

  // ---- phase E: k0 scores; sal = softmax(k0).q ----
  gemm512_lds16(Hs, Wkb + (size_t)(w*64)*HID, acc, lr, lg);
  {
    float bkv[4];
    #pragma unroll
    for (int j=0;j<4;j++) bkv[j] = bk[w*64 + j*16 + lr];
    #pragma unroll
    for (int r=0;r<4;r++){
      float v0 = acc[0][r]+bkv[0], v1 = acc[1][r]+bkv[1];
      float v2 = acc[2][r]+bkv[2], v3 = acc[3][r]+bkv[3];
      float mx = fmaxf(fmaxf(v0,v1),fmaxf(v2,v3));
      #pragma unroll
      for (int o=1;o<16;o<<=1) mx = fmaxf(mx, __shfl_xor(mx,o));
      float e0=__expf(v0-mx), e1=__expf(v1-mx), e2=__expf(v2-mx), e3=__expf(v3-mx);
      float se = e0+e1+e2+e3;
      float sq = e0*qreg[0][r]+e1*qreg[1][r]+e2*qreg[2][r]+e3*qreg[3][r];
      #pragma unroll
      for (int o=1;o<16;o<<=1){ se += __shfl_xor(se,o); sq += __shfl_xor(sq,o); }
      if (lr == 0) salS[lg*4 + r][w] = sq/se;
    }
  }
  __syncthreads();

  // ---- phase F: v0; yinit = sal * v0 ----
  gemm512_lds16(Hs, Wvb + (size_t)(w*64)*HID, acc, lr, lg);
  {
    float bvv[4];
    #pragma unroll
    for (int j=0;j<4;j++) bvv[j] = bv[w*64 + j*16 + lr];
    #pragma unroll
    for (int r=0;r<4;r++){
      int row = lg*4 + r;
      float s = salS[row][w];
      size_t base = (size_t)(b0+row)*HID + w*64 + lr;
      yinit[base +  0] = s*(acc[0][r]+bvv[0]);
      yinit[base + 16] = s*(acc[1][r]+bvv[1]);
      yinit[base + 32] = s*(acc[2][r]+bvv[2]);
      yinit[base + 48] = s*(acc[3][r]+bvv[3]);
    }
  }
}

// ---------------- FUSED kernel: hln (MFMA+LN) + score + softmax.q + MFMA partial-u ----------
__global__ __launch_bounds__(512, 4) void k_fused(
    const float* __restrict__ logsig,
    const __hip_bfloat16* __restrict__ Wipb,   // (512,64) bf16
    const float* __restrict__ bip,
    const float* __restrict__ g_in, const float* __restrict__ b_in,
    const __hip_bfloat16* __restrict__ Wkb,    // (512,512) bf16
    const float* __restrict__ bk,
    const float* __restrict__ qws,             // (B,512)
    float* __restrict__ up,                    // (B,NH,4,512) f32 partial u
    float* __restrict__ Asp)                   // (B,NH,4) partial alpha-sum
{
  int b = blockIdx.x, tc = blockIdx.y;
  int tid = threadIdx.x;
  int w = tid >> 6, l = tid & 63, lr = l & 15, lg = l >> 4;
  __shared__ __align__(16) char Hs[64*1024];     // 64 rows x 512 bf16, swizzled
  __shared__ float red[64][8][2];
  __shared__ float ms2[64][2];
  __shared__ float als[64][8];
  __shared__ unsigned short als_bt[2][16][64];   // alpha^T bf16 hi/lo (rows 8-15 unused)

  // ---- stage logsig x-tile (64x64 f32 -> bf16) into Hs cols 0..64 ----
  {
    int row = tid >> 3, cc = (tid & 7)*8;
    const float* srow = logsig + ((size_t)b*T_ + tc*64 + row)*CIN + cc;
    float4 a = *(const float4*)(srow);
    float4 c = *(const float4*)(srow+4);
    uint4 p = { pk2(a.x,a.y), pk2(a.z,a.w), pk2(c.x,c.y), pk2(c.z,c.w) };
    *(uint4*)(Hs + HSOFF(row, cc)) = p;
  }
  __syncthreads();

  // ---- phase 1: Hln = LN(x @ Wip^T + bip) ----
  proj_ln(Hs, Wipb, bip, g_in, b_in, red, ms2, tid, w, lr, lg);

  // ---- phase 2: scores S = Hln @ Wk_h^T (wave w = head w), A from LDS ----
  f32x4 acc[4][4];
  gemm512_lds(Hs, Wkb + (size_t)(w*64)*HID, acc, lr, lg);

  // ---- phase 3: per-row softmax over head cols, dot q, RK4 weight -> als (+bf16 hi/lo T) ----
  {
    float bkv[4], qv[4];
    #pragma unroll
    for (int j=0;j<4;j++){
      bkv[j] = bk[w*64 + j*16 + lr];
      qv[j]  = qws[(size_t)b*HID + w*64 + j*16 + lr];
    }
    #pragma unroll
    for (int i=0;i<4;i++){
      #pragma unroll
      for (int r=0;r<4;r++){
        float v0 = acc[i][0][r]+bkv[0], v1 = acc[i][1][r]+bkv[1];
        float v2 = acc[i][2][r]+bkv[2], v3 = acc[i][3][r]+bkv[3];
        float mx = fmaxf(fmaxf(v0,v1),fmaxf(v2,v3));
        #pragma unroll
        for (int o=1;o<16;o<<=1) mx = fmaxf(mx, __shfl_xor(mx,o));
        float e0=__expf(v0-mx), e1=__expf(v1-mx), e2=__expf(v2-mx), e3=__expf(v3-mx);
        float se = e0+e1+e2+e3;
        float sq = e0*qv[0]+e1*qv[1]+e2*qv[2]+e3*qv[3];
        #pragma unroll
        for (int o=1;o<16;o<<=1){ se += __shfl_xor(se,o); sq += __shfl_xor(sq,o); }
        if (lr == 0){
          int row = i*16 + lg*4 + r;
          int t = tc*64 + row;
          float wt = (t == 0) ? (5.f/6.f) : ((t == T_-1) ? (1.f/6.f) : 1.f);
          float alpha = wt * sq / se;
          als[row][w] = alpha;
          __hip_bfloat16 ah = __float2bfloat16(alpha);
          float rem = alpha - __bfloat162float(ah);
          als_bt[0][w][row] = __bfloat16_as_ushort(ah);
          als_bt[1][w][row] = __bfloat16_as_ushort(__float2bfloat16(rem));
        }
      }
    }
  }
  __syncthreads();

  // ---- phase 4: u = alpha^T @ H via MFMA (M=8 heads, N=64 cols/wave, K=64 rows) ----
  {
    f32x4 uacc[4];
    #pragma unroll
    for (int t=0;t<4;t++) uacc[t] = (f32x4){0.f,0.f,0.f,0.f};
    #pragma unroll
    for (int ks=0; ks<2; ks++){
      bf16x8 afh = *(const bf16x8*)&als_bt[0][lr][ks*32 + lg*8];
      bf16x8 afl = *(const bf16x8*)&als_bt[1][lr][ks*32 + lg*8];
      #pragma unroll
      for (int t=0;t<4;t++){
        int col = w*64 + t*16 + lr;
        union { unsigned u[4]; bf16x8 v; } bb;
        #pragma unroll
        for (int j2=0;j2<4;j2++){
          int r0 = ks*32 + lg*8 + 2*j2;
          unsigned lo = *(const unsigned short*)(Hs + HSOFF(r0,   col));
          unsigned hi = *(const unsigned short*)(Hs + HSOFF(r0+1, col));
          bb.u[j2] = lo | (hi << 16);
        }
        uacc[t] = __builtin_amdgcn_mfma_f32_16x16x32_bf16(afh, bb.v, uacc[t], 0,0,0);
        uacc[t] = __builtin_amdgcn_mfma_f32_16x16x32_bf16(afl, bb.v, uacc[t], 0,0,0);
      }
    }
    if (lg < 2){
      #pragma unroll
      for (int t=0;t<4;t++){
        #pragma unroll
        for (int rr=0; rr<4; rr++){
          int h = lg*4 + rr;
          up[((((size_t)b*NH + h)*4 + tc)*HID) + w*64 + t*16 + lr] = uacc[t][rr];
        }
      }
    }
    float s = als[l][w];
    #pragma unroll
    for (int o=1;o<64;o<<=1) s += __shfl_xor(s,o);
    if (l == 0) Asp[(((size_t)b*NH + w)*4) + tc] = s;
  }
}

// ---------------- reduce partials: u_bf (bf16) and Asum ----------------
__global__ __launch_bounds__(256) void k_ured(
    const float* __restrict__ up, const float* __restrict__ Asp,
    __hip_bfloat16* __restrict__ u_bf, float* __restrict__ Asum)
{
  int bh = blockIdx.x, tid = threadIdx.x;
  size_t base = (size_t)bh*4*HID;
  float s0 = 0.f, s1 = 0.f;
  #pragma unroll
  for (int c=0;c<4;c++){
    s0 += up[base + (size_t)c*HID + 2*tid];
    s1 += up[base + (size_t)c*HID + 2*tid+1];
  }
  ((unsigned*)u_bf)[(size_t)bh*(HID/2) + tid] = pk2(s0, s1);
  if (tid == 0)
    Asum[bh] = Asp[(size_t)bh*4] + Asp[(size_t)bh*4+1] + Asp[(size_t)bh*4+2] + Asp[(size_t)bh*4+3];
}

// ---------------- k_mid: yh (head GEMM, LDS-resident) + Wo GEMM + LN, fused ----------------
// Grid: B/64 blocks x 512 threads. Phase 1: wave w = head w. Phase 2: wave w = col-tile w.
__global__ __launch_bounds__(512) void k_mid(
    const __hip_bfloat16* __restrict__ u_bf,   // (B,8,512)
    const __hip_bfloat16* __restrict__ Wvb,    // (512,512)
    const float* __restrict__ bv, const float* __restrict__ Asum,
    const float* __restrict__ yinit,
    const __hip_bfloat16* __restrict__ Wob,    // (512,512)
    const float* __restrict__ bo,
    const float* __restrict__ g_ff, const float* __restrict__ b_ff,
    float* __restrict__ yo,                    // (B,512) f32
    __hip_bfloat16* __restrict__ yln)          // (B,512) bf16
{
  int b0 = blockIdx.x*64;
  int tid = threadIdx.x;
  int w = tid >> 6, l = tid & 63, lr = l & 15, lg = l >> 4;
  __shared__ __align__(16) char Hs[64*1024];
  __shared__ float red[64][8][2];
  __shared__ float ms2[64][2];
  f32x4 acc[4][4];

  // ---- phase 1: yh = u @ Wv_h^T + yinit + bv*Asum -> Hs (bf16, swizzled) ----
  #pragma unroll
  for (int i=0;i<4;i++)
    #pragma unroll
    for (int j=0;j<4;j++) acc[i][j] = (f32x4){0.f,0.f,0.f,0.f};
  {
    const __hip_bfloat16* Bbase = Wvb + (size_t)(w*64)*HID;
    for (int kk = 0; kk < HID; kk += 32){
      bf16x8 af[4], bfr[4];
      #pragma unroll
      for (int i=0;i<4;i++)
        af[i] = *(const bf16x8*)(u_bf + ((size_t)(b0 + i*16 + lr)*NH + w)*HID + kk + lg*8);
      #pragma unroll
      for (int j=0;j<4;j++)
        bfr[j] = *(const bf16x8*)(Bbase + (size_t)(j*16 + lr)*HID + kk + lg*8);
      #pragma unroll
      for (int i=0;i<4;i++)
        #pragma unroll
        for (int j=0;j<4;j++)
          acc[i][j] = __builtin_amdgcn_mfma_f32_16x16x32_bf16(af[i], bfr[j], acc[i][j], 0,0,0);
    }
  }
  {
    float bvv[4];
    #pragma unroll
    for (int j=0;j<4;j++) bvv[j] = bv[w*64 + j*16 + lr];
    #pragma unroll
    for (int i=0;i<4;i++){
      #pragma unroll
      for (int r=0;r<4;r++){
        int row = i*16 + lg*4 + r;
        float As = Asum[(size_t)(b0+row)*NH + w];
        #pragma unroll
        for (int j=0;j<4;j++){
          int col = w*64 + j*16 + lr;
          float v = acc[i][j][r] + yinit[(size_t)(b0+row)*HID + col] + bvv[j]*As;
          *(unsigned short*)(Hs + HSOFF(row, col)) =
              __bfloat16_as_ushort(__float2bfloat16(v));
        }
      }
    }
  }
  __syncthreads();

  // ---- phase 2: yo = yh @ Wo^T + bo (wave w = col tile), then row-LN -> yln ----
  gemm512_lds(Hs, Wob + (size_t)(w*64)*HID, acc, lr, lg);
  float bov[4], gv[4], bbv[4];
  #pragma unroll
  for (int j=0;j<4;j++){
    int col = w*64 + j*16 + lr;
    bov[j] = bo[col]; gv[j] = g_ff[col]; bbv[j] = b_ff[col];
  }
  #pragma unroll
  for (int i=0;i<4;i++){
    #pragma unroll
    for (int r=0;r<4;r++){
      float s = 0.f, s2 = 0.f;
      #pragma unroll
      for (int j=0;j<4;j++){ float v = acc[i][j][r] + bov[j]; s += v; s2 += v*v; }
      #pragma unroll
      for (int o=1;o<16;o<<=1){ s += __shfl_xor(s,o); s2 += __shfl_xor(s2,o); }
      if (lr == 0){ int row = i*16 + lg*4 + r; red[row][w][0] = s; red[row][w][1] = s2; }
    }
  }
  __syncthreads();
  if (tid < 64){
    float S = 0.f, S2 = 0.f;
    #pragma unroll
    for (int k=0;k<8;k++){ S += red[tid][k][0]; S2 += red[tid][k][1]; }
    float m = S*(1.f/512.f), var = S2*(1.f/512.f) - m*m;
    ms2[tid][0] = m; ms2[tid][1] = rsqrtf(var + 1e-5f);
  }
  __syncthreads();
  #pragma unroll
  for (int i=0;i<4;i++){
    #pragma unroll
    for (int r=0;r<4;r++){
      int row = i*16 + lg*4 + r;
      float m = ms2[row][0], rs = ms2[row][1];
      #pragma unroll
      for (int j=0;j<4;j++){
        int col = w*64 + j*16 + lr;
        float v = acc[i][j][r] + bov[j];
        yo[(size_t)(b0+row)*HID + col] = v;
        yln[(size_t)(b0+row)*HID + col] = __float2bfloat16((v - m)*rs*gv[j] + bbv[j]);
      }
    }
  }
}

// ---------------- kernel C3: a1 = relu(yln @ W1^T + b1) bf16 ----------------
__global__ __launch_bounds__(256) void k_ff1(
    const __hip_bfloat16* __restrict__ yln,  // (B,512)
    const __hip_bfloat16* __restrict__ W1b,  // (2048,512)
    const float* __restrict__ b1,
    __hip_bfloat16* __restrict__ a1b)        // (B,2048)
{
  int mb = blockIdx.x, nb = blockIdx.y;
  int tid = threadIdx.x;
  int w = tid >> 6, l = tid & 63, lr = l & 15, lg = l >> 4;
  int row0 = mb*64 + w*16;
  const __hip_bfloat16* Abase = yln + (size_t)(row0 + lr)*HID;
  const __hip_bfloat16* Bbase = W1b + (size_t)(nb*64)*HID;
  f32x4 acc[4];
  #pragma unroll
  for (int j=0;j<4;j++) acc[j] = (f32x4){0.f,0.f,0.f,0.f};
  for (int kk = 0; kk < HID; kk += 32){
    bf16x8 af = *(const bf16x8*)(Abase + kk + lg*8);
    #pragma unroll
    for (int j=0;j<4;j++){
      bf16x8 bfr = *(const bf16x8*)(Bbase + (size_t)(j*16 + lr)*HID + kk + lg*8);
      acc[j] = __builtin_amdgcn_mfma_f32_16x16x32_bf16(af, bfr, acc[j], 0,0,0);
    }
  }
  #pragma unroll
  for (int j=0;j<4;j++){
    int col = nb*64 + j*16 + lr;
    float bc = b1[col];
    #pragma unroll
    for (int r=0;r<4;r++){
      int row = row0 + lg*4 + r;
      a1b[(size_t)row*FFD + col] = __float2bfloat16(fmaxf(acc[j][r] + bc, 0.f));
    }
  }
}

// ---------------- kernel C4: y2 = a1 @ W2^T + b2 + yo ----------------
__global__ __launch_bounds__(256) void k_ff2(
    const __hip_bfloat16* __restrict__ a1b,  // (B,2048)
    const __hip_bfloat16* __restrict__ W2b,  // (512,2048)
    const float* __restrict__ b2,
    const float* __restrict__ yo,
    float* __restrict__ y2)                  // (B,512)
{
  int mb = blockIdx.x, nb = blockIdx.y;
  int tid = threadIdx.x;
  int w = tid >> 6, l = tid & 63, lr = l & 15, lg = l >> 4;
  int row0 = mb*64 + w*16;
  const __hip_bfloat16* Abase = a1b + (size_t)(row0 + lr)*FFD;
  const __hip_bfloat16* Bbase = W2b + (size_t)(nb*64)*FFD;
  f32x4 acc[4];
  #pragma unroll
  for (int j=0;j<4;j++) acc[j] = (f32x4){0.f,0.f,0.f,0.f};
  for (int kk = 0; kk < FFD; kk += 32){
    bf16x8 af = *(const bf16x8*)(Abase + kk + lg*8);
    #pragma unroll
    for (int j=0;j<4;j++){
      bf16x8 bfr = *(const bf16x8*)(Bbase + (size_t)(j*16 + lr)*FFD + kk + lg*8);
      acc[j] = __builtin_amdgcn_mfma_f32_16x16x32_bf16(af, bfr, acc[j], 0,0,0);
    }
  }
  #pragma unroll
  for (int j=0;j<4;j++){
    int col = nb*64 + j*16 + lr;
    float bc = b2[col];
    #pragma unroll
    for (int r=0;r<4;r++){
      int row = row0 + lg*4 + r;
      y2[(size_t)row*HID + col] = acc[j][r] + bc + yo[(size_t)row*HID + col];
    }
  }
}

// ---------------- kernel C5: out = y2 @ Wf^T + bf ----------------
__global__ __launch_bounds__(256) void k_final(
    const float* __restrict__ y2,
    const float* __restrict__ Wf, const float* __restrict__ bfv,
    float* __restrict__ out)
{
  int tid = threadIdx.x;
  int b0 = blockIdx.x*64;
  for (int i = tid; i < 64*OUTD; i += 256){
    int r = b0 + i/OUTD, c = i%OUTD;
    out[(size_t)r*OUTD + c] = bfv[c] + dot_ld4(Wf + (size_t)c*HID, y2 + (size_t)r*HID, HID/4);
  }
}

extern "C" void kernel_launch(void* const* d_in, const int* in_sizes, int n_in,
                              void* d_out, int out_size, void* d_ws, size_t ws_size,
                              hipStream_t stream)
{
  const float* initial = (const float*)d_in[0];
  const float* logsig  = (const float*)d_in[1];
  const float* Wi  = (const float*)d_in[2];  const float* bi  = (const float*)d_in[3];
  const float* Wip = (const float*)d_in[4];  const float* bip = (const float*)d_in[5];
  const float* g_in= (const float*)d_in[6];  const float* b_in= (const float*)d_in[7];
  const float* Wk  = (const float*)d_in[8];  const float* bk  = (const float*)d_in[9];
  const float* Wv  = (const float*)d_in[10]; const float* bv  = (const float*)d_in[11];
  const float* Wq  = (const float*)d_in[12]; const float* bq  = (const float*)d_in[13];
  const float* Wo  = (const float*)d_in[14]; const float* bo  = (const float*)d_in[15];
  const float* g_ff= (const float*)d_in[16]; const float* b_ff= (const float*)d_in[17];
  const float* W1  = (const float*)d_in[18]; const float* b1  = (const float*)d_in[19];
  const float* W2  = (const float*)d_in[20]; const float* b2  = (const float*)d_in[21];
  const float* Wf  = (const float*)d_in[22]; const float* bf  = (const float*)d_in[23];
  float* out = (float*)d_out;

  char* ws = (char*)d_ws;
  const size_t MB = 1<<20;
  float* qws   = (float*)(ws);                             // 512 KB
  float* yinit = (float*)(ws + 512*1024);                  // 512 KB
  __hip_bfloat16* u_bf = (__hip_bfloat16*)(ws + 3*MB);     // 2 MB
  float* Asum  = (float*)(ws + 5*MB);                      // 8 KB
  __hip_bfloat16* Wkb = (__hip_bfloat16*)(ws + 5*MB + 512*1024);  // 512 KB
  __hip_bfloat16* Wvb = (__hip_bfloat16*)(ws + 6*MB);      // 512 KB
  __hip_bfloat16* W1b = (__hip_bfloat16*)(ws + 6*MB + 512*1024);  // 2 MB
  __hip_bfloat16* W2b = (__hip_bfloat16*)(ws + 8*MB + 512*1024);  // 2 MB
  float* y2    = (float*)(ws + 10*MB + 512*1024);          // 512 KB
  __hip_bfloat16* yln = (__hip_bfloat16*)(ws + 11*MB);     // 256 KB
  __hip_bfloat16* a1b = (__hip_bfloat16*)(ws + 11*MB + 512*1024); // 1 MB
  __hip_bfloat16* Wob = (__hip_bfloat16*)(ws + 13*MB);     // 512 KB
  float* yo    = (float*)(ws + 14*MB);                     // 512 KB
  __hip_bfloat16* Wipb = (__hip_bfloat16*)(ws + 15*MB);    // 64 KB
  float* up    = (float*)(ws + 16*MB);                     // 16 MB
  float* Asp   = (float*)(ws + 33*MB);                     // 32 KB
  __hip_bfloat16* Wqb = (__hip_bfloat16*)(ws + 34*MB);     // 512 KB
  __hip_bfloat16* Wib = (__hip_bfloat16*)(ws + 35*MB);     // 16 KB

  k_cvt8<<<dim3((CVT_TOT + 255)/256), 256, 0, stream>>>(
      Wk, Wv, Wo, W1, W2, Wip, Wq, Wi,
      Wkb, Wvb, Wob, W1b, W2b, Wipb, Wqb, Wib);
  k_pre<<<dim3(B_/16), 512, 0, stream>>>(initial, logsig, Wib, bi, Wipb, bip,
                                         g_in, b_in, Wqb, bq, Wkb, bk, Wvb, bv,
                                         qws, yinit);
  k_fused<<<dim3(B_, 4), 512, 0, stream>>>(logsig, Wipb, bip, g_in, b_in,
                                           Wkb, bk, qws, up, Asp);
  k_ured<<<dim3(B_*NH), 256, 0, stream>>>(up, Asp, u_bf, Asum);
  k_mid<<<dim3(B_/64), 512, 0, stream>>>(u_bf, Wvb, bv, Asum, yinit,
                                         Wob, bo, g_ff, b_ff, yo, yln);
  k_ff1<<<dim3(B_/64, FFD/64), 256, 0, stream>>>(yln, W1b, b1, a1b);
  k_ff2<<<dim3(B_/64, HID/64), 256, 0, stream>>>(a1b, W2b, b2, yo, y2);
  k_final<<<dim3(B_/64), 256, 0, stream>>>(y2, Wf, bf, out);
}

// Round 10
// 249.340 us; speedup vs baseline: 5.4366x; 1.3426x over previous
//
#include <hip/hip_runtime.h>
#include <hip/hip_bf16.h>
#include <math.h>

#define B_ 256
#define T_ 256
#define CIN 64
#define HID 512
#define NH 8
#define HD 64
#define FFD 2048
#define OUTD 10

typedef __bf16 bf16x8 __attribute__((ext_vector_type(8)));
typedef float f32x4 __attribute__((ext_vector_type(4)));

// swizzled LDS byte offset for a [rows x 512] bf16 tile (row stride 1024B)
#define HSOFF(r,c) (((r)<<10) + ((((c)<<1)) ^ ((((r)&7))<<4)))

__device__ __forceinline__ float bf2f(unsigned u){
  union { unsigned i; float f; } c; c.i = u << 16; return c.f;
}
__device__ __forceinline__ unsigned pk2(float a, float b){
  return ((unsigned)__bfloat16_as_ushort(__float2bfloat16(a))) |
         (((unsigned)__bfloat16_as_ushort(__float2bfloat16(b))) << 16);
}

__device__ __forceinline__ float dot_ld4(const float* __restrict__ w, const float* x, int n4){
  float acc = 0.f;
  const float4* w4 = (const float4*)w;
  const float4* x4 = (const float4*)x;
  for (int k = 0; k < n4; k++){
    float4 a = w4[k], b = x4[k];
    acc += a.x*b.x + a.y*b.y + a.z*b.z + a.w*b.w;
  }
  return acc;
}

// ---------------- pack: f32 weight (N x K) -> bf16 MFMA-fragment order ----------------
// P[ ((n0*(K/32) + s)*4 + j)*64 + lane ]*8  where row = n0*64 + j*16 + lr,
// k = s*32 + lg*8 + e, lane = lg*16 + lr.  Each wave B-load = 1KB contiguous.
__device__ __forceinline__ void pack_one(const float* __restrict__ W,
                                         __hip_bfloat16* __restrict__ P,
                                         const int K, int g){
  int row = g / (K/8), kg = g % (K/8);
  int k0 = kg*8;
  int n0 = row >> 6, j = (row >> 4) & 3, lr = row & 15;
  int s = k0 >> 5, lg = (k0 >> 3) & 3;
  int lane = lg*16 + lr;
  const float* src = W + (size_t)row*K + k0;
  float4 a = *(const float4*)src;
  float4 b = *(const float4*)(src+4);
  uint4 p = { pk2(a.x,a.y), pk2(a.z,a.w), pk2(b.x,b.y), pk2(b.z,b.w) };
  size_t off = ((((size_t)n0*(K>>5) + s)*4 + j)*64 + lane)*8;
  *(uint4*)(P + off) = p;
}

#define G_KV (HID*HID/8)   // 32768
#define G_FF (FFD*HID/8)   // 131072
#define G_IP (HID*CIN/8)   // 4096
#define G_I  (CIN*128/8)   // 1024
#define PK_TOT (4*G_KV + 2*G_FF + G_IP + G_I)
__global__ __launch_bounds__(256) void k_pack(
    const float* __restrict__ Wk, const float* __restrict__ Wv,
    const float* __restrict__ Wo, const float* __restrict__ Wq,
    const float* __restrict__ W1, const float* __restrict__ W2,
    const float* __restrict__ Wip, const float* __restrict__ Wi,
    __hip_bfloat16* __restrict__ Pk, __hip_bfloat16* __restrict__ Pv,
    __hip_bfloat16* __restrict__ Po, __hip_bfloat16* __restrict__ Pq,
    __hip_bfloat16* __restrict__ P1, __hip_bfloat16* __restrict__ P2,
    __hip_bfloat16* __restrict__ Pip, __hip_bfloat16* __restrict__ Pi)
{
  int g = blockIdx.x*256 + threadIdx.x;
  if (g < G_KV) { pack_one(Wk, Pk, HID, g); return; }  g -= G_KV;
  if (g < G_KV) { pack_one(Wv, Pv, HID, g); return; }  g -= G_KV;
  if (g < G_KV) { pack_one(Wo, Po, HID, g); return; }  g -= G_KV;
  if (g < G_KV) { pack_one(Wq, Pq, HID, g); return; }  g -= G_KV;
  if (g < G_FF) { pack_one(W1, P1, HID, g); return; }  g -= G_FF;
  if (g < G_FF) { pack_one(W2, P2, FFD, g); return; }  g -= G_FF;
  if (g < G_IP) { pack_one(Wip, Pip, CIN, g); return; }  g -= G_IP;
  if (g < G_I ) { pack_one(Wi, Pi, 128, g); }
}

// ---- building block (M=64): A(64x64 in Hs cols 0..64) @ Wip^T + LN -> Hs (64x512 bf16) ----
__device__ __forceinline__ void proj_ln(
    char* Hs, const __hip_bfloat16* __restrict__ Pip,
    const float* __restrict__ bip, const float* __restrict__ g_in,
    const float* __restrict__ b_in,
    float (*red)[8][2], float (*ms2)[2],
    int tid, int w, int l, int lr, int lg)
{
  f32x4 acc[4][4];
  #pragma unroll
  for (int i=0;i<4;i++)
    #pragma unroll
    for (int j=0;j<4;j++) acc[i][j] = (f32x4){0.f,0.f,0.f,0.f};
  #pragma unroll
  for (int s = 0; s < 2; s++){
    bf16x8 af[4], bfr[4];
    #pragma unroll
    for (int i=0;i<4;i++)
      af[i] = *(const bf16x8*)(Hs + HSOFF(i*16 + lr, s*32 + lg*8));
    const __hip_bfloat16* fb = Pip + ((size_t)(w*2 + s)*4)*512 + l*8;
    #pragma unroll
    for (int j=0;j<4;j++)
      bfr[j] = *(const bf16x8*)(fb + j*512);
    #pragma unroll
    for (int i=0;i<4;i++)
      #pragma unroll
      for (int j=0;j<4;j++)
        acc[i][j] = __builtin_amdgcn_mfma_f32_16x16x32_bf16(af[i], bfr[j], acc[i][j], 0,0,0);
  }
  float bipv[4], gv[4], bbv[4];
  #pragma unroll
  for (int j=0;j<4;j++){
    int col = w*64 + j*16 + lr;
    bipv[j] = bip[col]; gv[j] = g_in[col]; bbv[j] = b_in[col];
  }
  #pragma unroll
  for (int i=0;i<4;i++){
    #pragma unroll
    for (int r=0;r<4;r++){
      float s = 0.f, s2 = 0.f;
      #pragma unroll
      for (int j=0;j<4;j++){ float v = acc[i][j][r] + bipv[j]; s += v; s2 += v*v; }
      #pragma unroll
      for (int o=1;o<16;o<<=1){ s += __shfl_xor(s,o); s2 += __shfl_xor(s2,o); }
      if (lr == 0){ int row = i*16 + lg*4 + r; red[row][w][0] = s; red[row][w][1] = s2; }
    }
  }
  __syncthreads();
  if (tid < 64){
    float S = 0.f, S2 = 0.f;
    #pragma unroll
    for (int k=0;k<8;k++){ S += red[tid][k][0]; S2 += red[tid][k][1]; }
    float m = S*(1.f/512.f), var = S2*(1.f/512.f) - m*m;
    ms2[tid][0] = m; ms2[tid][1] = rsqrtf(var + 1e-5f);
  }
  __syncthreads();
  #pragma unroll
  for (int i=0;i<4;i++){
    #pragma unroll
    for (int r=0;r<4;r++){
      int row = i*16 + lg*4 + r;
      float m = ms2[row][0], rs = ms2[row][1];
      #pragma unroll
      for (int j=0;j<4;j++){
        int col = w*64 + j*16 + lr;
        float v = (acc[i][j][r] + bipv[j] - m)*rs*gv[j] + bbv[j];
        *(unsigned short*)(Hs + HSOFF(row, col)) =
            __bfloat16_as_ushort(__float2bfloat16(v));
      }
    }
  }
  __syncthreads();
}

// ---- building block (M=64): acc = Hs(64x512) @ P^T (K=512, packed, n0 pre-applied) ----
__device__ __forceinline__ void gemm512_pk(
    const char* Hs, const __hip_bfloat16* __restrict__ Pm,
    f32x4 acc[4][4], int l, int lr, int lg)
{
  #pragma unroll
  for (int i=0;i<4;i++)
    #pragma unroll
    for (int j=0;j<4;j++) acc[i][j] = (f32x4){0.f,0.f,0.f,0.f};
  for (int s = 0; s < 16; s++){
    bf16x8 af[4], bfr[4];
    #pragma unroll
    for (int i=0;i<4;i++)
      af[i] = *(const bf16x8*)(Hs + HSOFF(i*16 + lr, s*32 + lg*8));
    const __hip_bfloat16* fb = Pm + (size_t)s*2048 + l*8;
    #pragma unroll
    for (int j=0;j<4;j++)
      bfr[j] = *(const bf16x8*)(fb + j*512);
    #pragma unroll
    for (int i=0;i<4;i++)
      #pragma unroll
      for (int j=0;j<4;j++)
        acc[i][j] = __builtin_amdgcn_mfma_f32_16x16x32_bf16(af[i], bfr[j], acc[i][j], 0,0,0);
  }
}

// ---- building block (M=16): A(16x64 in Hs cols 0..64) @ Wip^T + LN -> Hs (16x512 bf16) ----
__device__ __forceinline__ void proj_ln16(
    char* Hs, const __hip_bfloat16* __restrict__ Pip,
    const float* __restrict__ bip, const float* __restrict__ g_in,
    const float* __restrict__ b_in,
    float (*red)[8][2], float (*ms2)[2],
    int tid, int w, int l, int lr, int lg)
{
  f32x4 acc[4];
  #pragma unroll
  for (int j=0;j<4;j++) acc[j] = (f32x4){0.f,0.f,0.f,0.f};
  #pragma unroll
  for (int s = 0; s < 2; s++){
    bf16x8 af = *(const bf16x8*)(Hs + HSOFF(lr, s*32 + lg*8));
    const __hip_bfloat16* fb = Pip + ((size_t)(w*2 + s)*4)*512 + l*8;
    #pragma unroll
    for (int j=0;j<4;j++){
      bf16x8 bfr = *(const bf16x8*)(fb + j*512);
      acc[j] = __builtin_amdgcn_mfma_f32_16x16x32_bf16(af, bfr, acc[j], 0,0,0);
    }
  }
  float bipv[4], gv[4], bbv[4];
  #pragma unroll
  for (int j=0;j<4;j++){
    int col = w*64 + j*16 + lr;
    bipv[j] = bip[col]; gv[j] = g_in[col]; bbv[j] = b_in[col];
  }
  #pragma unroll
  for (int r=0;r<4;r++){
    float s = 0.f, s2 = 0.f;
    #pragma unroll
    for (int j=0;j<4;j++){ float v = acc[j][r] + bipv[j]; s += v; s2 += v*v; }
    #pragma unroll
    for (int o=1;o<16;o<<=1){ s += __shfl_xor(s,o); s2 += __shfl_xor(s2,o); }
    if (lr == 0){ int row = lg*4 + r; red[row][w][0] = s; red[row][w][1] = s2; }
  }
  __syncthreads();
  if (tid < 16){
    float S = 0.f, S2 = 0.f;
    #pragma unroll
    for (int k=0;k<8;k++){ S += red[tid][k][0]; S2 += red[tid][k][1]; }
    float m = S*(1.f/512.f), var = S2*(1.f/512.f) - m*m;
    ms2[tid][0] = m; ms2[tid][1] = rsqrtf(var + 1e-5f);
  }
  __syncthreads();
  #pragma unroll
  for (int r=0;r<4;r++){
    int row = lg*4 + r;
    float m = ms2[row][0], rs = ms2[row][1];
    #pragma unroll
    for (int j=0;j<4;j++){
      int col = w*64 + j*16 + lr;
      float v = (acc[j][r] + bipv[j] - m)*rs*gv[j] + bbv[j];
      *(unsigned short*)(Hs + HSOFF(row, col)) =
          __bfloat16_as_ushort(__float2bfloat16(v));
    }
  }
  __syncthreads();
}

// ---- building block (M=16): acc = Hs(16x512) @ P^T (K=512, packed, n0 pre-applied) ----
__device__ __forceinline__ void gemm512_pk16(
    const char* Hs, const __hip_bfloat16* __restrict__ Pm,
    f32x4 acc[4], int l, int lr, int lg)
{
  #pragma unroll
  for (int j=0;j<4;j++) acc[j] = (f32x4){0.f,0.f,0.f,0.f};
  for (int s = 0; s < 16; s++){
    bf16x8 af = *(const bf16x8*)(Hs + HSOFF(lr, s*32 + lg*8));
    const __hip_bfloat16* fb = Pm + (size_t)s*2048 + l*8;
    #pragma unroll
    for (int j=0;j<4;j++){
      bf16x8 bfr = *(const bf16x8*)(fb + j*512);
      acc[j] = __builtin_amdgcn_mfma_f32_16x16x32_bf16(af, bfr, acc[j], 0,0,0);
    }
  }
}

// ---------------- k_pre: batched init path (q, yinit), 16 blocks x 16 batch rows ----------
__global__ __launch_bounds__(512) void k_pre(
    const float* __restrict__ initial, const float* __restrict__ logsig,
    const __hip_bfloat16* __restrict__ Pi,  const float* __restrict__ bi,
    const __hip_bfloat16* __restrict__ Pip, const float* __restrict__ bip,
    const float* __restrict__ g_in, const float* __restrict__ b_in,
    const __hip_bfloat16* __restrict__ Pq, const float* __restrict__ bq,
    const __hip_bfloat16* __restrict__ Pk, const float* __restrict__ bk,
    const __hip_bfloat16* __restrict__ Pv, const float* __restrict__ bv,
    float* __restrict__ qout, float* __restrict__ yinit)
{
  int b0 = blockIdx.x*16;
  int tid = threadIdx.x;
  int w = tid >> 6, l = tid & 63, lr = l & 15, lg = l >> 4;
  __shared__ __align__(16) char Hs[16*1024];
  __shared__ float red[16][8][2];
  __shared__ float ms2[16][2];
  __shared__ float salS[16][8];
  f32x4 acc[4];

  // ---- phase A: stage xlast (16 rows x 64 cols) -> Hs; hq = LN(x @ Wip^T) ----
  {
    int row = tid >> 5, c = (tid & 31)*2;
    const float* s = logsig + ((size_t)(b0+row)*T_ + (T_-1))*CIN + c;
    float2 a = *(const float2*)s;
    *(unsigned*)(Hs + HSOFF(row, c)) = pk2(a.x, a.y);
  }
  __syncthreads();
  proj_ln16(Hs, Pip, bip, g_in, b_in, red, ms2, tid, w, l, lr, lg);

  // ---- phase B: q = softmax_h(hq @ Wq_h^T + bq), kept in registers ----
  float qreg[4][4];   // [j][r]
  gemm512_pk16(Hs, Pq + (size_t)w*32768, acc, l, lr, lg);
  {
    float bqv[4];
    #pragma unroll
    for (int j=0;j<4;j++) bqv[j] = bq[w*64 + j*16 + lr];
    #pragma unroll
    for (int r=0;r<4;r++){
      float v0 = acc[0][r]+bqv[0], v1 = acc[1][r]+bqv[1];
      float v2 = acc[2][r]+bqv[2], v3 = acc[3][r]+bqv[3];
      float mx = fmaxf(fmaxf(v0,v1),fmaxf(v2,v3));
      #pragma unroll
      for (int o=1;o<16;o<<=1) mx = fmaxf(mx, __shfl_xor(mx,o));
      float e0=__expf(v0-mx), e1=__expf(v1-mx), e2=__expf(v2-mx), e3=__expf(v3-mx);
      float se = e0+e1+e2+e3;
      #pragma unroll
      for (int o=1;o<16;o<<=1) se += __shfl_xor(se,o);
      float inv = 1.f/se;
      qreg[0][r]=e0*inv; qreg[1][r]=e1*inv; qreg[2][r]=e2*inv; qreg[3][r]=e3*inv;
      int row = lg*4 + r;
      size_t base = (size_t)(b0+row)*HID + w*64 + lr;
      qout[base +  0] = qreg[0][r]; qout[base + 16] = qreg[1][r];
      qout[base + 32] = qreg[2][r]; qout[base + 48] = qreg[3][r];
    }
  }
  __syncthreads();

  // ---- phase C: stage initial (16x128) -> Hs cols 64..192; ip = initial@Wi^T+bi -> cols 0..64
  {
    int row = tid >> 5, c = (tid & 31)*4;
    const float* s = initial + (size_t)(b0+row)*128 + c;
    float4 a = *(const float4*)s;
    uint2 p = { pk2(a.x,a.y), pk2(a.z,a.w) };
    *(uint2*)(Hs + HSOFF(row, 64 + c)) = p;
  }
  __syncthreads();
  if (w < 4){
    f32x4 a2 = (f32x4){0.f,0.f,0.f,0.f};
    #pragma unroll
    for (int s = 0; s < 4; s++){
      bf16x8 af = *(const bf16x8*)(Hs + HSOFF(lr, 64 + s*32 + lg*8));
      bf16x8 bfr = *(const bf16x8*)(Pi + ((size_t)s*4 + w)*512 + l*8);
      a2 = __builtin_amdgcn_mfma_f32_16x16x32_bf16(af, bfr, a2, 0,0,0);
    }
    float bic = bi[w*16 + lr];
    #pragma unroll
    for (int r=0;r<4;r++){
      *(unsigned short*)(Hs + HSOFF(lg*4 + r, w*16 + lr)) =
          __bfloat16_as_ushort(__float2bfloat16(a2[r] + bic));
    }
  }
  __syncthreads();

  // ---- phase D: h0 = LN(ip @ Wip^T) -> Hs ----
  proj_ln16(Hs, Pip, bip, g_in, b_in, red, ms2, tid, w, l, lr, lg);

  // ---- phase E: k0 scores; sal = softmax(k0).q ----
  gemm512_pk16(Hs, Pk + (size_t)w*32768, acc, l, lr, lg);
  {
    float bkv[4];
    #pragma unroll
    for (int j=0;j<4;j++) bkv[j] = bk[w*64 + j*16 + lr];
    #pragma unroll
    for (int r=0;r<4;r++){
      float v0 = acc[0][r]+bkv[0], v1 = acc[1][r]+bkv[1];
      float v2 = acc[2][r]+bkv[2], v3 = acc[3][r]+bkv[3];
      float mx = fmaxf(fmaxf(v0,v1),fmaxf(v2,v3));
      #pragma unroll
      for (int o=1;o<16;o<<=1) mx = fmaxf(mx, __shfl_xor(mx,o));
      float e0=__expf(v0-mx), e1=__expf(v1-mx), e2=__expf(v2-mx), e3=__expf(v3-mx);
      float se = e0+e1+e2+e3;
      float sq = e0*qreg[0][r]+e1*qreg[1][r]+e2*qreg[2][r]+e3*qreg[3][r];
      #pragma unroll
      for (int o=1;o<16;o<<=1){ se += __shfl_xor(se,o); sq += __shfl_xor(sq,o); }
      if (lr == 0) salS[lg*4 + r][w] = sq/se;
    }
  }
  __syncthreads();

  // ---- phase F: v0; yinit = sal * v0 ----
  gemm512_pk16(Hs, Pv + (size_t)w*32768, acc, l, lr, lg);
  {
    float bvv[4];
    #pragma unroll
    for (int j=0;j<4;j++) bvv[j] = bv[w*64 + j*16 + lr];
    #pragma unroll
    for (int r=0;r<4;r++){
      int row = lg*4 + r;
      float s = salS[row][w];
      size_t base = (size_t)(b0+row)*HID + w*64 + lr;
      yinit[base +  0] = s*(acc[0][r]+bvv[0]);
      yinit[base + 16] = s*(acc[1][r]+bvv[1]);
      yinit[base + 32] = s*(acc[2][r]+bvv[2]);
      yinit[base + 48] = s*(acc[3][r]+bvv[3]);
    }
  }
}

// ---------------- FUSED kernel: hln (MFMA+LN) + score + softmax.q + MFMA partial-u ----------
__global__ __launch_bounds__(512, 4) void k_fused(
    const float* __restrict__ logsig,
    const __hip_bfloat16* __restrict__ Pip,
    const float* __restrict__ bip,
    const float* __restrict__ g_in, const float* __restrict__ b_in,
    const __hip_bfloat16* __restrict__ Pk,
    const float* __restrict__ bk,
    const float* __restrict__ qws,             // (B,512)
    float* __restrict__ up,                    // (B,NH,4,512) f32 partial u
    float* __restrict__ Asp)                   // (B,NH,4) partial alpha-sum
{
  int b = blockIdx.x, tc = blockIdx.y;
  int tid = threadIdx.x;
  int w = tid >> 6, l = tid & 63, lr = l & 15, lg = l >> 4;
  __shared__ __align__(16) char Hs[64*1024];     // 64 rows x 512 bf16, swizzled
  __shared__ float red[64][8][2];
  __shared__ float ms2[64][2];
  __shared__ float als[64][8];
  __shared__ unsigned short als_bt[2][16][64];   // alpha^T bf16 hi/lo (rows 8-15 unused)

  // ---- stage logsig x-tile (64x64 f32 -> bf16) into Hs cols 0..64 ----
  {
    int row = tid >> 3, cc = (tid & 7)*8;
    const float* srow = logsig + ((size_t)b*T_ + tc*64 + row)*CIN + cc;
    float4 a = *(const float4*)(srow);
    float4 c = *(const float4*)(srow+4);
    uint4 p = { pk2(a.x,a.y), pk2(a.z,a.w), pk2(c.x,c.y), pk2(c.z,c.w) };
    *(uint4*)(Hs + HSOFF(row, cc)) = p;
  }
  __syncthreads();

  // ---- phase 1: Hln = LN(x @ Wip^T + bip) ----
  proj_ln(Hs, Pip, bip, g_in, b_in, red, ms2, tid, w, l, lr, lg);

  // ---- phase 2: scores S = Hln @ Wk_h^T (wave w = head w), A from LDS ----
  f32x4 acc[4][4];
  gemm512_pk(Hs, Pk + (size_t)w*32768, acc, l, lr, lg);

  // ---- phase 3: per-row softmax over head cols, dot q, RK4 weight -> als (+bf16 hi/lo T) ----
  {
    float bkv[4], qv[4];
    #pragma unroll
    for (int j=0;j<4;j++){
      bkv[j] = bk[w*64 + j*16 + lr];
      qv[j]  = qws[(size_t)b*HID + w*64 + j*16 + lr];
    }
    #pragma unroll
    for (int i=0;i<4;i++){
      #pragma unroll
      for (int r=0;r<4;r++){
        float v0 = acc[i][0][r]+bkv[0], v1 = acc[i][1][r]+bkv[1];
        float v2 = acc[i][2][r]+bkv[2], v3 = acc[i][3][r]+bkv[3];
        float mx = fmaxf(fmaxf(v0,v1),fmaxf(v2,v3));
        #pragma unroll
        for (int o=1;o<16;o<<=1) mx = fmaxf(mx, __shfl_xor(mx,o));
        float e0=__expf(v0-mx), e1=__expf(v1-mx), e2=__expf(v2-mx), e3=__expf(v3-mx);
        float se = e0+e1+e2+e3;
        float sq = e0*qv[0]+e1*qv[1]+e2*qv[2]+e3*qv[3];
        #pragma unroll
        for (int o=1;o<16;o<<=1){ se += __shfl_xor(se,o); sq += __shfl_xor(sq,o); }
        if (lr == 0){
          int row = i*16 + lg*4 + r;
          int t = tc*64 + row;
          float wt = (t == 0) ? (5.f/6.f) : ((t == T_-1) ? (1.f/6.f) : 1.f);
          float alpha = wt * sq / se;
          als[row][w] = alpha;
          __hip_bfloat16 ah = __float2bfloat16(alpha);
          float rem = alpha - __bfloat162float(ah);
          als_bt[0][w][row] = __bfloat16_as_ushort(ah);
          als_bt[1][w][row] = __bfloat16_as_ushort(__float2bfloat16(rem));
        }
      }
    }
  }
  __syncthreads();

  // ---- phase 4: u = alpha^T @ H via MFMA (M=8 heads, N=64 cols/wave, K=64 rows) ----
  {
    f32x4 uacc[4];
    #pragma unroll
    for (int t=0;t<4;t++) uacc[t] = (f32x4){0.f,0.f,0.f,0.f};
    #pragma unroll
    for (int ks=0; ks<2; ks++){
      bf16x8 afh = *(const bf16x8*)&als_bt[0][lr][ks*32 + lg*8];
      bf16x8 afl = *(const bf16x8*)&als_bt[1][lr][ks*32 + lg*8];
      #pragma unroll
      for (int t=0;t<4;t++){
        int col = w*64 + t*16 + lr;
        union { unsigned u[4]; bf16x8 v; } bb;
        #pragma unroll
        for (int j2=0;j2<4;j2++){
          int r0 = ks*32 + lg*8 + 2*j2;
          unsigned lo = *(const unsigned short*)(Hs + HSOFF(r0,   col));
          unsigned hi = *(const unsigned short*)(Hs + HSOFF(r0+1, col));
          bb.u[j2] = lo | (hi << 16);
        }
        uacc[t] = __builtin_amdgcn_mfma_f32_16x16x32_bf16(afh, bb.v, uacc[t], 0,0,0);
        uacc[t] = __builtin_amdgcn_mfma_f32_16x16x32_bf16(afl, bb.v, uacc[t], 0,0,0);
      }
    }
    if (lg < 2){
      #pragma unroll
      for (int t=0;t<4;t++){
        #pragma unroll
        for (int rr=0; rr<4; rr++){
          int h = lg*4 + rr;
          up[((((size_t)b*NH + h)*4 + tc)*HID) + w*64 + t*16 + lr] = uacc[t][rr];
        }
      }
    }
    float s = als[l][w];
    #pragma unroll
    for (int o=1;o<64;o<<=1) s += __shfl_xor(s,o);
    if (l == 0) Asp[(((size_t)b*NH + w)*4) + tc] = s;
  }
}

// ---------------- reduce partials: u_bf (bf16) and Asum ----------------
__global__ __launch_bounds__(256) void k_ured(
    const float* __restrict__ up, const float* __restrict__ Asp,
    __hip_bfloat16* __restrict__ u_bf, float* __restrict__ Asum)
{
  int bh = blockIdx.x, tid = threadIdx.x;
  size_t base = (size_t)bh*4*HID;
  float s0 = 0.f, s1 = 0.f;
  #pragma unroll
  for (int c=0;c<4;c++){
    s0 += up[base + (size_t)c*HID + 2*tid];
    s1 += up[base + (size_t)c*HID + 2*tid+1];
  }
  ((unsigned*)u_bf)[(size_t)bh*(HID/2) + tid] = pk2(s0, s1);
  if (tid == 0)
    Asum[bh] = Asp[(size_t)bh*4] + Asp[(size_t)bh*4+1] + Asp[(size_t)bh*4+2] + Asp[(size_t)bh*4+3];
}

// ---------------- k_mid: yh (head GEMM, LDS-resident) + Wo GEMM + LN, fused ----------------
__global__ __launch_bounds__(512) void k_mid(
    const __hip_bfloat16* __restrict__ u_bf,   // (B,8,512)
    const __hip_bfloat16* __restrict__ Pv,     // packed Wv
    const float* __restrict__ bv, const float* __restrict__ Asum,
    const float* __restrict__ yinit,
    const __hip_bfloat16* __restrict__ Po,     // packed Wo
    const float* __restrict__ bo,
    const float* __restrict__ g_ff, const float* __restrict__ b_ff,
    float* __restrict__ yo,                    // (B,512) f32
    __hip_bfloat16* __restrict__ yln)          // (B,512) bf16
{
  int b0 = blockIdx.x*64;
  int tid = threadIdx.x;
  int w = tid >> 6, l = tid & 63, lr = l & 15, lg = l >> 4;
  __shared__ __align__(16) char Hs[64*1024];
  __shared__ float red[64][8][2];
  __shared__ float ms2[64][2];
  f32x4 acc[4][4];

  // ---- phase 1: yh = u @ Wv_h^T + yinit + bv*Asum -> Hs (bf16, swizzled) ----
  #pragma unroll
  for (int i=0;i<4;i++)
    #pragma unroll
    for (int j=0;j<4;j++) acc[i][j] = (f32x4){0.f,0.f,0.f,0.f};
  for (int s = 0; s < 16; s++){
    bf16x8 af[4], bfr[4];
    #pragma unroll
    for (int i=0;i<4;i++)
      af[i] = *(const bf16x8*)(u_bf + ((size_t)(b0 + i*16 + lr)*NH + w)*HID + s*32 + lg*8);
    const __hip_bfloat16* fb = Pv + (size_t)w*32768 + (size_t)s*2048 + l*8;
    #pragma unroll
    for (int j=0;j<4;j++)
      bfr[j] = *(const bf16x8*)(fb + j*512);
    #pragma unroll
    for (int i=0;i<4;i++)
      #pragma unroll
      for (int j=0;j<4;j++)
        acc[i][j] = __builtin_amdgcn_mfma_f32_16x16x32_bf16(af[i], bfr[j], acc[i][j], 0,0,0);
  }
  {
    float bvv[4];
    #pragma unroll
    for (int j=0;j<4;j++) bvv[j] = bv[w*64 + j*16 + lr];
    #pragma unroll
    for (int i=0;i<4;i++){
      #pragma unroll
      for (int r=0;r<4;r++){
        int row = i*16 + lg*4 + r;
        float As = Asum[(size_t)(b0+row)*NH + w];
        #pragma unroll
        for (int j=0;j<4;j++){
          int col = w*64 + j*16 + lr;
          float v = acc[i][j][r] + yinit[(size_t)(b0+row)*HID + col] + bvv[j]*As;
          *(unsigned short*)(Hs + HSOFF(row, col)) =
              __bfloat16_as_ushort(__float2bfloat16(v));
        }
      }
    }
  }
  __syncthreads();

  // ---- phase 2: yo = yh @ Wo^T + bo (wave w = col tile), then row-LN -> yln ----
  gemm512_pk(Hs, Po + (size_t)w*32768, acc, l, lr, lg);
  float bov[4], gv[4], bbv[4];
  #pragma unroll
  for (int j=0;j<4;j++){
    int col = w*64 + j*16 + lr;
    bov[j] = bo[col]; gv[j] = g_ff[col]; bbv[j] = b_ff[col];
  }
  #pragma unroll
  for (int i=0;i<4;i++){
    #pragma unroll
    for (int r=0;r<4;r++){
      float s = 0.f, s2 = 0.f;
      #pragma unroll
      for (int j=0;j<4;j++){ float v = acc[i][j][r] + bov[j]; s += v; s2 += v*v; }
      #pragma unroll
      for (int o=1;o<16;o<<=1){ s += __shfl_xor(s,o); s2 += __shfl_xor(s2,o); }
      if (lr == 0){ int row = i*16 + lg*4 + r; red[row][w][0] = s; red[row][w][1] = s2; }
    }
  }
  __syncthreads();
  if (tid < 64){
    float S = 0.f, S2 = 0.f;
    #pragma unroll
    for (int k=0;k<8;k++){ S += red[tid][k][0]; S2 += red[tid][k][1]; }
    float m = S*(1.f/512.f), var = S2*(1.f/512.f) - m*m;
    ms2[tid][0] = m; ms2[tid][1] = rsqrtf(var + 1e-5f);
  }
  __syncthreads();
  #pragma unroll
  for (int i=0;i<4;i++){
    #pragma unroll
    for (int r=0;r<4;r++){
      int row = i*16 + lg*4 + r;
      float m = ms2[row][0], rs = ms2[row][1];
      #pragma unroll
      for (int j=0;j<4;j++){
        int col = w*64 + j*16 + lr;
        float v = acc[i][j][r] + bov[j];
        yo[(size_t)(b0+row)*HID + col] = v;
        yln[(size_t)(b0+row)*HID + col] = __float2bfloat16((v - m)*rs*gv[j] + bbv[j]);
      }
    }
  }
}

// ---------------- kernel C3: a1 = relu(yln @ W1^T + b1) bf16 ----------------
__global__ __launch_bounds__(256) void k_ff1(
    const __hip_bfloat16* __restrict__ yln,  // (B,512)
    const __hip_bfloat16* __restrict__ P1,   // packed W1
    const float* __restrict__ b1,
    __hip_bfloat16* __restrict__ a1b)        // (B,2048)
{
  int mb = blockIdx.x, nb = blockIdx.y;
  int tid = threadIdx.x;
  int w = tid >> 6, l = tid & 63, lr = l & 15, lg = l >> 4;
  int row0 = mb*64 + w*16;
  const __hip_bfloat16* Abase = yln + (size_t)(row0 + lr)*HID;
  const __hip_bfloat16* Pm = P1 + (size_t)nb*32768;
  f32x4 acc[4];
  #pragma unroll
  for (int j=0;j<4;j++) acc[j] = (f32x4){0.f,0.f,0.f,0.f};
  for (int s = 0; s < 16; s++){
    bf16x8 af = *(const bf16x8*)(Abase + s*32 + lg*8);
    const __hip_bfloat16* fb = Pm + (size_t)s*2048 + l*8;
    #pragma unroll
    for (int j=0;j<4;j++){
      bf16x8 bfr = *(const bf16x8*)(fb + j*512);
      acc[j] = __builtin_amdgcn_mfma_f32_16x16x32_bf16(af, bfr, acc[j], 0,0,0);
    }
  }
  #pragma unroll
  for (int j=0;j<4;j++){
    int col = nb*64 + j*16 + lr;
    float bc = b1[col];
    #pragma unroll
    for (int r=0;r<4;r++){
      int row = row0 + lg*4 + r;
      a1b[(size_t)row*FFD + col] = __float2bfloat16(fmaxf(acc[j][r] + bc, 0.f));
    }
  }
}

// ---------------- kernel C4: y2 = a1 @ W2^T + b2 + yo ----------------
__global__ __launch_bounds__(256) void k_ff2(
    const __hip_bfloat16* __restrict__ a1b,  // (B,2048)
    const __hip_bfloat16* __restrict__ P2,   // packed W2 (K=2048)
    const float* __restrict__ b2,
    const float* __restrict__ yo,
    float* __restrict__ y2)                  // (B,512)
{
  int mb = blockIdx.x, nb = blockIdx.y;
  int tid = threadIdx.x;
  int w = tid >> 6, l = tid & 63, lr = l & 15, lg = l >> 4;
  int row0 = mb*64 + w*16;
  const __hip_bfloat16* Abase = a1b + (size_t)(row0 + lr)*FFD;
  const __hip_bfloat16* Pm = P2 + (size_t)nb*131072;
  f32x4 acc[4];
  #pragma unroll
  for (int j=0;j<4;j++) acc[j] = (f32x4){0.f,0.f,0.f,0.f};
  for (int s = 0; s < 64; s++){
    bf16x8 af = *(const bf16x8*)(Abase + s*32 + lg*8);
    const __hip_bfloat16* fb = Pm + (size_t)s*2048 + l*8;
    #pragma unroll
    for (int j=0;j<4;j++){
      bf16x8 bfr = *(const bf16x8*)(fb + j*512);
      acc[j] = __builtin_amdgcn_mfma_f32_16x16x32_bf16(af, bfr, acc[j], 0,0,0);
    }
  }
  #pragma unroll
  for (int j=0;j<4;j++){
    int col = nb*64 + j*16 + lr;
    float bc = b2[col];
    #pragma unroll
    for (int r=0;r<4;r++){
      int row = row0 + lg*4 + r;
      y2[(size_t)row*HID + col] = acc[j][r] + bc + yo[(size_t)row*HID + col];
    }
  }
}

// ---------------- kernel C5: out = y2 @ Wf^T + bf ----------------
__global__ __launch_bounds__(256) void k_final(
    const float* __restrict__ y2,
    const float* __restrict__ Wf, const float* __restrict__ bfv,
    float* __restrict__ out)
{
  int tid = threadIdx.x;
  int b0 = blockIdx.x*64;
  for (int i = tid; i < 64*OUTD; i += 256){
    int r = b0 + i/OUTD, c = i%OUTD;
    out[(size_t)r*OUTD + c] = bfv[c] + dot_ld4(Wf + (size_t)c*HID, y2 + (size_t)r*HID, HID/4);
  }
}

extern "C" void kernel_launch(void* const* d_in, const int* in_sizes, int n_in,
                              void* d_out, int out_size, void* d_ws, size_t ws_size,
                              hipStream_t stream)
{
  const float* initial = (const float*)d_in[0];
  const float* logsig  = (const float*)d_in[1];
  const float* Wi  = (const float*)d_in[2];  const float* bi  = (const float*)d_in[3];
  const float* Wip = (const float*)d_in[4];  const float* bip = (const float*)d_in[5];
  const float* g_in= (const float*)d_in[6];  const float* b_in= (const float*)d_in[7];
  const float* Wk  = (const float*)d_in[8];  const float* bk  = (const float*)d_in[9];
  const float* Wv  = (const float*)d_in[10]; const float* bv  = (const float*)d_in[11];
  const float* Wq  = (const float*)d_in[12]; const float* bq  = (const float*)d_in[13];
  const float* Wo  = (const float*)d_in[14]; const float* bo  = (const float*)d_in[15];
  const float* g_ff= (const float*)d_in[16]; const float* b_ff= (const float*)d_in[17];
  const float* W1  = (const float*)d_in[18]; const float* b1  = (const float*)d_in[19];
  const float* W2  = (const float*)d_in[20]; const float* b2  = (const float*)d_in[21];
  const float* Wf  = (const float*)d_in[22]; const float* bf  = (const float*)d_in[23];
  float* out = (float*)d_out;

  char* ws = (char*)d_ws;
  const size_t MB = 1<<20;
  float* qws   = (float*)(ws);                             // 512 KB
  float* yinit = (float*)(ws + 512*1024);                  // 512 KB
  __hip_bfloat16* u_bf = (__hip_bfloat16*)(ws + 3*MB);     // 2 MB
  float* Asum  = (float*)(ws + 5*MB);                      // 8 KB
  __hip_bfloat16* Pk  = (__hip_bfloat16*)(ws + 5*MB + 512*1024);  // 512 KB
  __hip_bfloat16* Pv  = (__hip_bfloat16*)(ws + 6*MB);      // 512 KB
  __hip_bfloat16* P1  = (__hip_bfloat16*)(ws + 6*MB + 512*1024);  // 2 MB
  __hip_bfloat16* P2  = (__hip_bfloat16*)(ws + 8*MB + 512*1024);  // 2 MB
  float* y2    = (float*)(ws + 10*MB + 512*1024);          // 512 KB
  __hip_bfloat16* yln = (__hip_bfloat16*)(ws + 11*MB);     // 256 KB
  __hip_bfloat16* a1b = (__hip_bfloat16*)(ws + 11*MB + 512*1024); // 1 MB
  __hip_bfloat16* Po  = (__hip_bfloat16*)(ws + 13*MB);     // 512 KB
  float* yo    = (float*)(ws + 14*MB);                     // 512 KB
  __hip_bfloat16* Pip = (__hip_bfloat16*)(ws + 15*MB);     // 64 KB
  float* up    = (float*)(ws + 16*MB);                     // 16 MB
  float* Asp   = (float*)(ws + 33*MB);                     // 32 KB
  __hip_bfloat16* Pq  = (__hip_bfloat16*)(ws + 34*MB);     // 512 KB
  __hip_bfloat16* Pi  = (__hip_bfloat16*)(ws + 35*MB);     // 16 KB

  k_pack<<<dim3((PK_TOT + 255)/256), 256, 0, stream>>>(
      Wk, Wv, Wo, Wq, W1, W2, Wip, Wi,
      Pk, Pv, Po, Pq, P1, P2, Pip, Pi);
  k_pre<<<dim3(B_/16), 512, 0, stream>>>(initial, logsig, Pi, bi, Pip, bip,
                                         g_in, b_in, Pq, bq, Pk, bk, Pv, bv,
                                         qws, yinit);
  k_fused<<<dim3(B_, 4), 512, 0, stream>>>(logsig, Pip, bip, g_in, b_in,
                                           Pk, bk, qws, up, Asp);
  k_ured<<<dim3(B_*NH), 256, 0, stream>>>(up, Asp, u_bf, Asum);
  k_mid<<<dim3(B_/64), 512, 0, stream>>>(u_bf, Pv, bv, Asum, yinit,
                                         Po, bo, g_ff, b_ff, yo, yln);
  k_ff1<<<dim3(B_/64, FFD/64), 256, 0, stream>>>(yln, P1, b1, a1b);
  k_ff2<<<dim3(B_/64, HID/64), 256, 0, stream>>>(a1b, P2, b2, yo, y2);
  k_final<<<dim3(B_/64), 256, 0, stream>>>(y2, Wf, bf, out);
}

// Round 11
// 188.876 us; speedup vs baseline: 7.1769x; 1.3201x over previous
//
#include <hip/hip_runtime.h>
#include <hip/hip_bf16.h>
#include <math.h>

#define B_ 256
#define T_ 256
#define CIN 64
#define HID 512
#define NH 8
#define HD 64
#define FFD 2048
#define OUTD 10

typedef __bf16 bf16x8 __attribute__((ext_vector_type(8)));
typedef float f32x4 __attribute__((ext_vector_type(4)));

// swizzled LDS byte offset for a [rows x 512] bf16 tile (row stride 1024B)
#define HSOFF(r,c) (((r)<<10) + ((((c)<<1)) ^ ((((r)&7))<<4)))
// swizzled LDS byte offset for a [rows x 2048] bf16 tile (row stride 4096B)
#define HS2OFF(r,c) (((r)<<12) + ((((c)<<1)) ^ ((((r)&7))<<4)))

__device__ __forceinline__ float bf2f(unsigned u){
  union { unsigned i; float f; } c; c.i = u << 16; return c.f;
}
__device__ __forceinline__ unsigned pk2(float a, float b){
  return ((unsigned)__bfloat16_as_ushort(__float2bfloat16(a))) |
         (((unsigned)__bfloat16_as_ushort(__float2bfloat16(b))) << 16);
}

// ---------------- pack: f32 weight (N x K) -> bf16 MFMA-fragment order ----------------
__device__ __forceinline__ void pack_one(const float* __restrict__ W,
                                         __hip_bfloat16* __restrict__ P,
                                         const int K, int g){
  int row = g / (K/8), kg = g % (K/8);
  int k0 = kg*8;
  int n0 = row >> 6, j = (row >> 4) & 3, lr = row & 15;
  int s = k0 >> 5, lg = (k0 >> 3) & 3;
  int lane = lg*16 + lr;
  const float* src = W + (size_t)row*K + k0;
  float4 a = *(const float4*)src;
  float4 b = *(const float4*)(src+4);
  uint4 p = { pk2(a.x,a.y), pk2(a.z,a.w), pk2(b.x,b.y), pk2(b.z,b.w) };
  size_t off = ((((size_t)n0*(K>>5) + s)*4 + j)*64 + lane)*8;
  *(uint4*)(P + off) = p;
}

#define G_KV (HID*HID/8)   // 32768
#define G_FF (FFD*HID/8)   // 131072
#define G_IP (HID*CIN/8)   // 4096
#define G_I  (CIN*128/8)   // 1024
#define PK_TOT (4*G_KV + 2*G_FF + G_IP + G_I)
__global__ __launch_bounds__(256) void k_pack(
    const float* __restrict__ Wk, const float* __restrict__ Wv,
    const float* __restrict__ Wo, const float* __restrict__ Wq,
    const float* __restrict__ W1, const float* __restrict__ W2,
    const float* __restrict__ Wip, const float* __restrict__ Wi,
    __hip_bfloat16* __restrict__ Pk, __hip_bfloat16* __restrict__ Pv,
    __hip_bfloat16* __restrict__ Po, __hip_bfloat16* __restrict__ Pq,
    __hip_bfloat16* __restrict__ P1, __hip_bfloat16* __restrict__ P2,
    __hip_bfloat16* __restrict__ Pip, __hip_bfloat16* __restrict__ Pi)
{
  int g = blockIdx.x*256 + threadIdx.x;
  if (g < G_KV) { pack_one(Wk, Pk, HID, g); return; }  g -= G_KV;
  if (g < G_KV) { pack_one(Wv, Pv, HID, g); return; }  g -= G_KV;
  if (g < G_KV) { pack_one(Wo, Po, HID, g); return; }  g -= G_KV;
  if (g < G_KV) { pack_one(Wq, Pq, HID, g); return; }  g -= G_KV;
  if (g < G_FF) { pack_one(W1, P1, HID, g); return; }  g -= G_FF;
  if (g < G_FF) { pack_one(W2, P2, FFD, g); return; }  g -= G_FF;
  if (g < G_IP) { pack_one(Wip, Pip, CIN, g); return; }  g -= G_IP;
  if (g < G_I ) { pack_one(Wi, Pi, 128, g); }
}

// ---- building block (M=64): A(64x64 in Hs cols 0..64) @ Wip^T + LN -> Hs (64x512 bf16) ----
__device__ __forceinline__ void proj_ln(
    char* Hs, const __hip_bfloat16* __restrict__ Pip,
    const float* __restrict__ bip, const float* __restrict__ g_in,
    const float* __restrict__ b_in,
    float (*red)[8][2], float (*ms2)[2],
    int tid, int w, int l, int lr, int lg)
{
  f32x4 acc[4][4];
  #pragma unroll
  for (int i=0;i<4;i++)
    #pragma unroll
    for (int j=0;j<4;j++) acc[i][j] = (f32x4){0.f,0.f,0.f,0.f};
  #pragma unroll
  for (int s = 0; s < 2; s++){
    bf16x8 af[4], bfr[4];
    #pragma unroll
    for (int i=0;i<4;i++)
      af[i] = *(const bf16x8*)(Hs + HSOFF(i*16 + lr, s*32 + lg*8));
    const __hip_bfloat16* fb = Pip + ((size_t)(w*2 + s)*4)*512 + l*8;
    #pragma unroll
    for (int j=0;j<4;j++)
      bfr[j] = *(const bf16x8*)(fb + j*512);
    #pragma unroll
    for (int i=0;i<4;i++)
      #pragma unroll
      for (int j=0;j<4;j++)
        acc[i][j] = __builtin_amdgcn_mfma_f32_16x16x32_bf16(af[i], bfr[j], acc[i][j], 0,0,0);
  }
  float bipv[4], gv[4], bbv[4];
  #pragma unroll
  for (int j=0;j<4;j++){
    int col = w*64 + j*16 + lr;
    bipv[j] = bip[col]; gv[j] = g_in[col]; bbv[j] = b_in[col];
  }
  #pragma unroll
  for (int i=0;i<4;i++){
    #pragma unroll
    for (int r=0;r<4;r++){
      float s = 0.f, s2 = 0.f;
      #pragma unroll
      for (int j=0;j<4;j++){ float v = acc[i][j][r] + bipv[j]; s += v; s2 += v*v; }
      #pragma unroll
      for (int o=1;o<16;o<<=1){ s += __shfl_xor(s,o); s2 += __shfl_xor(s2,o); }
      if (lr == 0){ int row = i*16 + lg*4 + r; red[row][w][0] = s; red[row][w][1] = s2; }
    }
  }
  __syncthreads();
  if (tid < 64){
    float S = 0.f, S2 = 0.f;
    #pragma unroll
    for (int k=0;k<8;k++){ S += red[tid][k][0]; S2 += red[tid][k][1]; }
    float m = S*(1.f/512.f), var = S2*(1.f/512.f) - m*m;
    ms2[tid][0] = m; ms2[tid][1] = rsqrtf(var + 1e-5f);
  }
  __syncthreads();
  #pragma unroll
  for (int i=0;i<4;i++){
    #pragma unroll
    for (int r=0;r<4;r++){
      int row = i*16 + lg*4 + r;
      float m = ms2[row][0], rs = ms2[row][1];
      #pragma unroll
      for (int j=0;j<4;j++){
        int col = w*64 + j*16 + lr;
        float v = (acc[i][j][r] + bipv[j] - m)*rs*gv[j] + bbv[j];
        *(unsigned short*)(Hs + HSOFF(row, col)) =
            __bfloat16_as_ushort(__float2bfloat16(v));
      }
    }
  }
  __syncthreads();
}

// ---- building block (M=64): acc = Hs(64x512) @ P^T (K=512, packed, n0 pre-applied) ----
__device__ __forceinline__ void gemm512_pk(
    const char* Hs, const __hip_bfloat16* __restrict__ Pm,
    f32x4 acc[4][4], int l, int lr, int lg)
{
  #pragma unroll
  for (int i=0;i<4;i++)
    #pragma unroll
    for (int j=0;j<4;j++) acc[i][j] = (f32x4){0.f,0.f,0.f,0.f};
  #pragma unroll
  for (int s = 0; s < 16; s++){
    bf16x8 af[4], bfr[4];
    #pragma unroll
    for (int i=0;i<4;i++)
      af[i] = *(const bf16x8*)(Hs + HSOFF(i*16 + lr, s*32 + lg*8));
    const __hip_bfloat16* fb = Pm + (size_t)s*2048 + l*8;
    #pragma unroll
    for (int j=0;j<4;j++)
      bfr[j] = *(const bf16x8*)(fb + j*512);
    #pragma unroll
    for (int i=0;i<4;i++)
      #pragma unroll
      for (int j=0;j<4;j++)
        acc[i][j] = __builtin_amdgcn_mfma_f32_16x16x32_bf16(af[i], bfr[j], acc[i][j], 0,0,0);
  }
}

// ---- building block (M=16): A(16x64 in Hs cols 0..64) @ Wip^T + LN -> Hs (16x512 bf16) ----
__device__ __forceinline__ void proj_ln16(
    char* Hs, const __hip_bfloat16* __restrict__ Pip,
    const float* __restrict__ bip, const float* __restrict__ g_in,
    const float* __restrict__ b_in,
    float (*red)[8][2], float (*ms2)[2],
    int tid, int w, int l, int lr, int lg)
{
  f32x4 acc[4];
  #pragma unroll
  for (int j=0;j<4;j++) acc[j] = (f32x4){0.f,0.f,0.f,0.f};
  #pragma unroll
  for (int s = 0; s < 2; s++){
    bf16x8 af = *(const bf16x8*)(Hs + HSOFF(lr, s*32 + lg*8));
    const __hip_bfloat16* fb = Pip + ((size_t)(w*2 + s)*4)*512 + l*8;
    #pragma unroll
    for (int j=0;j<4;j++){
      bf16x8 bfr = *(const bf16x8*)(fb + j*512);
      acc[j] = __builtin_amdgcn_mfma_f32_16x16x32_bf16(af, bfr, acc[j], 0,0,0);
    }
  }
  float bipv[4], gv[4], bbv[4];
  #pragma unroll
  for (int j=0;j<4;j++){
    int col = w*64 + j*16 + lr;
    bipv[j] = bip[col]; gv[j] = g_in[col]; bbv[j] = b_in[col];
  }
  #pragma unroll
  for (int r=0;r<4;r++){
    float s = 0.f, s2 = 0.f;
    #pragma unroll
    for (int j=0;j<4;j++){ float v = acc[j][r] + bipv[j]; s += v; s2 += v*v; }
    #pragma unroll
    for (int o=1;o<16;o<<=1){ s += __shfl_xor(s,o); s2 += __shfl_xor(s2,o); }
    if (lr == 0){ int row = lg*4 + r; red[row][w][0] = s; red[row][w][1] = s2; }
  }
  __syncthreads();
  if (tid < 16){
    float S = 0.f, S2 = 0.f;
    #pragma unroll
    for (int k=0;k<8;k++){ S += red[tid][k][0]; S2 += red[tid][k][1]; }
    float m = S*(1.f/512.f), var = S2*(1.f/512.f) - m*m;
    ms2[tid][0] = m; ms2[tid][1] = rsqrtf(var + 1e-5f);
  }
  __syncthreads();
  #pragma unroll
  for (int r=0;r<4;r++){
    int row = lg*4 + r;
    float m = ms2[row][0], rs = ms2[row][1];
    #pragma unroll
    for (int j=0;j<4;j++){
      int col = w*64 + j*16 + lr;
      float v = (acc[j][r] + bipv[j] - m)*rs*gv[j] + bbv[j];
      *(unsigned short*)(Hs + HSOFF(row, col)) =
          __bfloat16_as_ushort(__float2bfloat16(v));
    }
  }
  __syncthreads();
}

// ---- building block (M=16): acc = Hs(16x512) @ P^T (K=512, packed, n0 pre-applied) ----
__device__ __forceinline__ void gemm512_pk16(
    const char* Hs, const __hip_bfloat16* __restrict__ Pm,
    f32x4 acc[4], int l, int lr, int lg)
{
  #pragma unroll
  for (int j=0;j<4;j++) acc[j] = (f32x4){0.f,0.f,0.f,0.f};
  #pragma unroll
  for (int s = 0; s < 16; s++){
    bf16x8 af = *(const bf16x8*)(Hs + HSOFF(lr, s*32 + lg*8));
    const __hip_bfloat16* fb = Pm + (size_t)s*2048 + l*8;
    #pragma unroll
    for (int j=0;j<4;j++){
      bf16x8 bfr = *(const bf16x8*)(fb + j*512);
      acc[j] = __builtin_amdgcn_mfma_f32_16x16x32_bf16(af, bfr, acc[j], 0,0,0);
    }
  }
}

// ---------------- k_pre: batched init path (q, yinit), 16 blocks x 16 batch rows ----------
__global__ __launch_bounds__(512) void k_pre(
    const float* __restrict__ initial, const float* __restrict__ logsig,
    const __hip_bfloat16* __restrict__ Pi,  const float* __restrict__ bi,
    const __hip_bfloat16* __restrict__ Pip, const float* __restrict__ bip,
    const float* __restrict__ g_in, const float* __restrict__ b_in,
    const __hip_bfloat16* __restrict__ Pq, const float* __restrict__ bq,
    const __hip_bfloat16* __restrict__ Pk, const float* __restrict__ bk,
    const __hip_bfloat16* __restrict__ Pv, const float* __restrict__ bv,
    float* __restrict__ qout, float* __restrict__ yinit)
{
  int b0 = blockIdx.x*16;
  int tid = threadIdx.x;
  int w = tid >> 6, l = tid & 63, lr = l & 15, lg = l >> 4;
  __shared__ __align__(16) char Hs[16*1024];
  __shared__ float red[16][8][2];
  __shared__ float ms2[16][2];
  __shared__ float salS[16][8];
  f32x4 acc[4];

  // ---- phase A: stage xlast (16 rows x 64 cols) -> Hs; hq = LN(x @ Wip^T) ----
  {
    int row = tid >> 5, c = (tid & 31)*2;
    const float* s = logsig + ((size_t)(b0+row)*T_ + (T_-1))*CIN + c;
    float2 a = *(const float2*)s;
    *(unsigned*)(Hs + HSOFF(row, c)) = pk2(a.x, a.y);
  }
  __syncthreads();
  proj_ln16(Hs, Pip, bip, g_in, b_in, red, ms2, tid, w, l, lr, lg);

  // ---- phase B: q = softmax_h(hq @ Wq_h^T + bq), kept in registers ----
  float qreg[4][4];   // [j][r]
  gemm512_pk16(Hs, Pq + (size_t)w*32768, acc, l, lr, lg);
  {
    float bqv[4];
    #pragma unroll
    for (int j=0;j<4;j++) bqv[j] = bq[w*64 + j*16 + lr];
    #pragma unroll
    for (int r=0;r<4;r++){
      float v0 = acc[0][r]+bqv[0], v1 = acc[1][r]+bqv[1];
      float v2 = acc[2][r]+bqv[2], v3 = acc[3][r]+bqv[3];
      float mx = fmaxf(fmaxf(v0,v1),fmaxf(v2,v3));
      #pragma unroll
      for (int o=1;o<16;o<<=1) mx = fmaxf(mx, __shfl_xor(mx,o));
      float e0=__expf(v0-mx), e1=__expf(v1-mx), e2=__expf(v2-mx), e3=__expf(v3-mx);
      float se = e0+e1+e2+e3;
      #pragma unroll
      for (int o=1;o<16;o<<=1) se += __shfl_xor(se,o);
      float inv = 1.f/se;
      qreg[0][r]=e0*inv; qreg[1][r]=e1*inv; qreg[2][r]=e2*inv; qreg[3][r]=e3*inv;
      int row = lg*4 + r;
      size_t base = (size_t)(b0+row)*HID + w*64 + lr;
      qout[base +  0] = qreg[0][r]; qout[base + 16] = qreg[1][r];
      qout[base + 32] = qreg[2][r]; qout[base + 48] = qreg[3][r];
    }
  }
  __syncthreads();

  // ---- phase C: stage initial (16x128) -> Hs cols 64..192; ip = initial@Wi^T+bi -> cols 0..64
  {
    int row = tid >> 5, c = (tid & 31)*4;
    const float* s = initial + (size_t)(b0+row)*128 + c;
    float4 a = *(const float4*)s;
    uint2 p = { pk2(a.x,a.y), pk2(a.z,a.w) };
    *(uint2*)(Hs + HSOFF(row, 64 + c)) = p;
  }
  __syncthreads();
  if (w < 4){
    f32x4 a2 = (f32x4){0.f,0.f,0.f,0.f};
    #pragma unroll
    for (int s = 0; s < 4; s++){
      bf16x8 af = *(const bf16x8*)(Hs + HSOFF(lr, 64 + s*32 + lg*8));
      bf16x8 bfr = *(const bf16x8*)(Pi + ((size_t)s*4 + w)*512 + l*8);
      a2 = __builtin_amdgcn_mfma_f32_16x16x32_bf16(af, bfr, a2, 0,0,0);
    }
    float bic = bi[w*16 + lr];
    #pragma unroll
    for (int r=0;r<4;r++){
      *(unsigned short*)(Hs + HSOFF(lg*4 + r, w*16 + lr)) =
          __bfloat16_as_ushort(__float2bfloat16(a2[r] + bic));
    }
  }
  __syncthreads();

  // ---- phase D: h0 = LN(ip @ Wip^T) -> Hs ----
  proj_ln16(Hs, Pip, bip, g_in, b_in, red, ms2, tid, w, l, lr, lg);

  // ---- phase E: k0 scores; sal = softmax(k0).q ----
  gemm512_pk16(Hs, Pk + (size_t)w*32768, acc, l, lr, lg);
  {
    float bkv[4];
    #pragma unroll
    for (int j=0;j<4;j++) bkv[j] = bk[w*64 + j*16 + lr];
    #pragma unroll
    for (int r=0;r<4;r++){
      float v0 = acc[0][r]+bkv[0], v1 = acc[1][r]+bkv[1];
      float v2 = acc[2][r]+bkv[2], v3 = acc[3][r]+bkv[3];
      float mx = fmaxf(fmaxf(v0,v1),fmaxf(v2,v3));
      #pragma unroll
      for (int o=1;o<16;o<<=1) mx = fmaxf(mx, __shfl_xor(mx,o));
      float e0=__expf(v0-mx), e1=__expf(v1-mx), e2=__expf(v2-mx), e3=__expf(v3-mx);
      float se = e0+e1+e2+e3;
      float sq = e0*qreg[0][r]+e1*qreg[1][r]+e2*qreg[2][r]+e3*qreg[3][r];
      #pragma unroll
      for (int o=1;o<16;o<<=1){ se += __shfl_xor(se,o); sq += __shfl_xor(sq,o); }
      if (lr == 0) salS[lg*4 + r][w] = sq/se;
    }
  }
  __syncthreads();

  // ---- phase F: v0; yinit = sal * v0 ----
  gemm512_pk16(Hs, Pv + (size_t)w*32768, acc, l, lr, lg);
  {
    float bvv[4];
    #pragma unroll
    for (int j=0;j<4;j++) bvv[j] = bv[w*64 + j*16 + lr];
    #pragma unroll
    for (int r=0;r<4;r++){
      int row = lg*4 + r;
      float s = salS[row][w];
      size_t base = (size_t)(b0+row)*HID + w*64 + lr;
      yinit[base +  0] = s*(acc[0][r]+bvv[0]);
      yinit[base + 16] = s*(acc[1][r]+bvv[1]);
      yinit[base + 32] = s*(acc[2][r]+bvv[2]);
      yinit[base + 48] = s*(acc[3][r]+bvv[3]);
    }
  }
}

// ---------------- FUSED kernel: hln (MFMA+LN) + score + softmax.q + MFMA partial-u ----------
__global__ __launch_bounds__(512, 4) void k_fused(
    const float* __restrict__ logsig,
    const __hip_bfloat16* __restrict__ Pip,
    const float* __restrict__ bip,
    const float* __restrict__ g_in, const float* __restrict__ b_in,
    const __hip_bfloat16* __restrict__ Pk,
    const float* __restrict__ bk,
    const float* __restrict__ qws,             // (B,512)
    float* __restrict__ up,                    // (B,NH,4,512) f32 partial u
    float* __restrict__ Asp)                   // (B,NH,4) partial alpha-sum
{
  int b = blockIdx.x, tc = blockIdx.y;
  int tid = threadIdx.x;
  int w = tid >> 6, l = tid & 63, lr = l & 15, lg = l >> 4;
  __shared__ __align__(16) char Hs[64*1024];     // 64 rows x 512 bf16, swizzled
  __shared__ float red[64][8][2];
  __shared__ float ms2[64][2];
  __shared__ float als[64][8];
  __shared__ unsigned short als_bt[2][16][64];   // alpha^T bf16 hi/lo (rows 8-15 unused)

  // ---- stage logsig x-tile (64x64 f32 -> bf16) into Hs cols 0..64 ----
  {
    int row = tid >> 3, cc = (tid & 7)*8;
    const float* srow = logsig + ((size_t)b*T_ + tc*64 + row)*CIN + cc;
    float4 a = *(const float4*)(srow);
    float4 c = *(const float4*)(srow+4);
    uint4 p = { pk2(a.x,a.y), pk2(a.z,a.w), pk2(c.x,c.y), pk2(c.z,c.w) };
    *(uint4*)(Hs + HSOFF(row, cc)) = p;
  }
  __syncthreads();

  // ---- phase 1: Hln = LN(x @ Wip^T + bip) ----
  proj_ln(Hs, Pip, bip, g_in, b_in, red, ms2, tid, w, l, lr, lg);

  // ---- phase 2: scores S = Hln @ Wk_h^T (wave w = head w), A from LDS ----
  f32x4 acc[4][4];
  gemm512_pk(Hs, Pk + (size_t)w*32768, acc, l, lr, lg);

  // ---- phase 3: per-row softmax over head cols, dot q, RK4 weight -> als (+bf16 hi/lo T) ----
  {
    float bkv[4], qv[4];
    #pragma unroll
    for (int j=0;j<4;j++){
      bkv[j] = bk[w*64 + j*16 + lr];
      qv[j]  = qws[(size_t)b*HID + w*64 + j*16 + lr];
    }
    #pragma unroll
    for (int i=0;i<4;i++){
      #pragma unroll
      for (int r=0;r<4;r++){
        float v0 = acc[i][0][r]+bkv[0], v1 = acc[i][1][r]+bkv[1];
        float v2 = acc[i][2][r]+bkv[2], v3 = acc[i][3][r]+bkv[3];
        float mx = fmaxf(fmaxf(v0,v1),fmaxf(v2,v3));
        #pragma unroll
        for (int o=1;o<16;o<<=1) mx = fmaxf(mx, __shfl_xor(mx,o));
        float e0=__expf(v0-mx), e1=__expf(v1-mx), e2=__expf(v2-mx), e3=__expf(v3-mx);
        float se = e0+e1+e2+e3;
        float sq = e0*qv[0]+e1*qv[1]+e2*qv[2]+e3*qv[3];
        #pragma unroll
        for (int o=1;o<16;o<<=1){ se += __shfl_xor(se,o); sq += __shfl_xor(sq,o); }
        if (lr == 0){
          int row = i*16 + lg*4 + r;
          int t = tc*64 + row;
          float wt = (t == 0) ? (5.f/6.f) : ((t == T_-1) ? (1.f/6.f) : 1.f);
          float alpha = wt * sq / se;
          als[row][w] = alpha;
          __hip_bfloat16 ah = __float2bfloat16(alpha);
          float rem = alpha - __bfloat162float(ah);
          als_bt[0][w][row] = __bfloat16_as_ushort(ah);
          als_bt[1][w][row] = __bfloat16_as_ushort(__float2bfloat16(rem));
        }
      }
    }
  }
  __syncthreads();

  // ---- phase 4: u = alpha^T @ H via MFMA (M=8 heads, N=64 cols/wave, K=64 rows) ----
  {
    f32x4 uacc[4];
    #pragma unroll
    for (int t=0;t<4;t++) uacc[t] = (f32x4){0.f,0.f,0.f,0.f};
    #pragma unroll
    for (int ks=0; ks<2; ks++){
      bf16x8 afh = *(const bf16x8*)&als_bt[0][lr][ks*32 + lg*8];
      bf16x8 afl = *(const bf16x8*)&als_bt[1][lr][ks*32 + lg*8];
      #pragma unroll
      for (int t=0;t<4;t++){
        int col = w*64 + t*16 + lr;
        union { unsigned u[4]; bf16x8 v; } bb;
        #pragma unroll
        for (int j2=0;j2<4;j2++){
          int r0 = ks*32 + lg*8 + 2*j2;
          unsigned lo = *(const unsigned short*)(Hs + HSOFF(r0,   col));
          unsigned hi = *(const unsigned short*)(Hs + HSOFF(r0+1, col));
          bb.u[j2] = lo | (hi << 16);
        }
        uacc[t] = __builtin_amdgcn_mfma_f32_16x16x32_bf16(afh, bb.v, uacc[t], 0,0,0);
        uacc[t] = __builtin_amdgcn_mfma_f32_16x16x32_bf16(afl, bb.v, uacc[t], 0,0,0);
      }
    }
    if (lg < 2){
      #pragma unroll
      for (int t=0;t<4;t++){
        #pragma unroll
        for (int rr=0; rr<4; rr++){
          int h = lg*4 + rr;
          up[((((size_t)b*NH + h)*4 + tc)*HID) + w*64 + t*16 + lr] = uacc[t][rr];
        }
      }
    }
    float s = als[l][w];
    #pragma unroll
    for (int o=1;o<64;o<<=1) s += __shfl_xor(s,o);
    if (l == 0) Asp[(((size_t)b*NH + w)*4) + tc] = s;
  }
}

// ---------------- reduce partials: u_bf (bf16) and Asum ----------------
__global__ __launch_bounds__(256) void k_ured(
    const float* __restrict__ up, const float* __restrict__ Asp,
    __hip_bfloat16* __restrict__ u_bf, float* __restrict__ Asum)
{
  int bh = blockIdx.x, tid = threadIdx.x;
  size_t base = (size_t)bh*4*HID;
  float s0 = 0.f, s1 = 0.f;
  #pragma unroll
  for (int c=0;c<4;c++){
    s0 += up[base + (size_t)c*HID + 2*tid];
    s1 += up[base + (size_t)c*HID + 2*tid+1];
  }
  ((unsigned*)u_bf)[(size_t)bh*(HID/2) + tid] = pk2(s0, s1);
  if (tid == 0)
    Asum[bh] = Asp[(size_t)bh*4] + Asp[(size_t)bh*4+1] + Asp[(size_t)bh*4+2] + Asp[(size_t)bh*4+3];
}

// ---------------- k_tail: yh + Wo + LN + FF1 + FF2 + final, fully LDS-resident -------------
// Grid: 16 blocks x 512 threads; 16 batch rows per block.
__global__ __launch_bounds__(512) void k_tail(
    const __hip_bfloat16* __restrict__ u_bf,   // (B,8,512)
    const __hip_bfloat16* __restrict__ Pv,
    const float* __restrict__ bv, const float* __restrict__ Asum,
    const float* __restrict__ yinit,
    const __hip_bfloat16* __restrict__ Po, const float* __restrict__ bo,
    const float* __restrict__ g_ff, const float* __restrict__ b_ff,
    const __hip_bfloat16* __restrict__ P1, const float* __restrict__ b1,
    const __hip_bfloat16* __restrict__ P2, const float* __restrict__ b2,
    const float* __restrict__ Wf, const float* __restrict__ bfv,
    float* __restrict__ out)
{
  int b0 = blockIdx.x*16;
  int tid = threadIdx.x;
  int w = tid >> 6, l = tid & 63, lr = l & 15, lg = l >> 4;
  __shared__ __align__(16) char Hs[16*1024];     // 16x512 bf16 swizzled (yh, then yln)
  __shared__ __align__(16) char A1[16*4096];     // 16x2048 bf16 swizzled (ff1 act)
  __shared__ float yoS[16][516];                 // f32 yo (then y2 in-place)
  __shared__ float red[16][8][2];
  __shared__ float ms2[16][2];
  f32x4 acc[4];

  // ---- phase 1: yh = u @ Wv_h^T + yinit + bv*Asum -> Hs ----
  #pragma unroll
  for (int j=0;j<4;j++) acc[j] = (f32x4){0.f,0.f,0.f,0.f};
  #pragma unroll
  for (int s = 0; s < 16; s++){
    bf16x8 af = *(const bf16x8*)(u_bf + ((size_t)(b0 + lr)*NH + w)*HID + s*32 + lg*8);
    const __hip_bfloat16* fb = Pv + (size_t)w*32768 + (size_t)s*2048 + l*8;
    #pragma unroll
    for (int j=0;j<4;j++){
      bf16x8 bfr = *(const bf16x8*)(fb + j*512);
      acc[j] = __builtin_amdgcn_mfma_f32_16x16x32_bf16(af, bfr, acc[j], 0,0,0);
    }
  }
  {
    float bvv[4];
    #pragma unroll
    for (int j=0;j<4;j++) bvv[j] = bv[w*64 + j*16 + lr];
    #pragma unroll
    for (int r=0;r<4;r++){
      int row = lg*4 + r;
      float As = Asum[(size_t)(b0+row)*NH + w];
      #pragma unroll
      for (int j=0;j<4;j++){
        int col = w*64 + j*16 + lr;
        float v = acc[j][r] + yinit[(size_t)(b0+row)*HID + col] + bvv[j]*As;
        *(unsigned short*)(Hs + HSOFF(row, col)) =
            __bfloat16_as_ushort(__float2bfloat16(v));
      }
    }
  }
  __syncthreads();

  // ---- phase 2: yo = yh @ Wo^T + bo -> yoS; LN -> yln overwrites Hs ----
  gemm512_pk16(Hs, Po + (size_t)w*32768, acc, l, lr, lg);
  {
    float bov[4], gv[4], bbv[4];
    #pragma unroll
    for (int j=0;j<4;j++){
      int col = w*64 + j*16 + lr;
      bov[j] = bo[col]; gv[j] = g_ff[col]; bbv[j] = b_ff[col];
    }
    #pragma unroll
    for (int r=0;r<4;r++){
      int row = lg*4 + r;
      float s = 0.f, s2 = 0.f;
      #pragma unroll
      for (int j=0;j<4;j++){
        float v = acc[j][r] + bov[j];
        yoS[row][w*64 + j*16 + lr] = v;
        s += v; s2 += v*v;
      }
      #pragma unroll
      for (int o=1;o<16;o<<=1){ s += __shfl_xor(s,o); s2 += __shfl_xor(s2,o); }
      if (lr == 0){ red[row][w][0] = s; red[row][w][1] = s2; }
    }
    __syncthreads();
    if (tid < 16){
      float S = 0.f, S2 = 0.f;
      #pragma unroll
      for (int k=0;k<8;k++){ S += red[tid][k][0]; S2 += red[tid][k][1]; }
      float m = S*(1.f/512.f), var = S2*(1.f/512.f) - m*m;
      ms2[tid][0] = m; ms2[tid][1] = rsqrtf(var + 1e-5f);
    }
    __syncthreads();
    #pragma unroll
    for (int r=0;r<4;r++){
      int row = lg*4 + r;
      float m = ms2[row][0], rs = ms2[row][1];
      #pragma unroll
      for (int j=0;j<4;j++){
        int col = w*64 + j*16 + lr;
        float v = (yoS[row][col] - m)*rs*gv[j] + bbv[j];
        *(unsigned short*)(Hs + HSOFF(row, col)) =
            __bfloat16_as_ushort(__float2bfloat16(v));
      }
    }
  }
  __syncthreads();

  // ---- phase 3: a1 = relu(yln @ W1^T + b1) -> A1 (wave w owns cols w*256..w*256+255) ----
  #pragma unroll
  for (int n0 = 0; n0 < 4; n0++){
    gemm512_pk16(Hs, P1 + (size_t)(w*4 + n0)*32768, acc, l, lr, lg);
    #pragma unroll
    for (int j=0;j<4;j++){
      int col = (w*4 + n0)*64 + j*16 + lr;
      float bc = b1[col];
      #pragma unroll
      for (int r=0;r<4;r++){
        int row = lg*4 + r;
        *(unsigned short*)(A1 + HS2OFF(row, col)) =
            __bfloat16_as_ushort(__float2bfloat16(fmaxf(acc[j][r] + bc, 0.f)));
      }
    }
  }
  __syncthreads();

  // ---- phase 4: y2 = a1 @ W2^T + b2 + yo (in-place into yoS) ----
  #pragma unroll
  for (int j=0;j<4;j++) acc[j] = (f32x4){0.f,0.f,0.f,0.f};
  #pragma unroll
  for (int s = 0; s < 64; s++){
    bf16x8 af = *(const bf16x8*)(A1 + HS2OFF(lr, s*32 + lg*8));
    const __hip_bfloat16* fb = P2 + (size_t)w*131072 + (size_t)s*2048 + l*8;
    #pragma unroll
    for (int j=0;j<4;j++){
      bf16x8 bfr = *(const bf16x8*)(fb + j*512);
      acc[j] = __builtin_amdgcn_mfma_f32_16x16x32_bf16(af, bfr, acc[j], 0,0,0);
    }
  }
  {
    float b2v[4];
    #pragma unroll
    for (int j=0;j<4;j++) b2v[j] = b2[w*64 + j*16 + lr];
    #pragma unroll
    for (int r=0;r<4;r++){
      int row = lg*4 + r;
      #pragma unroll
      for (int j=0;j<4;j++){
        int col = w*64 + j*16 + lr;
        yoS[row][col] = acc[j][r] + b2v[j] + yoS[row][col];
      }
    }
  }
  __syncthreads();

  // ---- phase 5: out = y2 @ Wf^T + bf ----
  {
    int pair = tid >> 1, half = tid & 1;
    if (pair < 16*OUTD){
      int row = pair / OUTD, oc = pair % OUTD;
      const float4* wr = (const float4*)(Wf + (size_t)oc*HID) + half*64;
      float sacc = 0.f;
      #pragma unroll 8
      for (int k4 = 0; k4 < 64; k4++){
        float4 a = wr[k4];
        int c = half*256 + k4*4;
        sacc += a.x*yoS[row][c] + a.y*yoS[row][c+1]
              + a.z*yoS[row][c+2] + a.w*yoS[row][c+3];
      }
      sacc += __shfl_xor(sacc, 1);
      if (half == 0) out[(size_t)(b0+row)*OUTD + oc] = bfv[oc] + sacc;
    }
  }
}

extern "C" void kernel_launch(void* const* d_in, const int* in_sizes, int n_in,
                              void* d_out, int out_size, void* d_ws, size_t ws_size,
                              hipStream_t stream)
{
  const float* initial = (const float*)d_in[0];
  const float* logsig  = (const float*)d_in[1];
  const float* Wi  = (const float*)d_in[2];  const float* bi  = (const float*)d_in[3];
  const float* Wip = (const float*)d_in[4];  const float* bip = (const float*)d_in[5];
  const float* g_in= (const float*)d_in[6];  const float* b_in= (const float*)d_in[7];
  const float* Wk  = (const float*)d_in[8];  const float* bk  = (const float*)d_in[9];
  const float* Wv  = (const float*)d_in[10]; const float* bv  = (const float*)d_in[11];
  const float* Wq  = (const float*)d_in[12]; const float* bq  = (const float*)d_in[13];
  const float* Wo  = (const float*)d_in[14]; const float* bo  = (const float*)d_in[15];
  const float* g_ff= (const float*)d_in[16]; const float* b_ff= (const float*)d_in[17];
  const float* W1  = (const float*)d_in[18]; const float* b1  = (const float*)d_in[19];
  const float* W2  = (const float*)d_in[20]; const float* b2  = (const float*)d_in[21];
  const float* Wf  = (const float*)d_in[22]; const float* bf  = (const float*)d_in[23];
  float* out = (float*)d_out;

  char* ws = (char*)d_ws;
  const size_t MB = 1<<20;
  float* qws   = (float*)(ws);                             // 512 KB
  float* yinit = (float*)(ws + 512*1024);                  // 512 KB
  __hip_bfloat16* u_bf = (__hip_bfloat16*)(ws + 3*MB);     // 2 MB
  float* Asum  = (float*)(ws + 5*MB);                      // 8 KB
  __hip_bfloat16* Pk  = (__hip_bfloat16*)(ws + 5*MB + 512*1024);  // 512 KB
  __hip_bfloat16* Pv  = (__hip_bfloat16*)(ws + 6*MB);      // 512 KB
  __hip_bfloat16* P1  = (__hip_bfloat16*)(ws + 6*MB + 512*1024);  // 2 MB
  __hip_bfloat16* P2  = (__hip_bfloat16*)(ws + 8*MB + 512*1024);  // 2 MB
  __hip_bfloat16* Po  = (__hip_bfloat16*)(ws + 13*MB);     // 512 KB
  __hip_bfloat16* Pip = (__hip_bfloat16*)(ws + 15*MB);     // 64 KB
  float* up    = (float*)(ws + 16*MB);                     // 16 MB
  float* Asp   = (float*)(ws + 33*MB);                     // 32 KB
  __hip_bfloat16* Pq  = (__hip_bfloat16*)(ws + 34*MB);     // 512 KB
  __hip_bfloat16* Pi  = (__hip_bfloat16*)(ws + 35*MB);     // 16 KB

  k_pack<<<dim3((PK_TOT + 255)/256), 256, 0, stream>>>(
      Wk, Wv, Wo, Wq, W1, W2, Wip, Wi,
      Pk, Pv, Po, Pq, P1, P2, Pip, Pi);
  k_pre<<<dim3(B_/16), 512, 0, stream>>>(initial, logsig, Pi, bi, Pip, bip,
                                         g_in, b_in, Pq, bq, Pk, bk, Pv, bv,
                                         qws, yinit);
  k_fused<<<dim3(B_, 4), 512, 0, stream>>>(logsig, Pip, bip, g_in, b_in,
                                           Pk, bk, qws, up, Asp);
  k_ured<<<dim3(B_*NH), 256, 0, stream>>>(up, Asp, u_bf, Asum);
  k_tail<<<dim3(B_/16), 512, 0, stream>>>(u_bf, Pv, bv, Asum, yinit,
                                          Po, bo, g_ff, b_ff,
                                          P1, b1, P2, b2, Wf, bf, out);
}